// Round 1
// baseline (941.631 us; speedup 1.0000x reference)
//
#include <hip/hip_runtime.h>

#define HIDN 2048
#define NHEAD 16
#define HD 128
#define SEQ 2048
#define BATCH 2
#define NROWS (BATCH*SEQ)   // 4096

typedef __bf16 bf16_t;
typedef bf16_t bf16x8 __attribute__((ext_vector_type(8)));
typedef float f32x4 __attribute__((ext_vector_type(4)));

__device__ __forceinline__ unsigned short f2bf(float x) {
  union { bf16_t b; unsigned short u; } cv; cv.b = (bf16_t)x; return cv.u;
}

#define MFMA16(a,b,c) __builtin_amdgcn_mfma_f32_16x16x32_bf16((a),(b),(c),0,0,0)

// ---------------------------------------------------------------- transpose+cvt
// W [2048][2048] f32 row-major -> Wt [n][k] bf16
__global__ __launch_bounds__(256) void transpose_cvt_kernel(
    const float* __restrict__ W, unsigned short* __restrict__ Wt) {
  __shared__ float t[32][33];
  int bn = blockIdx.x * 32;  // n tile
  int bk = blockIdx.y * 32;  // k tile
  int tx = threadIdx.x & 31, ty = threadIdx.x >> 5;  // 32x8
#pragma unroll
  for (int i = 0; i < 4; ++i) {
    int k = bk + ty + i * 8;
    t[ty + i * 8][tx] = W[(long)k * HIDN + bn + tx];
  }
  __syncthreads();
#pragma unroll
  for (int i = 0; i < 4; ++i) {
    int n = bn + ty + i * 8;
    Wt[(long)n * HIDN + bk + tx] = f2bf(t[tx][ty + i * 8]);
  }
}

// ---------------------------------------------------------------- rope tables
__global__ void rope_table_kernel(float* __restrict__ cosT, float* __restrict__ sinT) {
  int s = blockIdx.x, d = threadIdx.x;  // d in [0,64)
  float invf = powf(10000.0f, (-2.0f * (float)d) / 128.0f);
  float ang = (float)s * invf;
  cosT[s * 64 + d] = cosf(ang);
  sinT[s * 64 + d] = sinf(ang);
}

// ---------------------------------------------------------------- rmsnorm (f32 in -> bf16 out)
__global__ __launch_bounds__(256) void rmsnorm_kernel(
    const float* __restrict__ x, const float* __restrict__ w, unsigned short* __restrict__ out) {
  long row = blockIdx.x;
  const float* xr = x + row * HIDN;
  int c0 = threadIdx.x * 4;
  float4 v0 = *(const float4*)(xr + c0);
  float4 v1 = *(const float4*)(xr + 1024 + c0);
  float s = v0.x*v0.x + v0.y*v0.y + v0.z*v0.z + v0.w*v0.w
          + v1.x*v1.x + v1.y*v1.y + v1.z*v1.z + v1.w*v1.w;
#pragma unroll
  for (int off = 1; off < 64; off <<= 1) s += __shfl_xor(s, off);
  __shared__ float red[4];
  if ((threadIdx.x & 63) == 0) red[threadIdx.x >> 6] = s;
  __syncthreads();
  float tot = red[0] + red[1] + red[2] + red[3];
  float r = 1.0f / sqrtf(tot * (1.0f / (float)HIDN) + 1e-6f);
  float4 w0 = *(const float4*)(w + c0);
  float4 w1 = *(const float4*)(w + 1024 + c0);
  ushort4 o0, o1;
  o0.x = f2bf(v0.x * r * w0.x); o0.y = f2bf(v0.y * r * w0.y);
  o0.z = f2bf(v0.z * r * w0.z); o0.w = f2bf(v0.w * r * w0.w);
  o1.x = f2bf(v1.x * r * w1.x); o1.y = f2bf(v1.y * r * w1.y);
  o1.z = f2bf(v1.z * r * w1.z); o1.w = f2bf(v1.w * r * w1.w);
  *(ushort4*)(out + row * HIDN + c0) = o0;
  *(ushort4*)(out + row * HIDN + 1024 + c0) = o1;
}

// ---------------------------------------------------------------- GEMM
// C[M,N] = A[M,K](bf16) x Bt[N,K](bf16).  OUTMODE 0: f32 C, 1: bf16 C.
#define GBK 32
#define GPAD 8
template <int OUTMODE>
__global__ __launch_bounds__(256) void gemm_kernel(
    const unsigned short* __restrict__ A, const unsigned short* __restrict__ Bt,
    void* __restrict__ Cout, int M, int N, int K) {
  __shared__ unsigned short As[128][GBK + GPAD];
  __shared__ unsigned short Bs[128][GBK + GPAD];
  const int tid = threadIdx.x;
  const int lane = tid & 63, wave = tid >> 6;
  const int wm = (wave >> 1) * 64, wn = (wave & 1) * 64;
  const int lr = lane & 15, lkg = lane >> 4;
  const int lk = lkg * 8;
  const long bm = (long)blockIdx.y * 128, bn = (long)blockIdx.x * 128;
  f32x4 acc[4][4] = {};
  const int srow = tid >> 1, skc = (tid & 1) * 16;
  const unsigned short* Ag = A + (bm + srow) * K + skc;
  const unsigned short* Bg = Bt + (bn + srow) * K + skc;
  for (int k0 = 0; k0 < K; k0 += GBK) {
    int4 a0 = *(const int4*)(Ag + k0);
    int4 a1 = *(const int4*)(Ag + k0 + 8);
    int4 b0 = *(const int4*)(Bg + k0);
    int4 b1 = *(const int4*)(Bg + k0 + 8);
    __syncthreads();
    *(int4*)&As[srow][skc]     = a0;
    *(int4*)&As[srow][skc + 8] = a1;
    *(int4*)&Bs[srow][skc]     = b0;
    *(int4*)&Bs[srow][skc + 8] = b1;
    __syncthreads();
    bf16x8 af[4], bf[4];
#pragma unroll
    for (int m = 0; m < 4; ++m) af[m] = *(const bf16x8*)&As[wm + m * 16 + lr][lk];
#pragma unroll
    for (int n = 0; n < 4; ++n) bf[n] = *(const bf16x8*)&Bs[wn + n * 16 + lr][lk];
#pragma unroll
    for (int m = 0; m < 4; ++m)
#pragma unroll
      for (int n = 0; n < 4; ++n) acc[m][n] = MFMA16(af[m], bf[n], acc[m][n]);
  }
#pragma unroll
  for (int m = 0; m < 4; ++m)
#pragma unroll
    for (int n = 0; n < 4; ++n) {
      long r0 = bm + wm + m * 16 + lkg * 4;
      long c = bn + wn + n * 16 + lr;
#pragma unroll
      for (int r = 0; r < 4; ++r) {
        if (OUTMODE == 0) ((float*)Cout)[(r0 + r) * N + c] = acc[m][n][r];
        else ((unsigned short*)Cout)[(r0 + r) * N + c] = f2bf(acc[m][n][r]);
      }
    }
}

// ---------------------------------------------------------------- rope apply (f32 in -> bf16 out)
__global__ __launch_bounds__(256) void rope_kernel(
    const float* __restrict__ in, unsigned short* __restrict__ out,
    const float* __restrict__ cosT, const float* __restrict__ sinT) {
  long row = blockIdx.x;
  int s = (int)(row & (SEQ - 1));
  const float* ir = in + row * HIDN;
  unsigned short* orow = out + row * HIDN;
#pragma unroll
  for (int i = 0; i < 4; ++i) {
    int idx = threadIdx.x + i * 256;  // 0..1023
    int h = idx >> 6, d = idx & 63;
    float x1 = ir[h * HD + d], x2 = ir[h * HD + d + 64];
    float c = cosT[s * 64 + d], sn = sinT[s * 64 + d];
    orow[h * HD + d]      = f2bf(x1 * c - x2 * sn);
    orow[h * HD + d + 64] = f2bf(x2 * c + x1 * sn);
  }
}

// ---------------------------------------------------------------- flash attention
// Q,K,V bf16 [B*S, NH*HD] (cols = h*HD+d). O bf16 same layout. No mask.
__global__ __launch_bounds__(256) void flash_attn_kernel(
    const unsigned short* __restrict__ Q, const unsigned short* __restrict__ Kb,
    const unsigned short* __restrict__ Vb, unsigned short* __restrict__ O) {
  __shared__ unsigned short Ks[64][136];     // [kv][d] +8 pad
  __shared__ unsigned short Vt[128][72];     // [d][kv] +8 pad
  __shared__ unsigned short Ps[4][16][72];   // per-wave P [qrow][kv]
  const int qt = blockIdx.x, h = blockIdx.y, b = blockIdx.z;
  const int tid = threadIdx.x, wave = tid >> 6, lane = tid & 63;
  const int lr = lane & 15, lkg = lane >> 4, lk = lkg * 8;
  const float scale = 0.08838834764831845f;  // 1/sqrt(128)
  const long rowbase = (long)b * SEQ;
  const int qrow0 = qt * 64 + wave * 16;
  bf16x8 aq[4];
#pragma unroll
  for (int ks = 0; ks < 4; ++ks)
    aq[ks] = *(const bf16x8*)(Q + (rowbase + qrow0 + lr) * HIDN + h * HD + ks * 32 + lk);
  f32x4 acc[8] = {};
  float m_[4] = {-3.0e38f, -3.0e38f, -3.0e38f, -3.0e38f};
  float l_[4] = {0.f, 0.f, 0.f, 0.f};
  for (int kv0 = 0; kv0 < SEQ; kv0 += 64) {
    // stage K [64][128] and V^T [128][64]
#pragma unroll
    for (int i = 0; i < 4; ++i) {
      int c = tid + 256 * i;
      int kr = c >> 4, ko = (c & 15) * 8;
      int4 kvv = *(const int4*)(Kb + (rowbase + kv0 + kr) * HIDN + h * HD + ko);
      *(int4*)&Ks[kr][ko] = kvv;
      int4 vv = *(const int4*)(Vb + (rowbase + kv0 + kr) * HIDN + h * HD + ko);
      const unsigned short* pv = (const unsigned short*)&vv;
#pragma unroll
      for (int j = 0; j < 8; ++j) Vt[ko + j][kr] = pv[j];
    }
    __syncthreads();
    // scores: 16x64 per wave
    f32x4 sa[4] = {};
#pragma unroll
    for (int n = 0; n < 4; ++n)
#pragma unroll
      for (int ks = 0; ks < 4; ++ks) {
        bf16x8 bk = *(const bf16x8*)&Ks[n * 16 + lr][ks * 32 + lk];
        sa[n] = MFMA16(aq[ks], bk, sa[n]);
      }
#pragma unroll
    for (int n = 0; n < 4; ++n)
#pragma unroll
      for (int r = 0; r < 4; ++r) sa[n][r] *= scale;
    // online softmax per q row (row = 4*lkg + r)
#pragma unroll
    for (int r = 0; r < 4; ++r) {
      float mx = fmaxf(fmaxf(sa[0][r], sa[1][r]), fmaxf(sa[2][r], sa[3][r]));
#pragma unroll
      for (int off = 1; off < 16; off <<= 1) mx = fmaxf(mx, __shfl_xor(mx, off));
      float mnew = fmaxf(m_[r], mx);
      float corr = __expf(m_[r] - mnew);
      float psum = 0.f;
#pragma unroll
      for (int n = 0; n < 4; ++n) {
        float p = __expf(sa[n][r] - mnew);
        sa[n][r] = p;
        psum += p;
      }
#pragma unroll
      for (int off = 1; off < 16; off <<= 1) psum += __shfl_xor(psum, off);
      l_[r] = l_[r] * corr + psum;
      m_[r] = mnew;
#pragma unroll
      for (int df = 0; df < 8; ++df) acc[df][r] *= corr;
    }
    // write P (bf16) to per-wave LDS
#pragma unroll
    for (int r = 0; r < 4; ++r)
#pragma unroll
      for (int n = 0; n < 4; ++n) Ps[wave][lkg * 4 + r][n * 16 + lr] = f2bf(sa[n][r]);
    __syncthreads();
    // PV
    bf16x8 pa0 = *(const bf16x8*)&Ps[wave][lr][lk];
    bf16x8 pa1 = *(const bf16x8*)&Ps[wave][lr][32 + lk];
#pragma unroll
    for (int df = 0; df < 8; ++df) {
      bf16x8 bv0 = *(const bf16x8*)&Vt[df * 16 + lr][lk];
      bf16x8 bv1 = *(const bf16x8*)&Vt[df * 16 + lr][32 + lk];
      acc[df] = MFMA16(pa0, bv0, acc[df]);
      acc[df] = MFMA16(pa1, bv1, acc[df]);
    }
    __syncthreads();
  }
#pragma unroll
  for (int r = 0; r < 4; ++r) {
    float invl = 1.0f / l_[r];
    long orow = rowbase + qrow0 + lkg * 4 + r;
#pragma unroll
    for (int df = 0; df < 8; ++df)
      O[orow * HIDN + h * HD + df * 16 + lr] = f2bf(acc[df][r] * invl);
  }
}

// ---------------------------------------------------------------- elementwise
__global__ __launch_bounds__(256) void add_kernel(
    const float* __restrict__ a, const float* __restrict__ b, float* __restrict__ out) {
  long i = ((long)blockIdx.x * 256 + threadIdx.x) * 4;
  float4 va = *(const float4*)(a + i);
  float4 vb = *(const float4*)(b + i);
  float4 o; o.x = va.x + vb.x; o.y = va.y + vb.y; o.z = va.z + vb.z; o.w = va.w + vb.w;
  *(float4*)(out + i) = o;
}

__global__ __launch_bounds__(256) void add_inplace_kernel(
    float* __restrict__ out, const float* __restrict__ a) {
  long i = ((long)blockIdx.x * 256 + threadIdx.x) * 4;
  float4 va = *(const float4*)(a + i);
  float4 vo = *(const float4*)(out + i);
  vo.x += va.x; vo.y += va.y; vo.z += va.z; vo.w += va.w;
  *(float4*)(out + i) = vo;
}

__global__ __launch_bounds__(256) void silu_mul_kernel(
    const float* __restrict__ g1, const float* __restrict__ g3, unsigned short* __restrict__ out) {
  long i = ((long)blockIdx.x * 256 + threadIdx.x) * 4;
  float4 a = *(const float4*)(g1 + i);
  float4 b = *(const float4*)(g3 + i);
  ushort4 o;
  o.x = f2bf(a.x / (1.f + __expf(-a.x)) * b.x);
  o.y = f2bf(a.y / (1.f + __expf(-a.y)) * b.y);
  o.z = f2bf(a.z / (1.f + __expf(-a.z)) * b.z);
  o.w = f2bf(a.w / (1.f + __expf(-a.w)) * b.w);
  *(ushort4*)(out + i) = o;
}

// ---------------------------------------------------------------- launcher
extern "C" void kernel_launch(void* const* d_in, const int* in_sizes, int n_in,
                              void* d_out, int out_size, void* d_ws, size_t ws_size,
                              hipStream_t stream) {
  const float* hidden = (const float*)d_in[0];
  const float* W[7] = {(const float*)d_in[1], (const float*)d_in[2], (const float*)d_in[3],
                       (const float*)d_in[4], (const float*)d_in[5], (const float*)d_in[6],
                       (const float*)d_in[7]};  // Wq,Wk,Wv,Wo,w1,w2,w3
  const float* ln1 = (const float*)d_in[8];
  const float* ln2 = (const float*)d_in[9];
  float* out = (float*)d_out;

  char* ws = (char*)d_ws;
  size_t off = 0;
  auto alloc = [&](size_t bytes) -> void* {
    void* p = ws + off;
    off += (bytes + 255) & ~(size_t)255;
    return p;
  };
  unsigned short* wT[7];
  for (int i = 0; i < 7; ++i) wT[i] = (unsigned short*)alloc((size_t)HIDN * HIDN * 2);
  unsigned short* xb   = (unsigned short*)alloc((size_t)NROWS * HIDN * 2);
  unsigned short* qb   = (unsigned short*)alloc((size_t)NROWS * HIDN * 2);
  unsigned short* kb   = (unsigned short*)alloc((size_t)NROWS * HIDN * 2);
  unsigned short* vb   = (unsigned short*)alloc((size_t)NROWS * HIDN * 2);
  unsigned short* ctxb = (unsigned short*)alloc((size_t)NROWS * HIDN * 2);
  float* tmp0 = (float*)alloc((size_t)NROWS * HIDN * 4);
  float* tmp1 = (float*)alloc((size_t)NROWS * HIDN * 4);
  float* cosT = (float*)alloc((size_t)SEQ * 64 * 4);
  float* sinT = (float*)alloc((size_t)SEQ * 64 * 4);
  if (off > ws_size) return;  // workspace insufficient — fail visibly (wrong output)

  dim3 tgrid(HIDN / 32, HIDN / 32);
  for (int i = 0; i < 7; ++i)
    transpose_cvt_kernel<<<tgrid, 256, 0, stream>>>(W[i], wT[i]);
  rope_table_kernel<<<SEQ, 64, 0, stream>>>(cosT, sinT);

  rmsnorm_kernel<<<NROWS, 256, 0, stream>>>(hidden, ln1, xb);

  dim3 ggrid(HIDN / 128, NROWS / 128);
  gemm_kernel<0><<<ggrid, 256, 0, stream>>>(xb, wT[0], tmp0, NROWS, HIDN, HIDN);  // q pre-rope
  gemm_kernel<0><<<ggrid, 256, 0, stream>>>(xb, wT[1], tmp1, NROWS, HIDN, HIDN);  // k pre-rope
  rope_kernel<<<NROWS, 256, 0, stream>>>(tmp0, qb, cosT, sinT);
  rope_kernel<<<NROWS, 256, 0, stream>>>(tmp1, kb, cosT, sinT);
  gemm_kernel<1><<<ggrid, 256, 0, stream>>>(xb, wT[2], vb, NROWS, HIDN, HIDN);    // v

  flash_attn_kernel<<<dim3(SEQ / 64, NHEAD, BATCH), 256, 0, stream>>>(qb, kb, vb, ctxb);

  gemm_kernel<0><<<ggrid, 256, 0, stream>>>(ctxb, wT[3], tmp0, NROWS, HIDN, HIDN);  // attn_out
  add_kernel<<<NROWS * HIDN / 1024, 256, 0, stream>>>(hidden, tmp0, out);           // h

  rmsnorm_kernel<<<NROWS, 256, 0, stream>>>(out, ln2, xb);                          // y
  gemm_kernel<0><<<ggrid, 256, 0, stream>>>(xb, wT[4], tmp0, NROWS, HIDN, HIDN);    // g1 = y@w1
  gemm_kernel<0><<<ggrid, 256, 0, stream>>>(xb, wT[6], tmp1, NROWS, HIDN, HIDN);    // g3 = y@w3
  silu_mul_kernel<<<NROWS * HIDN / 1024, 256, 0, stream>>>(tmp0, tmp1, qb);         // gs
  gemm_kernel<0><<<ggrid, 256, 0, stream>>>(qb, wT[5], tmp0, NROWS, HIDN, HIDN);    // mlp = gs@w2
  add_inplace_kernel<<<NROWS * HIDN / 1024, 256, 0, stream>>>(out, tmp0);           // out = h + mlp
}

// Round 2
// 754.520 us; speedup vs baseline: 1.2480x; 1.2480x over previous
//
#include <hip/hip_runtime.h>

#define HIDN 2048
#define NHEAD 16
#define HD 128
#define SEQ 2048
#define BATCH 2
#define NROWS (BATCH*SEQ)   // 4096

typedef __bf16 bf16_t;
typedef bf16_t bf16x8 __attribute__((ext_vector_type(8)));
typedef float f32x4 __attribute__((ext_vector_type(4)));

#define AS1 __attribute__((address_space(1)))
#define AS3 __attribute__((address_space(3)))

__device__ __forceinline__ unsigned short f2bf(float x) {
  union { bf16_t b; unsigned short u; } cv; cv.b = (bf16_t)x; return cv.u;
}

#define MFMA16(a,b,c) __builtin_amdgcn_mfma_f32_16x16x32_bf16((a),(b),(c),0,0,0)

__device__ __forceinline__ void gload16(const void* g, void* l) {
  __builtin_amdgcn_global_load_lds((const AS1 void*)g, (AS3 void*)l, 16, 0, 0);
}

// ---------------------------------------------------------------- transpose+cvt
__global__ __launch_bounds__(256) void transpose_cvt_kernel(
    const float* __restrict__ W, unsigned short* __restrict__ Wt) {
  __shared__ float t[32][33];
  int bn = blockIdx.x * 32;
  int bk = blockIdx.y * 32;
  int tx = threadIdx.x & 31, ty = threadIdx.x >> 5;
#pragma unroll
  for (int i = 0; i < 4; ++i) {
    int k = bk + ty + i * 8;
    t[ty + i * 8][tx] = W[(long)k * HIDN + bn + tx];
  }
  __syncthreads();
#pragma unroll
  for (int i = 0; i < 4; ++i) {
    int n = bn + ty + i * 8;
    Wt[(long)n * HIDN + bk + tx] = f2bf(t[tx][ty + i * 8]);
  }
}

// ---------------------------------------------------------------- rope tables
__global__ void rope_table_kernel(float* __restrict__ cosT, float* __restrict__ sinT) {
  int s = blockIdx.x, d = threadIdx.x;
  float invf = powf(10000.0f, (-2.0f * (float)d) / 128.0f);
  float ang = (float)s * invf;
  cosT[s * 64 + d] = cosf(ang);
  sinT[s * 64 + d] = sinf(ang);
}

// ---------------------------------------------------------------- rmsnorm
__global__ __launch_bounds__(256) void rmsnorm_kernel(
    const float* __restrict__ x, const float* __restrict__ w, unsigned short* __restrict__ out) {
  long row = blockIdx.x;
  const float* xr = x + row * HIDN;
  int c0 = threadIdx.x * 4;
  float4 v0 = *(const float4*)(xr + c0);
  float4 v1 = *(const float4*)(xr + 1024 + c0);
  float s = v0.x*v0.x + v0.y*v0.y + v0.z*v0.z + v0.w*v0.w
          + v1.x*v1.x + v1.y*v1.y + v1.z*v1.z + v1.w*v1.w;
#pragma unroll
  for (int off = 1; off < 64; off <<= 1) s += __shfl_xor(s, off);
  __shared__ float red[4];
  if ((threadIdx.x & 63) == 0) red[threadIdx.x >> 6] = s;
  __syncthreads();
  float tot = red[0] + red[1] + red[2] + red[3];
  float r = 1.0f / sqrtf(tot * (1.0f / (float)HIDN) + 1e-6f);
  float4 w0 = *(const float4*)(w + c0);
  float4 w1 = *(const float4*)(w + 1024 + c0);
  ushort4 o0, o1;
  o0.x = f2bf(v0.x * r * w0.x); o0.y = f2bf(v0.y * r * w0.y);
  o0.z = f2bf(v0.z * r * w0.z); o0.w = f2bf(v0.w * r * w0.w);
  o1.x = f2bf(v1.x * r * w1.x); o1.y = f2bf(v1.y * r * w1.y);
  o1.z = f2bf(v1.z * r * w1.z); o1.w = f2bf(v1.w * r * w1.w);
  *(ushort4*)(out + row * HIDN + c0) = o0;
  *(ushort4*)(out + row * HIDN + 1024 + c0) = o1;
}

// ---------------------------------------------------------------- GEMM (m97 structure)
// C[M,N] = A[M,K](bf16) x Bt[N,K](bf16). global_load_lds w16, pre-swizzled source.
template <int OUTMODE>
__global__ __launch_bounds__(256) void gemm_kernel(
    const unsigned short* __restrict__ A, const unsigned short* __restrict__ Bt,
    void* __restrict__ Cout, int M, int N, int K) {
  __shared__ unsigned short As[128 * 32];
  __shared__ unsigned short Bs[128 * 32];
  const int tid = threadIdx.x;
  const int lane = tid & 63, wave = tid >> 6;
  const int wm = (wave >> 1) * 64, wn = (wave & 1) * 64;
  const int lr = lane & 15, lkg = lane >> 4;
  const long bm = (long)blockIdx.y * 128, bn = (long)blockIdx.x * 128;
  f32x4 acc[4][4] = {};
  // staging: wave issues 2 A + 2 B instrs; instr j covers 16 rows (1 KiB)
  const int rA0 = wave * 32 + (lane >> 2);         // j=0 row; j=1: +16
  const int gs0 = (lane & 3) ^ ((rA0 >> 1) & 3);
  const int gs1 = (lane & 3) ^ (((rA0 + 16) >> 1) & 3);
  const unsigned short* Ag0 = A + (bm + rA0) * K + gs0 * 8;
  const unsigned short* Ag1 = A + (bm + rA0 + 16) * K + gs1 * 8;
  const unsigned short* Bg0 = Bt + (bn + rA0) * K + gs0 * 8;
  const unsigned short* Bg1 = Bt + (bn + rA0 + 16) * K + gs1 * 8;
  unsigned short* lA0 = &As[(wave * 32) * 32];
  unsigned short* lA1 = &As[(wave * 32 + 16) * 32];
  unsigned short* lB0 = &Bs[(wave * 32) * 32];
  unsigned short* lB1 = &Bs[(wave * 32 + 16) * 32];
  for (int k0 = 0; k0 < K; k0 += 32) {
    __syncthreads();                 // previous tile fully consumed
    gload16(Ag0 + k0, lA0);
    gload16(Ag1 + k0, lA1);
    gload16(Bg0 + k0, lB0);
    gload16(Bg1 + k0, lB1);
    __syncthreads();                 // drains vmcnt -> tile ready
    bf16x8 af[4], bfr[4];
#pragma unroll
    for (int m = 0; m < 4; ++m) {
      int row = wm + m * 16 + lr;
      af[m] = *(const bf16x8*)((const char*)As + row * 64 + ((lkg ^ ((row >> 1) & 3)) << 4));
    }
#pragma unroll
    for (int n = 0; n < 4; ++n) {
      int row = wn + n * 16 + lr;
      bfr[n] = *(const bf16x8*)((const char*)Bs + row * 64 + ((lkg ^ ((row >> 1) & 3)) << 4));
    }
#pragma unroll
    for (int m = 0; m < 4; ++m)
#pragma unroll
      for (int n = 0; n < 4; ++n) acc[m][n] = MFMA16(af[m], bfr[n], acc[m][n]);
  }
#pragma unroll
  for (int m = 0; m < 4; ++m)
#pragma unroll
    for (int n = 0; n < 4; ++n) {
      long r0 = bm + wm + m * 16 + lkg * 4;
      long c = bn + wn + n * 16 + lr;
#pragma unroll
      for (int r = 0; r < 4; ++r) {
        if (OUTMODE == 0) ((float*)Cout)[(r0 + r) * N + c] = acc[m][n][r];
        else ((unsigned short*)Cout)[(r0 + r) * N + c] = f2bf(acc[m][n][r]);
      }
    }
}

// ---------------------------------------------------------------- rope apply
__global__ __launch_bounds__(256) void rope_kernel(
    const float* __restrict__ in, unsigned short* __restrict__ out,
    const float* __restrict__ cosT, const float* __restrict__ sinT) {
  long row = blockIdx.x;
  int s = (int)(row & (SEQ - 1));
  const float* ir = in + row * HIDN;
  unsigned short* orow = out + row * HIDN;
#pragma unroll
  for (int i = 0; i < 4; ++i) {
    int idx = threadIdx.x + i * 256;
    int h = idx >> 6, d = idx & 63;
    float x1 = ir[h * HD + d], x2 = ir[h * HD + d + 64];
    float c = cosT[s * 64 + d], sn = sinT[s * 64 + d];
    orow[h * HD + d]      = f2bf(x1 * c - x2 * sn);
    orow[h * HD + d + 64] = f2bf(x2 * c + x1 * sn);
  }
}

// ---------------------------------------------------------------- flash attention
// K: linear [64][128] via global_load_lds + source slot^row swizzle.
// V^T: linear [128][64] + XOR-swizzle ((d&7)^((d>>3)&7))<<4 on byte offset.
__global__ __launch_bounds__(256) void flash_attn_kernel(
    const unsigned short* __restrict__ Q, const unsigned short* __restrict__ Kb,
    const unsigned short* __restrict__ Vb, unsigned short* __restrict__ O) {
  __shared__ unsigned short Ks[64 * 128];
  __shared__ unsigned short VtL[128 * 64];
  __shared__ unsigned short Ps[4][16][72];
  const int qt = blockIdx.x, h = blockIdx.y, b = blockIdx.z;
  const int tid = threadIdx.x, wave = tid >> 6, lane = tid & 63;
  const int lr = lane & 15, lkg = lane >> 4, lk = lkg * 8;
  const float scale = 0.08838834764831845f;  // 1/sqrt(128)
  const long rowbase = (long)b * SEQ;
  const int qrow0 = qt * 64 + wave * 16;
  bf16x8 aq[4];
#pragma unroll
  for (int ks = 0; ks < 4; ++ks)
    aq[ks] = *(const bf16x8*)(Q + (rowbase + qrow0 + lr) * HIDN + h * HD + ks * 32 + lk);
  // K staging geometry: wave w instr j covers rows [w*16+j*4, +4)
  const int krow = wave * 16 + (lane >> 4);        // +4 per j
  const int kslot0 = (lane & 15) ^ (krow & 15);    // (krow+4)&15 etc. below
  f32x4 acc[8] = {};
  float m_[4] = {-3.0e38f, -3.0e38f, -3.0e38f, -3.0e38f};
  float l_[4] = {0.f, 0.f, 0.f, 0.f};
  char* vb8 = (char*)VtL;
  for (int kv0 = 0; kv0 < SEQ; kv0 += 64) {
    // ---- stage K via global_load_lds (async) ----
#pragma unroll
    for (int j = 0; j < 4; ++j) {
      int rl = krow + j * 4;
      int slot = (lane & 15) ^ (rl & 15);
      gload16(Kb + (rowbase + kv0 + rl) * HIDN + h * HD + slot * 8,
              &Ks[(wave * 16 + j * 4) * 128]);
    }
    // ---- stage V^T (register path, swizzled scalar writes) ----
#pragma unroll
    for (int i = 0; i < 4; ++i) {
      int c = tid + 256 * i;
      int kr = c >> 4, ko8 = (c & 15) * 8;
      int4 vv = *(const int4*)(Vb + (rowbase + kv0 + kr) * HIDN + h * HD + ko8);
      const unsigned short* pv = (const unsigned short*)&vv;
      int cl7 = c & 7;
#pragma unroll
      for (int j = 0; j < 8; ++j) {
        int d = ko8 + j;
        *(unsigned short*)(vb8 + d * 128 + ((kr * 2) ^ ((j ^ cl7) << 4))) = pv[j];
      }
    }
    __syncthreads();   // drains vmcnt (K ready) + V writes visible
    // ---- scores: 16x64 per wave ----
    f32x4 sa[4] = {};
#pragma unroll
    for (int n = 0; n < 4; ++n) {
      int row = n * 16 + lr;
#pragma unroll
      for (int ks = 0; ks < 4; ++ks) {
        bf16x8 bk = *(const bf16x8*)((const char*)Ks + row * 256 + (((ks * 4 + lkg) ^ (row & 15)) << 4));
        sa[n] = MFMA16(aq[ks], bk, sa[n]);
      }
    }
#pragma unroll
    for (int n = 0; n < 4; ++n)
#pragma unroll
      for (int r = 0; r < 4; ++r) sa[n][r] *= scale;
    // ---- online softmax per q row ----
#pragma unroll
    for (int r = 0; r < 4; ++r) {
      float mx = fmaxf(fmaxf(sa[0][r], sa[1][r]), fmaxf(sa[2][r], sa[3][r]));
#pragma unroll
      for (int off = 1; off < 16; off <<= 1) mx = fmaxf(mx, __shfl_xor(mx, off));
      float mnew = fmaxf(m_[r], mx);
      float corr = __expf(m_[r] - mnew);
      float psum = 0.f;
#pragma unroll
      for (int n = 0; n < 4; ++n) {
        float p = __expf(sa[n][r] - mnew);
        sa[n][r] = p;
        psum += p;
      }
#pragma unroll
      for (int off = 1; off < 16; off <<= 1) psum += __shfl_xor(psum, off);
      l_[r] = l_[r] * corr + psum;
      m_[r] = mnew;
#pragma unroll
      for (int df = 0; df < 8; ++df) acc[df][r] *= corr;
    }
#pragma unroll
    for (int r = 0; r < 4; ++r)
#pragma unroll
      for (int n = 0; n < 4; ++n) Ps[wave][lkg * 4 + r][n * 16 + lr] = f2bf(sa[n][r]);
    __syncthreads();
    // ---- PV ----
    bf16x8 pa0 = *(const bf16x8*)&Ps[wave][lr][lk];
    bf16x8 pa1 = *(const bf16x8*)&Ps[wave][lr][32 + lk];
#pragma unroll
    for (int df = 0; df < 8; ++df) {
      int row = df * 16 + lr;
      int sw = ((row & 7) ^ ((row >> 3) & 7)) << 4;
      bf16x8 bv0 = *(const bf16x8*)(vb8 + row * 128 + ((lkg * 16) ^ sw));
      bf16x8 bv1 = *(const bf16x8*)(vb8 + row * 128 + ((64 + lkg * 16) ^ sw));
      acc[df] = MFMA16(pa0, bv0, acc[df]);
      acc[df] = MFMA16(pa1, bv1, acc[df]);
    }
    __syncthreads();
  }
#pragma unroll
  for (int r = 0; r < 4; ++r) {
    float invl = 1.0f / l_[r];
    long orow = rowbase + qrow0 + lkg * 4 + r;
#pragma unroll
    for (int df = 0; df < 8; ++df)
      O[orow * HIDN + h * HD + df * 16 + lr] = f2bf(acc[df][r] * invl);
  }
}

// ---------------------------------------------------------------- elementwise
__global__ __launch_bounds__(256) void add_kernel(
    const float* __restrict__ a, const float* __restrict__ b, float* __restrict__ out) {
  long i = ((long)blockIdx.x * 256 + threadIdx.x) * 4;
  float4 va = *(const float4*)(a + i);
  float4 vb = *(const float4*)(b + i);
  float4 o; o.x = va.x + vb.x; o.y = va.y + vb.y; o.z = va.z + vb.z; o.w = va.w + vb.w;
  *(float4*)(out + i) = o;
}

__global__ __launch_bounds__(256) void add_inplace_kernel(
    float* __restrict__ out, const float* __restrict__ a) {
  long i = ((long)blockIdx.x * 256 + threadIdx.x) * 4;
  float4 va = *(const float4*)(a + i);
  float4 vo = *(const float4*)(out + i);
  vo.x += va.x; vo.y += va.y; vo.z += va.z; vo.w += va.w;
  *(float4*)(out + i) = vo;
}

__global__ __launch_bounds__(256) void silu_mul_kernel(
    const float* __restrict__ g1, const float* __restrict__ g3, unsigned short* __restrict__ out) {
  long i = ((long)blockIdx.x * 256 + threadIdx.x) * 4;
  float4 a = *(const float4*)(g1 + i);
  float4 b = *(const float4*)(g3 + i);
  ushort4 o;
  o.x = f2bf(a.x / (1.f + __expf(-a.x)) * b.x);
  o.y = f2bf(a.y / (1.f + __expf(-a.y)) * b.y);
  o.z = f2bf(a.z / (1.f + __expf(-a.z)) * b.z);
  o.w = f2bf(a.w / (1.f + __expf(-a.w)) * b.w);
  *(ushort4*)(out + i) = o;
}

// ---------------------------------------------------------------- launcher
extern "C" void kernel_launch(void* const* d_in, const int* in_sizes, int n_in,
                              void* d_out, int out_size, void* d_ws, size_t ws_size,
                              hipStream_t stream) {
  const float* hidden = (const float*)d_in[0];
  const float* W[7] = {(const float*)d_in[1], (const float*)d_in[2], (const float*)d_in[3],
                       (const float*)d_in[4], (const float*)d_in[5], (const float*)d_in[6],
                       (const float*)d_in[7]};  // Wq,Wk,Wv,Wo,w1,w2,w3
  const float* ln1 = (const float*)d_in[8];
  const float* ln2 = (const float*)d_in[9];
  float* out = (float*)d_out;

  char* ws = (char*)d_ws;
  size_t off = 0;
  auto alloc = [&](size_t bytes) -> void* {
    void* p = ws + off;
    off += (bytes + 255) & ~(size_t)255;
    return p;
  };
  unsigned short* wT[7];
  for (int i = 0; i < 7; ++i) wT[i] = (unsigned short*)alloc((size_t)HIDN * HIDN * 2);
  unsigned short* xb   = (unsigned short*)alloc((size_t)NROWS * HIDN * 2);
  unsigned short* qb   = (unsigned short*)alloc((size_t)NROWS * HIDN * 2);
  unsigned short* kb   = (unsigned short*)alloc((size_t)NROWS * HIDN * 2);
  unsigned short* vb   = (unsigned short*)alloc((size_t)NROWS * HIDN * 2);
  unsigned short* ctxb = (unsigned short*)alloc((size_t)NROWS * HIDN * 2);
  float* tmp0 = (float*)alloc((size_t)NROWS * HIDN * 4);
  float* tmp1 = (float*)alloc((size_t)NROWS * HIDN * 4);
  float* cosT = (float*)alloc((size_t)SEQ * 64 * 4);
  float* sinT = (float*)alloc((size_t)SEQ * 64 * 4);
  if (off > ws_size) return;

  dim3 tgrid(HIDN / 32, HIDN / 32);
  for (int i = 0; i < 7; ++i)
    transpose_cvt_kernel<<<tgrid, 256, 0, stream>>>(W[i], wT[i]);
  rope_table_kernel<<<SEQ, 64, 0, stream>>>(cosT, sinT);

  rmsnorm_kernel<<<NROWS, 256, 0, stream>>>(hidden, ln1, xb);

  dim3 ggrid(HIDN / 128, NROWS / 128);
  gemm_kernel<0><<<ggrid, 256, 0, stream>>>(xb, wT[0], tmp0, NROWS, HIDN, HIDN);  // q pre-rope
  gemm_kernel<0><<<ggrid, 256, 0, stream>>>(xb, wT[1], tmp1, NROWS, HIDN, HIDN);  // k pre-rope
  rope_kernel<<<NROWS, 256, 0, stream>>>(tmp0, qb, cosT, sinT);
  rope_kernel<<<NROWS, 256, 0, stream>>>(tmp1, kb, cosT, sinT);
  gemm_kernel<1><<<ggrid, 256, 0, stream>>>(xb, wT[2], vb, NROWS, HIDN, HIDN);    // v

  flash_attn_kernel<<<dim3(SEQ / 64, NHEAD, BATCH), 256, 0, stream>>>(qb, kb, vb, ctxb);

  gemm_kernel<0><<<ggrid, 256, 0, stream>>>(ctxb, wT[3], tmp0, NROWS, HIDN, HIDN);  // attn_out
  add_kernel<<<NROWS * HIDN / 1024, 256, 0, stream>>>(hidden, tmp0, out);           // h

  rmsnorm_kernel<<<NROWS, 256, 0, stream>>>(out, ln2, xb);                          // y
  gemm_kernel<0><<<ggrid, 256, 0, stream>>>(xb, wT[4], tmp0, NROWS, HIDN, HIDN);    // g1
  gemm_kernel<0><<<ggrid, 256, 0, stream>>>(xb, wT[6], tmp1, NROWS, HIDN, HIDN);    // g3
  silu_mul_kernel<<<NROWS * HIDN / 1024, 256, 0, stream>>>(tmp0, tmp1, qb);         // silu(g1)*g3
  gemm_kernel<0><<<ggrid, 256, 0, stream>>>(qb, wT[5], tmp0, NROWS, HIDN, HIDN);    // mlp
  add_inplace_kernel<<<NROWS * HIDN / 1024, 256, 0, stream>>>(out, tmp0);           // out = h+mlp
}

// Round 3
// 566.193 us; speedup vs baseline: 1.6631x; 1.3326x over previous
//
#include <hip/hip_runtime.h>

#define HIDN 2048
#define NHEAD 16
#define HD 128
#define SEQ 2048
#define BATCH 2
#define NROWS (BATCH*SEQ)   // 4096

typedef __bf16 bf16_t;
typedef bf16_t bf16x8 __attribute__((ext_vector_type(8)));
typedef float f32x4 __attribute__((ext_vector_type(4)));

#define AS1 __attribute__((address_space(1)))
#define AS3 __attribute__((address_space(3)))

__device__ __forceinline__ unsigned short f2bf(float x) {
  union { bf16_t b; unsigned short u; } cv; cv.b = (bf16_t)x; return cv.u;
}

#define MFMA16(a,b,c) __builtin_amdgcn_mfma_f32_16x16x32_bf16((a),(b),(c),0,0,0)

__device__ __forceinline__ void gload16(const void* g, void* l) {
  __builtin_amdgcn_global_load_lds((const AS1 void*)g, (AS3 void*)l, 16, 0, 0);
}

// ---------------------------------------------------------------- transpose+cvt
// W [2048][2048] f32 row-major -> Wt rows per TMODE mapping (bf16).
// TMODE 0: dst=n. TMODE 1 (qk rope-interleave): d=n&127 -> f=((d&63)<<1)|(d>>6).
// TMODE 2 (gate interleave): dst=(n>>4)*32 + half*16 + (n&15).
template <int TMODE>
__global__ __launch_bounds__(256) void transpose_cvt_kernel(
    const float* __restrict__ W, unsigned short* __restrict__ Wt, int half) {
  __shared__ float t[32][33];
  int bn = blockIdx.x * 32;
  int bk = blockIdx.y * 32;
  int tx = threadIdx.x & 31, ty = threadIdx.x >> 5;
#pragma unroll
  for (int i = 0; i < 4; ++i) {
    int k = bk + ty + i * 8;
    t[ty + i * 8][tx] = W[(long)k * HIDN + bn + tx];
  }
  __syncthreads();
#pragma unroll
  for (int i = 0; i < 4; ++i) {
    int n = bn + ty + i * 8;
    int dst;
    if (TMODE == 0) dst = n;
    else if (TMODE == 1) { int d = n & 127; dst = (n & ~127) | ((d & 63) << 1) | (d >> 6); }
    else dst = (n >> 4) * 32 + half * 16 + (n & 15);
    Wt[(long)dst * HIDN + bk + tx] = f2bf(t[tx][ty + i * 8]);
  }
}

// ---------------------------------------------------------------- rope tables
__global__ void rope_table_kernel(float* __restrict__ cosT, float* __restrict__ sinT) {
  int s = blockIdx.x, d = threadIdx.x;
  float invf = powf(10000.0f, (-2.0f * (float)d) / 128.0f);
  float ang = (float)s * invf;
  cosT[s * 64 + d] = cosf(ang);
  sinT[s * 64 + d] = sinf(ang);
}

// ---------------------------------------------------------------- rmsnorm
__global__ __launch_bounds__(256) void rmsnorm_kernel(
    const float* __restrict__ x, const float* __restrict__ w, unsigned short* __restrict__ out) {
  long row = blockIdx.x;
  const float* xr = x + row * HIDN;
  int c0 = threadIdx.x * 4;
  float4 v0 = *(const float4*)(xr + c0);
  float4 v1 = *(const float4*)(xr + 1024 + c0);
  float s = v0.x*v0.x + v0.y*v0.y + v0.z*v0.z + v0.w*v0.w
          + v1.x*v1.x + v1.y*v1.y + v1.z*v1.z + v1.w*v1.w;
#pragma unroll
  for (int off = 1; off < 64; off <<= 1) s += __shfl_xor(s, off);
  __shared__ float red[4];
  if ((threadIdx.x & 63) == 0) red[threadIdx.x >> 6] = s;
  __syncthreads();
  float tot = red[0] + red[1] + red[2] + red[3];
  float r = 1.0f / sqrtf(tot * (1.0f / (float)HIDN) + 1e-6f);
  float4 w0 = *(const float4*)(w + c0);
  float4 w1 = *(const float4*)(w + 1024 + c0);
  ushort4 o0, o1;
  o0.x = f2bf(v0.x * r * w0.x); o0.y = f2bf(v0.y * r * w0.y);
  o0.z = f2bf(v0.z * r * w0.z); o0.w = f2bf(v0.w * r * w0.w);
  o1.x = f2bf(v1.x * r * w1.x); o1.y = f2bf(v1.y * r * w1.y);
  o1.z = f2bf(v1.z * r * w1.z); o1.w = f2bf(v1.w * r * w1.w);
  *(ushort4*)(out + row * HIDN + c0) = o0;
  *(ushort4*)(out + row * HIDN + 1024 + c0) = o1;
}

// ---------------------------------------------------------------- GEMM (m97 structure, fused epilogues)
// C = A[M,2048] x Bt[N,2048]^T.
// MODE 0 QKV (N=6144): cols>>11 route to q/k/v; q,k get fused rope (weights pre-interleaved).
// MODE 1 GATE (N=4096): w1/w3 interleaved 16-col groups -> silu(g1)*g3 -> bf16 p0.
// MODE 2 ADDH: f32 p0 = p1 + acc.   MODE 3 ADDOUT: f32 p0 += acc.
template <int MODE>
__global__ __launch_bounds__(256) void gemm_kernel(
    const unsigned short* __restrict__ A, const unsigned short* __restrict__ Bt, int N,
    void* __restrict__ p0, const void* __restrict__ p1, void* __restrict__ p2,
    const float* __restrict__ cosT, const float* __restrict__ sinT) {
  __shared__ unsigned short As[128 * 32];
  __shared__ unsigned short Bs[128 * 32];
  const int tid = threadIdx.x;
  const int lane = tid & 63, wave = tid >> 6;
  const int wm = (wave >> 1) * 64, wn = (wave & 1) * 64;
  const int lr = lane & 15, lkg = lane >> 4;
  const long bm = (long)blockIdx.y * 128, bn = (long)blockIdx.x * 128;
  f32x4 acc[4][4] = {};
  const int rA0 = wave * 32 + (lane >> 2);
  const int gs0 = (lane & 3) ^ ((rA0 >> 1) & 3);
  const int gs1 = (lane & 3) ^ (((rA0 + 16) >> 1) & 3);
  const unsigned short* Ag0 = A + (bm + rA0) * HIDN + gs0 * 8;
  const unsigned short* Ag1 = A + (bm + rA0 + 16) * HIDN + gs1 * 8;
  const unsigned short* Bg0 = Bt + (bn + rA0) * HIDN + gs0 * 8;
  const unsigned short* Bg1 = Bt + (bn + rA0 + 16) * HIDN + gs1 * 8;
  unsigned short* lA0 = &As[(wave * 32) * 32];
  unsigned short* lA1 = &As[(wave * 32 + 16) * 32];
  unsigned short* lB0 = &Bs[(wave * 32) * 32];
  unsigned short* lB1 = &Bs[(wave * 32 + 16) * 32];
  for (int k0 = 0; k0 < HIDN; k0 += 32) {
    __syncthreads();
    gload16(Ag0 + k0, lA0);
    gload16(Ag1 + k0, lA1);
    gload16(Bg0 + k0, lB0);
    gload16(Bg1 + k0, lB1);
    __syncthreads();
    bf16x8 af[4], bfr[4];
#pragma unroll
    for (int m = 0; m < 4; ++m) {
      int row = wm + m * 16 + lr;
      af[m] = *(const bf16x8*)((const char*)As + row * 64 + ((lkg ^ ((row >> 1) & 3)) << 4));
    }
#pragma unroll
    for (int n = 0; n < 4; ++n) {
      int row = wn + n * 16 + lr;
      bfr[n] = *(const bf16x8*)((const char*)Bs + row * 64 + ((lkg ^ ((row >> 1) & 3)) << 4));
    }
#pragma unroll
    for (int m = 0; m < 4; ++m)
#pragma unroll
      for (int n = 0; n < 4; ++n) acc[m][n] = MFMA16(af[m], bfr[n], acc[m][n]);
  }
  // ---------------- epilogues ----------------
  if (MODE == 2 || MODE == 3) {
    float* fout = (float*)p0;
    const float* addsrc = (const float*)p1;
#pragma unroll
    for (int m = 0; m < 4; ++m)
#pragma unroll
      for (int n = 0; n < 4; ++n) {
        long r0 = bm + wm + m * 16 + lkg * 4;
        long c = bn + wn + n * 16 + lr;
#pragma unroll
        for (int r = 0; r < 4; ++r) {
          long idx = (r0 + r) * 2048 + c;
          if (MODE == 2) fout[idx] = addsrc[idx] + acc[m][n][r];
          else fout[idx] = fout[idx] + acc[m][n][r];
        }
      }
  } else if (MODE == 1) {
    unsigned short* bout = (unsigned short*)p0;
#pragma unroll
    for (int m = 0; m < 4; ++m)
#pragma unroll
      for (int n = 0; n < 4; n += 2) {
        long r0 = bm + wm + m * 16 + lkg * 4;
        int ggrp = (int)((bn + wn + n * 16) >> 5);
        long c = (long)ggrp * 16 + lr;
#pragma unroll
        for (int r = 0; r < 4; ++r) {
          float x = acc[m][n][r], g = acc[m][n + 1][r];
          float sv = x / (1.0f + __expf(-x)) * g;
          bout[(r0 + r) * 2048 + c] = f2bf(sv);
        }
      }
  } else {  // MODE 0: QKV with fused rope
    int gc0 = (int)bn + wn;                 // block col base + wave offset
    int buf = (gc0 + lr) >> 11;             // uniform per block actually (bn aligned 128)
    unsigned short* dst = (buf == 0) ? (unsigned short*)p0
                        : (buf == 1) ? (unsigned short*)(void*)const_cast<void*>(p1)
                                     : (unsigned short*)p2;
    if (buf == 2) {
#pragma unroll
      for (int m = 0; m < 4; ++m)
#pragma unroll
        for (int n = 0; n < 4; ++n) {
          long r0 = bm + wm + m * 16 + lkg * 4;
          int wc = (gc0 + n * 16 + lr) & 2047;
#pragma unroll
          for (int r = 0; r < 4; ++r) dst[(r0 + r) * 2048 + wc] = f2bf(acc[m][n][r]);
        }
    } else {
#pragma unroll
      for (int m = 0; m < 4; ++m)
#pragma unroll
        for (int n = 0; n < 4; ++n) {
          long r0 = bm + wm + m * 16 + lkg * 4;
          int wc = (gc0 + n * 16 + lr) & 2047;
          int f = wc & 127, hh = wc >> 7;
          int j = f >> 1, odd = f & 1;
          int oc = hh * 128 + (odd ? 64 : 0) + j;
#pragma unroll
          for (int r = 0; r < 4; ++r) {
            long row = r0 + r;
            int s = (int)(row & (SEQ - 1));
            float cv = cosT[s * 64 + j], sn = sinT[s * 64 + j];
            float v = acc[m][n][r];
            float o = __shfl_xor(v, 1);
            float res = odd ? (v * cv + o * sn) : (v * cv - o * sn);
            dst[row * 2048 + oc] = f2bf(res);
          }
        }
    }
  }
}

// ---------------------------------------------------------------- flash attention
// Double-buffered K via global_load_lds (source-swizzled), V reg-staged with
// conflict-free b64 swizzled writes, async prefetch of tile t+1 under compute(t).
__global__ __launch_bounds__(256) void flash_attn_kernel(
    const unsigned short* __restrict__ Q, const unsigned short* __restrict__ Kb,
    const unsigned short* __restrict__ Vb, unsigned short* __restrict__ O) {
  __shared__ unsigned short Ks[2][64 * 128];
  __shared__ unsigned short VtL[128 * 64];
  __shared__ unsigned short Ps[4][16][72];
  const int qt = blockIdx.x, h = blockIdx.y, b = blockIdx.z;
  const int tid = threadIdx.x, wave = tid >> 6, lane = tid & 63;
  const int lr = lane & 15, lkg = lane >> 4, lk = lkg * 8;
  const float scale = 0.08838834764831845f;  // 1/sqrt(128)
  const long rowbase = (long)b * SEQ;
  const int qrow0 = qt * 64 + wave * 16;
  bf16x8 aq[4];
#pragma unroll
  for (int ks = 0; ks < 4; ++ks)
    aq[ks] = *(const bf16x8*)(Q + (rowbase + qrow0 + lr) * HIDN + h * HD + ks * 32 + lk);
  // V staging geometry: thread -> kv-quad kq, d-block db (8 d's)
  const int kq = tid & 15, db = tid >> 4;
  // K staging row-within-group
  const int krl = lane >> 4;
  char* vb8 = (char*)VtL;
  f32x4 acc[8] = {};
  float m_[4] = {-3.0e38f, -3.0e38f, -3.0e38f, -3.0e38f};
  float l_[4] = {0.f, 0.f, 0.f, 0.f};
  ushort4 vreg[2][4];
  // ---- prologue: stage K(0), load V(0) ----
#pragma unroll
  for (int j = 0; j < 4; ++j) {
    int rl = wave * 16 + j * 4 + krl;
    int slot = (lane & 15) ^ (rl & 15);
    gload16(Kb + (rowbase + rl) * HIDN + h * HD + slot * 8,
            &Ks[0][(wave * 16 + j * 4) * 128]);
  }
#pragma unroll
  for (int j = 0; j < 4; ++j)
#pragma unroll
    for (int i = 0; i < 2; ++i)
      vreg[i][j] = *(const ushort4*)(Vb + (rowbase + kq * 4 + j) * HIDN + h * HD + db * 8 + i * 4);

  for (int t = 0; t < SEQ / 64; ++t) {
    asm volatile("s_waitcnt vmcnt(0)" ::: "memory");   // K(t) DMA + V(t) regs landed
    // ---- write V(t) to LDS: 8 x ds_write_b64, conflict-free swizzle ----
#pragma unroll
    for (int i = 0; i < 2; ++i)
#pragma unroll
      for (int dd = 0; dd < 4; ++dd) {
        int d = db * 8 + i * 4 + dd;
        ushort4 w;
        w.x = ((const unsigned short*)&vreg[i][0])[dd];
        w.y = ((const unsigned short*)&vreg[i][1])[dd];
        w.z = ((const unsigned short*)&vreg[i][2])[dd];
        w.w = ((const unsigned short*)&vreg[i][3])[dd];
        *(ushort4*)(vb8 + d * 128 + ((kq * 8) ^ ((d & 7) << 4))) = w;
      }
    asm volatile("s_waitcnt lgkmcnt(0)" ::: "memory"); // own V writes done
    asm volatile("s_barrier" ::: "memory");            // K(t)+V(t) visible to all
    // ---- prefetch tile t+1 (flies under compute) ----
    if (t + 1 < SEQ / 64) {
      const long kvn = (long)(t + 1) * 64;
#pragma unroll
      for (int j = 0; j < 4; ++j) {
        int rl = wave * 16 + j * 4 + krl;
        int slot = (lane & 15) ^ (rl & 15);
        gload16(Kb + (rowbase + kvn + rl) * HIDN + h * HD + slot * 8,
                &Ks[(t + 1) & 1][(wave * 16 + j * 4) * 128]);
      }
#pragma unroll
      for (int j = 0; j < 4; ++j)
#pragma unroll
        for (int i = 0; i < 2; ++i)
          vreg[i][j] = *(const ushort4*)(Vb + (rowbase + kvn + kq * 4 + j) * HIDN + h * HD + db * 8 + i * 4);
    }
    // ---- QK^T from Ks[t&1] ----
    const char* ksb = (const char*)Ks[t & 1];
    f32x4 sa[4] = {};
#pragma unroll
    for (int n = 0; n < 4; ++n) {
      int row = n * 16 + lr;
#pragma unroll
      for (int ks = 0; ks < 4; ++ks) {
        bf16x8 bk = *(const bf16x8*)(ksb + row * 256 + (((ks * 4 + lkg) ^ (row & 15)) << 4));
        sa[n] = MFMA16(aq[ks], bk, sa[n]);
      }
    }
#pragma unroll
    for (int n = 0; n < 4; ++n)
#pragma unroll
      for (int r = 0; r < 4; ++r) sa[n][r] *= scale;
    // ---- online softmax ----
#pragma unroll
    for (int r = 0; r < 4; ++r) {
      float mx = fmaxf(fmaxf(sa[0][r], sa[1][r]), fmaxf(sa[2][r], sa[3][r]));
#pragma unroll
      for (int off = 1; off < 16; off <<= 1) mx = fmaxf(mx, __shfl_xor(mx, off));
      float mnew = fmaxf(m_[r], mx);
      float corr = __expf(m_[r] - mnew);
      float psum = 0.f;
#pragma unroll
      for (int n = 0; n < 4; ++n) {
        float p = __expf(sa[n][r] - mnew);
        sa[n][r] = p;
        psum += p;
      }
#pragma unroll
      for (int off = 1; off < 16; off <<= 1) psum += __shfl_xor(psum, off);
      l_[r] = l_[r] * corr + psum;
      m_[r] = mnew;
#pragma unroll
      for (int df = 0; df < 8; ++df) acc[df][r] *= corr;
    }
#pragma unroll
    for (int r = 0; r < 4; ++r)
#pragma unroll
      for (int n = 0; n < 4; ++n) Ps[wave][lkg * 4 + r][n * 16 + lr] = f2bf(sa[n][r]);
    asm volatile("s_waitcnt lgkmcnt(0)" ::: "memory");
    asm volatile("s_barrier" ::: "memory");
    // ---- PV ----
    bf16x8 pa0 = *(const bf16x8*)&Ps[wave][lr][lk];
    bf16x8 pa1 = *(const bf16x8*)&Ps[wave][lr][32 + lk];
#pragma unroll
    for (int df = 0; df < 8; ++df) {
      int row = df * 16 + lr;
      int sw = (row & 7) << 4;
      bf16x8 bv0 = *(const bf16x8*)(vb8 + row * 128 + ((lkg * 16) ^ sw));
      bf16x8 bv1 = *(const bf16x8*)(vb8 + row * 128 + (((4 + lkg) * 16) ^ sw));
      acc[df] = MFMA16(pa0, bv0, acc[df]);
      acc[df] = MFMA16(pa1, bv1, acc[df]);
    }
    asm volatile("s_barrier" ::: "memory");            // protect VtL/Ps before next overwrite
  }
#pragma unroll
  for (int r = 0; r < 4; ++r) {
    float invl = 1.0f / l_[r];
    long orow = rowbase + qrow0 + lkg * 4 + r;
#pragma unroll
    for (int df = 0; df < 8; ++df)
      O[orow * HIDN + h * HD + df * 16 + lr] = f2bf(acc[df][r] * invl);
  }
}

// ---------------------------------------------------------------- launcher
extern "C" void kernel_launch(void* const* d_in, const int* in_sizes, int n_in,
                              void* d_out, int out_size, void* d_ws, size_t ws_size,
                              hipStream_t stream) {
  const float* hidden = (const float*)d_in[0];
  const float* Wq = (const float*)d_in[1];
  const float* Wk = (const float*)d_in[2];
  const float* Wv = (const float*)d_in[3];
  const float* Wo = (const float*)d_in[4];
  const float* w1 = (const float*)d_in[5];
  const float* w2 = (const float*)d_in[6];
  const float* w3 = (const float*)d_in[7];
  const float* ln1 = (const float*)d_in[8];
  const float* ln2 = (const float*)d_in[9];
  float* out = (float*)d_out;

  char* ws = (char*)d_ws;
  size_t off = 0;
  auto alloc = [&](size_t bytes) -> void* {
    void* p = ws + off;
    off += (bytes + 255) & ~(size_t)255;
    return p;
  };
  // weight block: rows [q:2048 | k:2048 | v:2048 | o:2048 | gate:4096 | down:2048]
  unsigned short* wblk = (unsigned short*)alloc((size_t)(2048L * 6 + 2048) * HIDN * 2);
  unsigned short* wQ = wblk;
  unsigned short* wK = wblk + (size_t)2048 * HIDN;
  unsigned short* wV = wblk + (size_t)4096 * HIDN;
  unsigned short* wO = wblk + (size_t)6144 * HIDN;
  unsigned short* wG = wblk + (size_t)8192 * HIDN;   // 4096 rows (w1/w3 interleaved)
  unsigned short* wD = wblk + (size_t)12288 * HIDN;
  unsigned short* xb   = (unsigned short*)alloc((size_t)NROWS * HIDN * 2);
  unsigned short* qb   = (unsigned short*)alloc((size_t)NROWS * HIDN * 2);
  unsigned short* kb   = (unsigned short*)alloc((size_t)NROWS * HIDN * 2);
  unsigned short* vb   = (unsigned short*)alloc((size_t)NROWS * HIDN * 2);
  unsigned short* ctxb = (unsigned short*)alloc((size_t)NROWS * HIDN * 2);
  float* cosT = (float*)alloc((size_t)SEQ * 64 * 4);
  float* sinT = (float*)alloc((size_t)SEQ * 64 * 4);
  if (off > ws_size) return;

  dim3 tgrid(HIDN / 32, HIDN / 32);
  transpose_cvt_kernel<1><<<tgrid, 256, 0, stream>>>(Wq, wQ, 0);
  transpose_cvt_kernel<1><<<tgrid, 256, 0, stream>>>(Wk, wK, 0);
  transpose_cvt_kernel<0><<<tgrid, 256, 0, stream>>>(Wv, wV, 0);
  transpose_cvt_kernel<0><<<tgrid, 256, 0, stream>>>(Wo, wO, 0);
  transpose_cvt_kernel<2><<<tgrid, 256, 0, stream>>>(w1, wG, 0);
  transpose_cvt_kernel<2><<<tgrid, 256, 0, stream>>>(w3, wG, 1);
  transpose_cvt_kernel<0><<<tgrid, 256, 0, stream>>>(w2, wD, 0);
  rope_table_kernel<<<SEQ, 64, 0, stream>>>(cosT, sinT);

  rmsnorm_kernel<<<NROWS, 256, 0, stream>>>(hidden, ln1, xb);

  // QKV fused (N=6144) with rope epilogue -> qb,kb,vb
  gemm_kernel<0><<<dim3(6144 / 128, NROWS / 128), 256, 0, stream>>>(
      xb, wQ, 6144, qb, kb, vb, cosT, sinT);

  flash_attn_kernel<<<dim3(SEQ / 64, NHEAD, BATCH), 256, 0, stream>>>(qb, kb, vb, ctxb);

  // attn_out + residual -> out (f32)
  gemm_kernel<2><<<dim3(2048 / 128, NROWS / 128), 256, 0, stream>>>(
      ctxb, wO, 2048, out, hidden, nullptr, nullptr, nullptr);

  rmsnorm_kernel<<<NROWS, 256, 0, stream>>>(out, ln2, xb);

  // gate: silu(y@w1)*(y@w3) fused (N=4096 interleaved) -> qb (reused as gs)
  gemm_kernel<1><<<dim3(4096 / 128, NROWS / 128), 256, 0, stream>>>(
      xb, wG, 4096, qb, nullptr, nullptr, nullptr, nullptr);

  // down: out += gs @ w2
  gemm_kernel<3><<<dim3(2048 / 128, NROWS / 128), 256, 0, stream>>>(
      qb, wD, 2048, out, nullptr, nullptr, nullptr, nullptr);
}

// Round 4
// 534.588 us; speedup vs baseline: 1.7614x; 1.0591x over previous
//
#include <hip/hip_runtime.h>

#define HIDN 2048
#define NHEAD 16
#define HD 128
#define SEQ 2048
#define BATCH 2
#define NROWS (BATCH*SEQ)   // 4096

typedef __bf16 bf16_t;
typedef bf16_t bf16x8 __attribute__((ext_vector_type(8)));
typedef float f32x4 __attribute__((ext_vector_type(4)));

#define AS1 __attribute__((address_space(1)))
#define AS3 __attribute__((address_space(3)))

__device__ __forceinline__ unsigned short f2bf(float x) {
  union { bf16_t b; unsigned short u; } cv; cv.b = (bf16_t)x; return cv.u;
}

#define MFMA16(a,b,c) __builtin_amdgcn_mfma_f32_16x16x32_bf16((a),(b),(c),0,0,0)

__device__ __forceinline__ void gload16(const void* g, void* l) {
  __builtin_amdgcn_global_load_lds((const AS1 void*)g, (AS3 void*)l, 16, 0, 0);
}

// ---------------------------------------------------------------- transpose+cvt
// TMODE 0: dst=n. TMODE 1 (qk rope-interleave). TMODE 2 (gate interleave).
template <int TMODE>
__global__ __launch_bounds__(256) void transpose_cvt_kernel(
    const float* __restrict__ W, unsigned short* __restrict__ Wt, int half) {
  __shared__ float t[32][33];
  int bn = blockIdx.x * 32;
  int bk = blockIdx.y * 32;
  int tx = threadIdx.x & 31, ty = threadIdx.x >> 5;
#pragma unroll
  for (int i = 0; i < 4; ++i) {
    int k = bk + ty + i * 8;
    t[ty + i * 8][tx] = W[(long)k * HIDN + bn + tx];
  }
  __syncthreads();
#pragma unroll
  for (int i = 0; i < 4; ++i) {
    int n = bn + ty + i * 8;
    int dst;
    if (TMODE == 0) dst = n;
    else if (TMODE == 1) { int d = n & 127; dst = (n & ~127) | ((d & 63) << 1) | (d >> 6); }
    else dst = (n >> 4) * 32 + half * 16 + (n & 15);
    Wt[(long)dst * HIDN + bk + tx] = f2bf(t[tx][ty + i * 8]);
  }
}

// ---------------------------------------------------------------- rope tables
__global__ void rope_table_kernel(float* __restrict__ cosT, float* __restrict__ sinT) {
  int s = blockIdx.x, d = threadIdx.x;
  float invf = powf(10000.0f, (-2.0f * (float)d) / 128.0f);
  float ang = (float)s * invf;
  cosT[s * 64 + d] = cosf(ang);
  sinT[s * 64 + d] = sinf(ang);
}

// ---------------------------------------------------------------- rmsnorm
__global__ __launch_bounds__(256) void rmsnorm_kernel(
    const float* __restrict__ x, const float* __restrict__ w, unsigned short* __restrict__ out) {
  long row = blockIdx.x;
  const float* xr = x + row * HIDN;
  int c0 = threadIdx.x * 4;
  float4 v0 = *(const float4*)(xr + c0);
  float4 v1 = *(const float4*)(xr + 1024 + c0);
  float s = v0.x*v0.x + v0.y*v0.y + v0.z*v0.z + v0.w*v0.w
          + v1.x*v1.x + v1.y*v1.y + v1.z*v1.z + v1.w*v1.w;
#pragma unroll
  for (int off = 1; off < 64; off <<= 1) s += __shfl_xor(s, off);
  __shared__ float red[4];
  if ((threadIdx.x & 63) == 0) red[threadIdx.x >> 6] = s;
  __syncthreads();
  float tot = red[0] + red[1] + red[2] + red[3];
  float r = 1.0f / sqrtf(tot * (1.0f / (float)HIDN) + 1e-6f);
  float4 w0 = *(const float4*)(w + c0);
  float4 w1 = *(const float4*)(w + 1024 + c0);
  ushort4 o0, o1;
  o0.x = f2bf(v0.x * r * w0.x); o0.y = f2bf(v0.y * r * w0.y);
  o0.z = f2bf(v0.z * r * w0.z); o0.w = f2bf(v0.w * r * w0.w);
  o1.x = f2bf(v1.x * r * w1.x); o1.y = f2bf(v1.y * r * w1.y);
  o1.z = f2bf(v1.z * r * w1.z); o1.w = f2bf(v1.w * r * w1.w);
  *(ushort4*)(out + row * HIDN + c0) = o0;
  *(ushort4*)(out + row * HIDN + 1024 + c0) = o1;
}

// ---------------------------------------------------------------- GEMM 256x256 (deep pipeline)
// C = A[M,2048] x Bt[N,2048]^T. 512 thr / 8 waves (2Mx4N), BK=64, dbuf LDS 128 KiB.
// Counted vmcnt (never 0 in-loop), slot^row&7 LDS swizzle, setprio MFMA clusters.
// MODE 0: QKV+rope -> p0/p1/p2 bf16. MODE 1: gate silu-mul -> p0 bf16.
template <int MODE>
__global__ __launch_bounds__(512, 2) void gemm256_kernel(
    const unsigned short* __restrict__ A, const unsigned short* __restrict__ Bt,
    int nbx,
    void* __restrict__ p0, void* __restrict__ p1, void* __restrict__ p2,
    const float* __restrict__ cosT, const float* __restrict__ sinT) {
  __shared__ unsigned short L[65536];   // [2 dbuf][ A:16384 | B:16384 ] shorts
  const int tid = threadIdx.x;
  const int wave = tid >> 6, lane = tid & 63;
  const int lr = lane & 15, lkg = lane >> 4;
  const int wr = wave >> 2, wc = wave & 3;
  // XCD-bijective block swizzle (nwg % 8 == 0 guaranteed by launcher)
  const int nwg = (int)gridDim.x;
  const int bid = (int)blockIdx.x;
  const int wg = (bid & 7) * (nwg >> 3) + (bid >> 3);
  const int bx = wg % nbx, by = wg / nbx;
  const long bm = (long)by * 256, bn = (long)bx * 256;
  // staging geometry: wave covers rows j*64 + wave*8 + (lane>>3), slot (lane&7)^(lane>>3)
  const int srow = wave * 8 + (lane >> 3);
  const int sslot = (lane & 7) ^ (lane >> 3);
  const unsigned short* Ag = A + (bm + srow) * HIDN + sslot * 8;
  const unsigned short* Bg = Bt + (bn + srow) * HIDN + sslot * 8;
  f32x4 acc[8][4] = {};

#define STAGE256(kt2)                                                            \
  {                                                                              \
    const long ko = (long)(kt2) * 64;                                            \
    unsigned short* Ld = &L[((kt2) & 1) * 32768];                                \
    _Pragma("unroll")                                                            \
    for (int j = 0; j < 4; ++j) {                                                \
      gload16(Ag + ko + (long)j * 64 * HIDN, &Ld[(j * 64 + wave * 8) * 64]);     \
      gload16(Bg + ko + (long)j * 64 * HIDN, &Ld[16384 + (j * 64 + wave * 8) * 64]); \
    }                                                                            \
  }

  STAGE256(0);
  STAGE256(1);
  asm volatile("s_waitcnt vmcnt(8)" ::: "memory");
  __builtin_amdgcn_sched_barrier(0);
  __builtin_amdgcn_s_barrier();

  for (int kt = 0; kt < 32; ++kt) {
    const int d = kt & 1;
    const char* Lb = (const char*)L + d * 65536;
    // B fragments (shared by all 4 quadrants)
    bf16x8 bfr[4][2];
#pragma unroll
    for (int n = 0; n < 4; ++n) {
      int row = wc * 64 + n * 16 + lr;
      int x7 = row & 7;
#pragma unroll
      for (int ks = 0; ks < 2; ++ks) {
        int s = ks * 4 + lkg;
        bfr[n][ks] = *(const bf16x8*)(Lb + 32768 + row * 128 + ((s ^ x7) << 4));
      }
    }
    // 4 quadrant phases: 2 m-frags x 4 n-frags x 2 k-steps = 16 MFMA each
#pragma unroll
    for (int q = 0; q < 4; ++q) {
      bf16x8 af[2][2];
#pragma unroll
      for (int mm = 0; mm < 2; ++mm) {
        int row = wr * 128 + (q * 2 + mm) * 16 + lr;
        int x7 = row & 7;
#pragma unroll
        for (int ks = 0; ks < 2; ++ks) {
          int s = ks * 4 + lkg;
          af[mm][ks] = *(const bf16x8*)(Lb + row * 128 + ((s ^ x7) << 4));
        }
      }
      __builtin_amdgcn_s_setprio(1);
#pragma unroll
      for (int mm = 0; mm < 2; ++mm)
#pragma unroll
        for (int n = 0; n < 4; ++n) {
          acc[q * 2 + mm][n] = MFMA16(af[mm][0], bfr[n][0], acc[q * 2 + mm][n]);
          acc[q * 2 + mm][n] = MFMA16(af[mm][1], bfr[n][1], acc[q * 2 + mm][n]);
        }
      __builtin_amdgcn_s_setprio(0);
    }
    if (kt == 31) break;
    asm volatile("s_waitcnt lgkmcnt(0)" ::: "memory");   // own ds_reads of buf[d] done
    __builtin_amdgcn_sched_barrier(0);
    __builtin_amdgcn_s_barrier();                         // all waves done reading buf[d]
    if (kt < 30) {
      STAGE256(kt + 2);                                   // refill buf[d] (T kt+2)
      asm volatile("s_waitcnt vmcnt(8)" ::: "memory");    // T(kt+1) landed; T(kt+2) flying
    } else {
      asm volatile("s_waitcnt vmcnt(0)" ::: "memory");    // tail: T31 landed
    }
    __builtin_amdgcn_sched_barrier(0);
    __builtin_amdgcn_s_barrier();                         // buf[d^1] ready for everyone
  }
#undef STAGE256

  // ---------------- epilogues ----------------
  const int gc0 = (int)bn + wc * 64;
  if (MODE == 1) {
    unsigned short* bout = (unsigned short*)p0;
#pragma unroll
    for (int m = 0; m < 8; ++m) {
      long r0 = bm + wr * 128 + m * 16 + lkg * 4;
#pragma unroll
      for (int n = 0; n < 4; n += 2) {
        int ggrp = (gc0 + n * 16) >> 5;
        long c = (long)ggrp * 16 + lr;
#pragma unroll
        for (int r = 0; r < 4; ++r) {
          float x = acc[m][n][r], g = acc[m][n + 1][r];
          float sv = x / (1.0f + __expf(-x)) * g;
          bout[(r0 + r) * 2048 + c] = f2bf(sv);
        }
      }
    }
  } else {  // MODE 0: QKV with fused rope on q,k
    int bufid = gc0 >> 11;
    unsigned short* dst = (bufid == 0) ? (unsigned short*)p0
                        : (bufid == 1) ? (unsigned short*)p1
                                       : (unsigned short*)p2;
    if (bufid == 2) {
#pragma unroll
      for (int m = 0; m < 8; ++m) {
        long r0 = bm + wr * 128 + m * 16 + lkg * 4;
#pragma unroll
        for (int n = 0; n < 4; ++n) {
          int wcol = (gc0 + n * 16 + lr) & 2047;
#pragma unroll
          for (int r = 0; r < 4; ++r) dst[(r0 + r) * 2048 + wcol] = f2bf(acc[m][n][r]);
        }
      }
    } else {
#pragma unroll
      for (int m = 0; m < 8; ++m) {
        long r0 = bm + wr * 128 + m * 16 + lkg * 4;
#pragma unroll
        for (int n = 0; n < 4; ++n) {
          int wcol = (gc0 + n * 16 + lr) & 2047;
          int f = wcol & 127, hh = wcol >> 7;
          int j = f >> 1, odd = f & 1;
          int oc = hh * 128 + (odd ? 64 : 0) + j;
#pragma unroll
          for (int r = 0; r < 4; ++r) {
            long row = r0 + r;
            int s = (int)(row & (SEQ - 1));
            float cv = cosT[s * 64 + j], sn = sinT[s * 64 + j];
            float v = acc[m][n][r];
            float o = __shfl_xor(v, 1);
            float res = odd ? (v * cv + o * sn) : (v * cv - o * sn);
            dst[row * 2048 + oc] = f2bf(res);
          }
        }
      }
    }
  }
}

// ---------------------------------------------------------------- GEMM 128x128 (m97) for N=2048
// MODE 2 ADDH: f32 p0 = p1 + acc.   MODE 3 ADDOUT: f32 p0 += acc.
template <int MODE>
__global__ __launch_bounds__(256) void gemm_kernel(
    const unsigned short* __restrict__ A, const unsigned short* __restrict__ Bt, int N,
    void* __restrict__ p0, const void* __restrict__ p1) {
  __shared__ unsigned short As[128 * 32];
  __shared__ unsigned short Bs[128 * 32];
  const int tid = threadIdx.x;
  const int lane = tid & 63, wave = tid >> 6;
  const int wm = (wave >> 1) * 64, wn = (wave & 1) * 64;
  const int lr = lane & 15, lkg = lane >> 4;
  const long bm = (long)blockIdx.y * 128, bn = (long)blockIdx.x * 128;
  f32x4 acc[4][4] = {};
  const int rA0 = wave * 32 + (lane >> 2);
  const int gs0 = (lane & 3) ^ ((rA0 >> 1) & 3);
  const int gs1 = (lane & 3) ^ (((rA0 + 16) >> 1) & 3);
  const unsigned short* Ag0 = A + (bm + rA0) * HIDN + gs0 * 8;
  const unsigned short* Ag1 = A + (bm + rA0 + 16) * HIDN + gs1 * 8;
  const unsigned short* Bg0 = Bt + (bn + rA0) * HIDN + gs0 * 8;
  const unsigned short* Bg1 = Bt + (bn + rA0 + 16) * HIDN + gs1 * 8;
  unsigned short* lA0 = &As[(wave * 32) * 32];
  unsigned short* lA1 = &As[(wave * 32 + 16) * 32];
  unsigned short* lB0 = &Bs[(wave * 32) * 32];
  unsigned short* lB1 = &Bs[(wave * 32 + 16) * 32];
  for (int k0 = 0; k0 < HIDN; k0 += 32) {
    __syncthreads();
    gload16(Ag0 + k0, lA0);
    gload16(Ag1 + k0, lA1);
    gload16(Bg0 + k0, lB0);
    gload16(Bg1 + k0, lB1);
    __syncthreads();
    bf16x8 af[4], bfr[4];
#pragma unroll
    for (int m = 0; m < 4; ++m) {
      int row = wm + m * 16 + lr;
      af[m] = *(const bf16x8*)((const char*)As + row * 64 + ((lkg ^ ((row >> 1) & 3)) << 4));
    }
#pragma unroll
    for (int n = 0; n < 4; ++n) {
      int row = wn + n * 16 + lr;
      bfr[n] = *(const bf16x8*)((const char*)Bs + row * 64 + ((lkg ^ ((row >> 1) & 3)) << 4));
    }
#pragma unroll
    for (int m = 0; m < 4; ++m)
#pragma unroll
      for (int n = 0; n < 4; ++n) acc[m][n] = MFMA16(af[m], bfr[n], acc[m][n]);
  }
  float* fout = (float*)p0;
  const float* addsrc = (const float*)p1;
#pragma unroll
  for (int m = 0; m < 4; ++m)
#pragma unroll
    for (int n = 0; n < 4; ++n) {
      long r0 = bm + wm + m * 16 + lkg * 4;
      long c = bn + wn + n * 16 + lr;
#pragma unroll
      for (int r = 0; r < 4; ++r) {
        long idx = (r0 + r) * 2048 + c;
        if (MODE == 2) fout[idx] = addsrc[idx] + acc[m][n][r];
        else fout[idx] = fout[idx] + acc[m][n][r];
      }
    }
}

// ---------------------------------------------------------------- flash attention
__global__ __launch_bounds__(256) void flash_attn_kernel(
    const unsigned short* __restrict__ Q, const unsigned short* __restrict__ Kb,
    const unsigned short* __restrict__ Vb, unsigned short* __restrict__ O) {
  __shared__ unsigned short Ks[2][64 * 128];
  __shared__ unsigned short VtL[128 * 64];
  __shared__ unsigned short Ps[4][16][72];
  const int qt = blockIdx.x, h = blockIdx.y, b = blockIdx.z;
  const int tid = threadIdx.x, wave = tid >> 6, lane = tid & 63;
  const int lr = lane & 15, lkg = lane >> 4, lk = lkg * 8;
  const float scale = 0.08838834764831845f;  // 1/sqrt(128)
  const long rowbase = (long)b * SEQ;
  const int qrow0 = qt * 64 + wave * 16;
  bf16x8 aq[4];
#pragma unroll
  for (int ks = 0; ks < 4; ++ks)
    aq[ks] = *(const bf16x8*)(Q + (rowbase + qrow0 + lr) * HIDN + h * HD + ks * 32 + lk);
  const int kq = tid & 15, db = tid >> 4;
  const int krl = lane >> 4;
  char* vb8 = (char*)VtL;
  f32x4 acc[8] = {};
  float m_[4] = {-3.0e38f, -3.0e38f, -3.0e38f, -3.0e38f};
  float l_[4] = {0.f, 0.f, 0.f, 0.f};
  ushort4 vreg[2][4];
#pragma unroll
  for (int j = 0; j < 4; ++j) {
    int rl = wave * 16 + j * 4 + krl;
    int slot = (lane & 15) ^ (rl & 15);
    gload16(Kb + (rowbase + rl) * HIDN + h * HD + slot * 8,
            &Ks[0][(wave * 16 + j * 4) * 128]);
  }
#pragma unroll
  for (int j = 0; j < 4; ++j)
#pragma unroll
    for (int i = 0; i < 2; ++i)
      vreg[i][j] = *(const ushort4*)(Vb + (rowbase + kq * 4 + j) * HIDN + h * HD + db * 8 + i * 4);

  for (int t = 0; t < SEQ / 64; ++t) {
    asm volatile("s_waitcnt vmcnt(0)" ::: "memory");
#pragma unroll
    for (int i = 0; i < 2; ++i)
#pragma unroll
      for (int dd = 0; dd < 4; ++dd) {
        int d = db * 8 + i * 4 + dd;
        ushort4 w;
        w.x = ((const unsigned short*)&vreg[i][0])[dd];
        w.y = ((const unsigned short*)&vreg[i][1])[dd];
        w.z = ((const unsigned short*)&vreg[i][2])[dd];
        w.w = ((const unsigned short*)&vreg[i][3])[dd];
        *(ushort4*)(vb8 + d * 128 + ((kq * 8) ^ ((d & 7) << 4))) = w;
      }
    asm volatile("s_waitcnt lgkmcnt(0)" ::: "memory");
    asm volatile("s_barrier" ::: "memory");
    if (t + 1 < SEQ / 64) {
      const long kvn = (long)(t + 1) * 64;
#pragma unroll
      for (int j = 0; j < 4; ++j) {
        int rl = wave * 16 + j * 4 + krl;
        int slot = (lane & 15) ^ (rl & 15);
        gload16(Kb + (rowbase + kvn + rl) * HIDN + h * HD + slot * 8,
                &Ks[(t + 1) & 1][(wave * 16 + j * 4) * 128]);
      }
#pragma unroll
      for (int j = 0; j < 4; ++j)
#pragma unroll
        for (int i = 0; i < 2; ++i)
          vreg[i][j] = *(const ushort4*)(Vb + (rowbase + kvn + kq * 4 + j) * HIDN + h * HD + db * 8 + i * 4);
    }
    const char* ksb = (const char*)Ks[t & 1];
    f32x4 sa[4] = {};
#pragma unroll
    for (int n = 0; n < 4; ++n) {
      int row = n * 16 + lr;
#pragma unroll
      for (int ks = 0; ks < 4; ++ks) {
        bf16x8 bk = *(const bf16x8*)(ksb + row * 256 + (((ks * 4 + lkg) ^ (row & 15)) << 4));
        sa[n] = MFMA16(aq[ks], bk, sa[n]);
      }
    }
#pragma unroll
    for (int n = 0; n < 4; ++n)
#pragma unroll
      for (int r = 0; r < 4; ++r) sa[n][r] *= scale;
#pragma unroll
    for (int r = 0; r < 4; ++r) {
      float mx = fmaxf(fmaxf(sa[0][r], sa[1][r]), fmaxf(sa[2][r], sa[3][r]));
#pragma unroll
      for (int off = 1; off < 16; off <<= 1) mx = fmaxf(mx, __shfl_xor(mx, off));
      float mnew = fmaxf(m_[r], mx);
      float corr = __expf(m_[r] - mnew);
      float psum = 0.f;
#pragma unroll
      for (int n = 0; n < 4; ++n) {
        float p = __expf(sa[n][r] - mnew);
        sa[n][r] = p;
        psum += p;
      }
#pragma unroll
      for (int off = 1; off < 16; off <<= 1) psum += __shfl_xor(psum, off);
      l_[r] = l_[r] * corr + psum;
      m_[r] = mnew;
#pragma unroll
      for (int df = 0; df < 8; ++df) acc[df][r] *= corr;
    }
#pragma unroll
    for (int r = 0; r < 4; ++r)
#pragma unroll
      for (int n = 0; n < 4; ++n) Ps[wave][lkg * 4 + r][n * 16 + lr] = f2bf(sa[n][r]);
    asm volatile("s_waitcnt lgkmcnt(0)" ::: "memory");
    asm volatile("s_barrier" ::: "memory");
    bf16x8 pa0 = *(const bf16x8*)&Ps[wave][lr][lk];
    bf16x8 pa1 = *(const bf16x8*)&Ps[wave][lr][32 + lk];
#pragma unroll
    for (int df = 0; df < 8; ++df) {
      int row = df * 16 + lr;
      int sw = (row & 7) << 4;
      bf16x8 bv0 = *(const bf16x8*)(vb8 + row * 128 + ((lkg * 16) ^ sw));
      bf16x8 bv1 = *(const bf16x8*)(vb8 + row * 128 + (((4 + lkg) * 16) ^ sw));
      acc[df] = MFMA16(pa0, bv0, acc[df]);
      acc[df] = MFMA16(pa1, bv1, acc[df]);
    }
    asm volatile("s_barrier" ::: "memory");
  }
#pragma unroll
  for (int r = 0; r < 4; ++r) {
    float invl = 1.0f / l_[r];
    long orow = rowbase + qrow0 + lkg * 4 + r;
#pragma unroll
    for (int df = 0; df < 8; ++df)
      O[orow * HIDN + h * HD + df * 16 + lr] = f2bf(acc[df][r] * invl);
  }
}

// ---------------------------------------------------------------- launcher
extern "C" void kernel_launch(void* const* d_in, const int* in_sizes, int n_in,
                              void* d_out, int out_size, void* d_ws, size_t ws_size,
                              hipStream_t stream) {
  const float* hidden = (const float*)d_in[0];
  const float* Wq = (const float*)d_in[1];
  const float* Wk = (const float*)d_in[2];
  const float* Wv = (const float*)d_in[3];
  const float* Wo = (const float*)d_in[4];
  const float* w1 = (const float*)d_in[5];
  const float* w2 = (const float*)d_in[6];
  const float* w3 = (const float*)d_in[7];
  const float* ln1 = (const float*)d_in[8];
  const float* ln2 = (const float*)d_in[9];
  float* out = (float*)d_out;

  char* ws = (char*)d_ws;
  size_t off = 0;
  auto alloc = [&](size_t bytes) -> void* {
    void* p = ws + off;
    off += (bytes + 255) & ~(size_t)255;
    return p;
  };
  unsigned short* wblk = (unsigned short*)alloc((size_t)(2048L * 6 + 2048) * HIDN * 2);
  unsigned short* wQ = wblk;
  unsigned short* wK = wblk + (size_t)2048 * HIDN;
  unsigned short* wV = wblk + (size_t)4096 * HIDN;
  unsigned short* wO = wblk + (size_t)6144 * HIDN;
  unsigned short* wG = wblk + (size_t)8192 * HIDN;   // 4096 rows (w1/w3 interleaved)
  unsigned short* wD = wblk + (size_t)12288 * HIDN;
  unsigned short* xb   = (unsigned short*)alloc((size_t)NROWS * HIDN * 2);
  unsigned short* qb   = (unsigned short*)alloc((size_t)NROWS * HIDN * 2);
  unsigned short* kb   = (unsigned short*)alloc((size_t)NROWS * HIDN * 2);
  unsigned short* vb   = (unsigned short*)alloc((size_t)NROWS * HIDN * 2);
  unsigned short* ctxb = (unsigned short*)alloc((size_t)NROWS * HIDN * 2);
  float* cosT = (float*)alloc((size_t)SEQ * 64 * 4);
  float* sinT = (float*)alloc((size_t)SEQ * 64 * 4);
  if (off > ws_size) return;

  dim3 tgrid(HIDN / 32, HIDN / 32);
  transpose_cvt_kernel<1><<<tgrid, 256, 0, stream>>>(Wq, wQ, 0);
  transpose_cvt_kernel<1><<<tgrid, 256, 0, stream>>>(Wk, wK, 0);
  transpose_cvt_kernel<0><<<tgrid, 256, 0, stream>>>(Wv, wV, 0);
  transpose_cvt_kernel<0><<<tgrid, 256, 0, stream>>>(Wo, wO, 0);
  transpose_cvt_kernel<2><<<tgrid, 256, 0, stream>>>(w1, wG, 0);
  transpose_cvt_kernel<2><<<tgrid, 256, 0, stream>>>(w3, wG, 1);
  transpose_cvt_kernel<0><<<tgrid, 256, 0, stream>>>(w2, wD, 0);
  rope_table_kernel<<<SEQ, 64, 0, stream>>>(cosT, sinT);

  rmsnorm_kernel<<<NROWS, 256, 0, stream>>>(hidden, ln1, xb);

  // QKV fused (N=6144) deep-pipeline 256^2 with rope epilogue -> qb,kb,vb
  gemm256_kernel<0><<<(6144 / 256) * (NROWS / 256), 512, 0, stream>>>(
      xb, wQ, 6144 / 256, qb, kb, vb, cosT, sinT);

  flash_attn_kernel<<<dim3(SEQ / 64, NHEAD, BATCH), 256, 0, stream>>>(qb, kb, vb, ctxb);

  // attn_out + residual -> out (f32)
  gemm_kernel<2><<<dim3(2048 / 128, NROWS / 128), 256, 0, stream>>>(
      ctxb, wO, 2048, out, hidden);

  rmsnorm_kernel<<<NROWS, 256, 0, stream>>>(out, ln2, xb);

  // gate: silu(y@w1)*(y@w3) fused (N=4096 interleaved) -> qb
  gemm256_kernel<1><<<(4096 / 256) * (NROWS / 256), 512, 0, stream>>>(
      xb, wG, 4096 / 256, qb, nullptr, nullptr, nullptr, nullptr);

  // down: out += gs @ w2
  gemm_kernel<3><<<dim3(2048 / 128, NROWS / 128), 256, 0, stream>>>(
      qb, wD, 2048, out, nullptr);
}

// Round 5
// 512.967 us; speedup vs baseline: 1.8357x; 1.0421x over previous
//
#include <hip/hip_runtime.h>

#define HIDN 2048
#define NHEAD 16
#define HD 128
#define SEQ 2048
#define BATCH 2
#define NROWS (BATCH*SEQ)   // 4096

typedef __bf16 bf16_t;
typedef bf16_t bf16x8 __attribute__((ext_vector_type(8)));
typedef float f32x4 __attribute__((ext_vector_type(4)));

#define AS1 __attribute__((address_space(1)))
#define AS3 __attribute__((address_space(3)))

__device__ __forceinline__ unsigned short f2bf(float x) {
  union { bf16_t b; unsigned short u; } cv; cv.b = (bf16_t)x; return cv.u;
}

#define MFMA16(a,b,c) __builtin_amdgcn_mfma_f32_16x16x32_bf16((a),(b),(c),0,0,0)

__device__ __forceinline__ void gload16(const void* g, void* l) {
  __builtin_amdgcn_global_load_lds((const AS1 void*)g, (AS3 void*)l, 16, 0, 0);
}

// ---------------------------------------------------------------- transpose+cvt
// TMODE 0: dst=n. TMODE 1 (qk rope-interleave). TMODE 2 (gate interleave).
template <int TMODE>
__global__ __launch_bounds__(256) void transpose_cvt_kernel(
    const float* __restrict__ W, unsigned short* __restrict__ Wt, int half) {
  __shared__ float t[32][33];
  int bn = blockIdx.x * 32;
  int bk = blockIdx.y * 32;
  int tx = threadIdx.x & 31, ty = threadIdx.x >> 5;
#pragma unroll
  for (int i = 0; i < 4; ++i) {
    int k = bk + ty + i * 8;
    t[ty + i * 8][tx] = W[(long)k * HIDN + bn + tx];
  }
  __syncthreads();
#pragma unroll
  for (int i = 0; i < 4; ++i) {
    int n = bn + ty + i * 8;
    int dst;
    if (TMODE == 0) dst = n;
    else if (TMODE == 1) { int d = n & 127; dst = (n & ~127) | ((d & 63) << 1) | (d >> 6); }
    else dst = (n >> 4) * 32 + half * 16 + (n & 15);
    Wt[(long)dst * HIDN + bk + tx] = f2bf(t[tx][ty + i * 8]);
  }
}

// ---------------------------------------------------------------- rope tables
__global__ void rope_table_kernel(float* __restrict__ cosT, float* __restrict__ sinT) {
  int s = blockIdx.x, d = threadIdx.x;
  float invf = powf(10000.0f, (-2.0f * (float)d) / 128.0f);
  float ang = (float)s * invf;
  cosT[s * 64 + d] = cosf(ang);
  sinT[s * 64 + d] = sinf(ang);
}

// ---------------------------------------------------------------- rmsnorm
__global__ __launch_bounds__(256) void rmsnorm_kernel(
    const float* __restrict__ x, const float* __restrict__ w, unsigned short* __restrict__ out) {
  long row = blockIdx.x;
  const float* xr = x + row * HIDN;
  int c0 = threadIdx.x * 4;
  float4 v0 = *(const float4*)(xr + c0);
  float4 v1 = *(const float4*)(xr + 1024 + c0);
  float s = v0.x*v0.x + v0.y*v0.y + v0.z*v0.z + v0.w*v0.w
          + v1.x*v1.x + v1.y*v1.y + v1.z*v1.z + v1.w*v1.w;
#pragma unroll
  for (int off = 1; off < 64; off <<= 1) s += __shfl_xor(s, off);
  __shared__ float red[4];
  if ((threadIdx.x & 63) == 0) red[threadIdx.x >> 6] = s;
  __syncthreads();
  float tot = red[0] + red[1] + red[2] + red[3];
  float r = 1.0f / sqrtf(tot * (1.0f / (float)HIDN) + 1e-6f);
  float4 w0 = *(const float4*)(w + c0);
  float4 w1 = *(const float4*)(w + 1024 + c0);
  ushort4 o0, o1;
  o0.x = f2bf(v0.x * r * w0.x); o0.y = f2bf(v0.y * r * w0.y);
  o0.z = f2bf(v0.z * r * w0.z); o0.w = f2bf(v0.w * r * w0.w);
  o1.x = f2bf(v1.x * r * w1.x); o1.y = f2bf(v1.y * r * w1.y);
  o1.z = f2bf(v1.z * r * w1.z); o1.w = f2bf(v1.w * r * w1.w);
  *(ushort4*)(out + row * HIDN + c0) = o0;
  *(ushort4*)(out + row * HIDN + 1024 + c0) = o1;
}

// ---------------------------------------------------------------- GEMM 256x256 (deep pipeline)
// MODE 0: QKV+rope (q pre-scaled by 1/sqrt(HD)). MODE 1: gate silu-mul.
template <int MODE>
__global__ __launch_bounds__(512, 2) void gemm256_kernel(
    const unsigned short* __restrict__ A, const unsigned short* __restrict__ Bt,
    int nbx,
    void* __restrict__ p0, void* __restrict__ p1, void* __restrict__ p2,
    const float* __restrict__ cosT, const float* __restrict__ sinT) {
  __shared__ unsigned short L[65536];   // [2 dbuf][ A:16384 | B:16384 ] shorts
  const int tid = threadIdx.x;
  const int wave = tid >> 6, lane = tid & 63;
  const int lr = lane & 15, lkg = lane >> 4;
  const int wr = wave >> 2, wc = wave & 3;
  const int nwg = (int)gridDim.x;
  const int bid = (int)blockIdx.x;
  const int wg = (bid & 7) * (nwg >> 3) + (bid >> 3);
  const int bx = wg % nbx, by = wg / nbx;
  const long bm = (long)by * 256, bn = (long)bx * 256;
  const int srow = wave * 8 + (lane >> 3);
  const int sslot = (lane & 7) ^ (lane >> 3);
  const unsigned short* Ag = A + (bm + srow) * HIDN + sslot * 8;
  const unsigned short* Bg = Bt + (bn + srow) * HIDN + sslot * 8;
  f32x4 acc[8][4] = {};

#define STAGE256(kt2)                                                            \
  {                                                                              \
    const long ko = (long)(kt2) * 64;                                            \
    unsigned short* Ld = &L[((kt2) & 1) * 32768];                                \
    _Pragma("unroll")                                                            \
    for (int j = 0; j < 4; ++j) {                                                \
      gload16(Ag + ko + (long)j * 64 * HIDN, &Ld[(j * 64 + wave * 8) * 64]);     \
      gload16(Bg + ko + (long)j * 64 * HIDN, &Ld[16384 + (j * 64 + wave * 8) * 64]); \
    }                                                                            \
  }

  STAGE256(0);
  STAGE256(1);
  asm volatile("s_waitcnt vmcnt(8)" ::: "memory");
  __builtin_amdgcn_sched_barrier(0);
  __builtin_amdgcn_s_barrier();

  for (int kt = 0; kt < 32; ++kt) {
    const int d = kt & 1;
    const char* Lb = (const char*)L + d * 65536;
    bf16x8 bfr[4][2];
#pragma unroll
    for (int n = 0; n < 4; ++n) {
      int row = wc * 64 + n * 16 + lr;
      int x7 = row & 7;
#pragma unroll
      for (int ks = 0; ks < 2; ++ks) {
        int s = ks * 4 + lkg;
        bfr[n][ks] = *(const bf16x8*)(Lb + 32768 + row * 128 + ((s ^ x7) << 4));
      }
    }
#pragma unroll
    for (int q = 0; q < 4; ++q) {
      bf16x8 af[2][2];
#pragma unroll
      for (int mm = 0; mm < 2; ++mm) {
        int row = wr * 128 + (q * 2 + mm) * 16 + lr;
        int x7 = row & 7;
#pragma unroll
        for (int ks = 0; ks < 2; ++ks) {
          int s = ks * 4 + lkg;
          af[mm][ks] = *(const bf16x8*)(Lb + row * 128 + ((s ^ x7) << 4));
        }
      }
      __builtin_amdgcn_s_setprio(1);
#pragma unroll
      for (int mm = 0; mm < 2; ++mm)
#pragma unroll
        for (int n = 0; n < 4; ++n) {
          acc[q * 2 + mm][n] = MFMA16(af[mm][0], bfr[n][0], acc[q * 2 + mm][n]);
          acc[q * 2 + mm][n] = MFMA16(af[mm][1], bfr[n][1], acc[q * 2 + mm][n]);
        }
      __builtin_amdgcn_s_setprio(0);
    }
    if (kt == 31) break;
    asm volatile("s_waitcnt lgkmcnt(0)" ::: "memory");
    __builtin_amdgcn_sched_barrier(0);
    __builtin_amdgcn_s_barrier();
    if (kt < 30) {
      STAGE256(kt + 2);
      asm volatile("s_waitcnt vmcnt(8)" ::: "memory");
    } else {
      asm volatile("s_waitcnt vmcnt(0)" ::: "memory");
    }
    __builtin_amdgcn_sched_barrier(0);
    __builtin_amdgcn_s_barrier();
  }
#undef STAGE256

  // ---------------- epilogues ----------------
  const int gc0 = (int)bn + wc * 64;
  if (MODE == 1) {
    unsigned short* bout = (unsigned short*)p0;
#pragma unroll
    for (int m = 0; m < 8; ++m) {
      long r0 = bm + wr * 128 + m * 16 + lkg * 4;
#pragma unroll
      for (int n = 0; n < 4; n += 2) {
        int ggrp = (gc0 + n * 16) >> 5;
        long c = (long)ggrp * 16 + lr;
#pragma unroll
        for (int r = 0; r < 4; ++r) {
          float x = acc[m][n][r], g = acc[m][n + 1][r];
          float sv = x / (1.0f + __expf(-x)) * g;
          bout[(r0 + r) * 2048 + c] = f2bf(sv);
        }
      }
    }
  } else {  // MODE 0: QKV with fused rope on q,k; q pre-scaled by 1/sqrt(HD)
    int bufid = gc0 >> 11;
    unsigned short* dst = (bufid == 0) ? (unsigned short*)p0
                        : (bufid == 1) ? (unsigned short*)p1
                                       : (unsigned short*)p2;
    if (bufid == 2) {
#pragma unroll
      for (int m = 0; m < 8; ++m) {
        long r0 = bm + wr * 128 + m * 16 + lkg * 4;
#pragma unroll
        for (int n = 0; n < 4; ++n) {
          int wcol = (gc0 + n * 16 + lr) & 2047;
#pragma unroll
          for (int r = 0; r < 4; ++r) dst[(r0 + r) * 2048 + wcol] = f2bf(acc[m][n][r]);
        }
      }
    } else {
      const float qscale = (bufid == 0) ? 0.08838834764831845f : 1.0f;
#pragma unroll
      for (int m = 0; m < 8; ++m) {
        long r0 = bm + wr * 128 + m * 16 + lkg * 4;
#pragma unroll
        for (int n = 0; n < 4; ++n) {
          int wcol = (gc0 + n * 16 + lr) & 2047;
          int f = wcol & 127, hh = wcol >> 7;
          int j = f >> 1, odd = f & 1;
          int oc = hh * 128 + (odd ? 64 : 0) + j;
#pragma unroll
          for (int r = 0; r < 4; ++r) {
            long row = r0 + r;
            int s = (int)(row & (SEQ - 1));
            float cv = cosT[s * 64 + j], sn = sinT[s * 64 + j];
            float v = acc[m][n][r];
            float o = __shfl_xor(v, 1);
            float res = (odd ? (v * cv + o * sn) : (v * cv - o * sn)) * qscale;
            dst[row * 2048 + oc] = f2bf(res);
          }
        }
      }
    }
  }
}

// ---------------------------------------------------------------- GEMM 128x128 (m97) for N=2048
// MODE 2 ADDH: f32 p0 = p1 + acc.   MODE 3 ADDOUT: f32 p0 += acc.
template <int MODE>
__global__ __launch_bounds__(256) void gemm_kernel(
    const unsigned short* __restrict__ A, const unsigned short* __restrict__ Bt, int N,
    void* __restrict__ p0, const void* __restrict__ p1) {
  __shared__ unsigned short As[128 * 32];
  __shared__ unsigned short Bs[128 * 32];
  const int tid = threadIdx.x;
  const int lane = tid & 63, wave = tid >> 6;
  const int wm = (wave >> 1) * 64, wn = (wave & 1) * 64;
  const int lr = lane & 15, lkg = lane >> 4;
  const long bm = (long)blockIdx.y * 128, bn = (long)blockIdx.x * 128;
  f32x4 acc[4][4] = {};
  const int rA0 = wave * 32 + (lane >> 2);
  const int gs0 = (lane & 3) ^ ((rA0 >> 1) & 3);
  const int gs1 = (lane & 3) ^ (((rA0 + 16) >> 1) & 3);
  const unsigned short* Ag0 = A + (bm + rA0) * HIDN + gs0 * 8;
  const unsigned short* Ag1 = A + (bm + rA0 + 16) * HIDN + gs1 * 8;
  const unsigned short* Bg0 = Bt + (bn + rA0) * HIDN + gs0 * 8;
  const unsigned short* Bg1 = Bt + (bn + rA0 + 16) * HIDN + gs1 * 8;
  unsigned short* lA0 = &As[(wave * 32) * 32];
  unsigned short* lA1 = &As[(wave * 32 + 16) * 32];
  unsigned short* lB0 = &Bs[(wave * 32) * 32];
  unsigned short* lB1 = &Bs[(wave * 32 + 16) * 32];
  for (int k0 = 0; k0 < HIDN; k0 += 32) {
    __syncthreads();
    gload16(Ag0 + k0, lA0);
    gload16(Ag1 + k0, lA1);
    gload16(Bg0 + k0, lB0);
    gload16(Bg1 + k0, lB1);
    __syncthreads();
    bf16x8 af[4], bfr[4];
#pragma unroll
    for (int m = 0; m < 4; ++m) {
      int row = wm + m * 16 + lr;
      af[m] = *(const bf16x8*)((const char*)As + row * 64 + ((lkg ^ ((row >> 1) & 3)) << 4));
    }
#pragma unroll
    for (int n = 0; n < 4; ++n) {
      int row = wn + n * 16 + lr;
      bfr[n] = *(const bf16x8*)((const char*)Bs + row * 64 + ((lkg ^ ((row >> 1) & 3)) << 4));
    }
#pragma unroll
    for (int m = 0; m < 4; ++m)
#pragma unroll
      for (int n = 0; n < 4; ++n) acc[m][n] = MFMA16(af[m], bfr[n], acc[m][n]);
  }
  float* fout = (float*)p0;
  const float* addsrc = (const float*)p1;
#pragma unroll
  for (int m = 0; m < 4; ++m)
#pragma unroll
    for (int n = 0; n < 4; ++n) {
      long r0 = bm + wm + m * 16 + lkg * 4;
      long c = bn + wn + n * 16 + lr;
#pragma unroll
      for (int r = 0; r < 4; ++r) {
        long idx = (r0 + r) * 2048 + c;
        if (MODE == 2) fout[idx] = addsrc[idx] + acc[m][n][r];
        else fout[idx] = fout[idx] + acc[m][n][r];
      }
    }
}

// ---------------------------------------------------------------- flash attention
// Swapped QK^T (A=K, B=Q): S^T layout -> kv lane-local softmax (q = lane&15).
// Q pre-scaled by 1/sqrt(HD) in the QKV epilogue.
__global__ __launch_bounds__(256) void flash_attn_kernel(
    const unsigned short* __restrict__ Q, const unsigned short* __restrict__ Kb,
    const unsigned short* __restrict__ Vb, unsigned short* __restrict__ O) {
  __shared__ unsigned short Ks[2][64 * 128];
  __shared__ unsigned short VtL[128 * 64];
  __shared__ unsigned short Ps[4][16][72];
  const int qt = blockIdx.x, h = blockIdx.y, b = blockIdx.z;
  const int tid = threadIdx.x, wave = tid >> 6, lane = tid & 63;
  const int lr = lane & 15, lkg = lane >> 4, lk = lkg * 8;
  const long rowbase = (long)b * SEQ;
  const int qrow0 = qt * 64 + wave * 16;
  bf16x8 aq[4];
#pragma unroll
  for (int ks = 0; ks < 4; ++ks)
    aq[ks] = *(const bf16x8*)(Q + (rowbase + qrow0 + lr) * HIDN + h * HD + ks * 32 + lk);
  const int kq = tid & 15, db = tid >> 4;
  const int krl = lane >> 4;
  char* vb8 = (char*)VtL;
  f32x4 acc[8] = {};
  float m_ = -3.0e38f, l_ = 0.f;   // per-lane state for q-row = lr (replicated x4 over lkg)
  ushort4 vreg[2][4];
#pragma unroll
  for (int j = 0; j < 4; ++j) {
    int rl = wave * 16 + j * 4 + krl;
    int slot = (lane & 15) ^ (rl & 15);
    gload16(Kb + (rowbase + rl) * HIDN + h * HD + slot * 8,
            &Ks[0][(wave * 16 + j * 4) * 128]);
  }
#pragma unroll
  for (int j = 0; j < 4; ++j)
#pragma unroll
    for (int i = 0; i < 2; ++i)
      vreg[i][j] = *(const ushort4*)(Vb + (rowbase + kq * 4 + j) * HIDN + h * HD + db * 8 + i * 4);

  for (int t = 0; t < SEQ / 64; ++t) {
    asm volatile("s_waitcnt vmcnt(0)" ::: "memory");   // own K-DMA + V-reg loads landed
#pragma unroll
    for (int i = 0; i < 2; ++i)
#pragma unroll
      for (int dd = 0; dd < 4; ++dd) {
        int d = db * 8 + i * 4 + dd;
        ushort4 w;
        w.x = ((const unsigned short*)&vreg[i][0])[dd];
        w.y = ((const unsigned short*)&vreg[i][1])[dd];
        w.z = ((const unsigned short*)&vreg[i][2])[dd];
        w.w = ((const unsigned short*)&vreg[i][3])[dd];
        *(ushort4*)(vb8 + d * 128 + ((kq * 8) ^ ((d & 7) << 4))) = w;
      }
    asm volatile("s_waitcnt lgkmcnt(0)" ::: "memory");
    asm volatile("s_barrier" ::: "memory");            // all waves: K(t)+V(t) visible
    if (t + 1 < SEQ / 64) {
      const long kvn = (long)(t + 1) * 64;
#pragma unroll
      for (int j = 0; j < 4; ++j) {
        int rl = wave * 16 + j * 4 + krl;
        int slot = (lane & 15) ^ (rl & 15);
        gload16(Kb + (rowbase + kvn + rl) * HIDN + h * HD + slot * 8,
                &Ks[(t + 1) & 1][(wave * 16 + j * 4) * 128]);
      }
#pragma unroll
      for (int j = 0; j < 4; ++j)
#pragma unroll
        for (int i = 0; i < 2; ++i)
          vreg[i][j] = *(const ushort4*)(Vb + (rowbase + kvn + kq * 4 + j) * HIDN + h * HD + db * 8 + i * 4);
    }
    // ---- S^T = K x Q^T : col = q (lane&15), row = kv = n*16 + 4*lkg + r ----
    const char* ksb = (const char*)Ks[t & 1];
    f32x4 sa[4] = {};
#pragma unroll
    for (int n = 0; n < 4; ++n) {
      int row = n * 16 + lr;
#pragma unroll
      for (int ks = 0; ks < 4; ++ks) {
        bf16x8 bk = *(const bf16x8*)(ksb + row * 256 + (((ks * 4 + lkg) ^ (row & 15)) << 4));
        sa[n] = MFMA16(bk, aq[ks], sa[n]);
      }
    }
    // ---- softmax: kv lane-local; reduce = 2 shfl (xor16, xor32) ----
    float pmax = sa[0][0];
#pragma unroll
    for (int n = 0; n < 4; ++n)
#pragma unroll
      for (int r = 0; r < 4; ++r) pmax = fmaxf(pmax, sa[n][r]);
    pmax = fmaxf(pmax, __shfl_xor(pmax, 16));
    pmax = fmaxf(pmax, __shfl_xor(pmax, 32));
    float mnew = fmaxf(m_, pmax);
    float corr = __expf(m_ - mnew);
    float psum = 0.f;
#pragma unroll
    for (int n = 0; n < 4; ++n)
#pragma unroll
      for (int r = 0; r < 4; ++r) {
        float p = __expf(sa[n][r] - mnew);
        sa[n][r] = p;
        psum += p;
      }
    psum += __shfl_xor(psum, 16);
    psum += __shfl_xor(psum, 32);
    l_ = l_ * corr + psum;
    m_ = mnew;
    // broadcast corr to the acc-row owners: acc row q = 4*lkg + r, corr lives at lane q
    float corr4[4];
#pragma unroll
    for (int r = 0; r < 4; ++r) corr4[r] = __shfl(corr, 4 * lkg + r);
#pragma unroll
    for (int df = 0; df < 8; ++df)
#pragma unroll
      for (int r = 0; r < 4; ++r) acc[df][r] *= corr4[r];
    // ---- P -> per-wave LDS (b64 packed: kv n*16+4*lkg+r contiguous in r) ----
#pragma unroll
    for (int n = 0; n < 4; ++n) {
      ushort4 pw;
      pw.x = f2bf(sa[n][0]); pw.y = f2bf(sa[n][1]);
      pw.z = f2bf(sa[n][2]); pw.w = f2bf(sa[n][3]);
      *(ushort4*)&Ps[wave][lr][n * 16 + 4 * lkg] = pw;
    }
    // no block barrier needed: Ps is per-wave; within-wave LDS RAW is in-order
    bf16x8 pa0 = *(const bf16x8*)&Ps[wave][lr][lk];
    bf16x8 pa1 = *(const bf16x8*)&Ps[wave][lr][32 + lk];
#pragma unroll
    for (int df = 0; df < 8; ++df) {
      int row = df * 16 + lr;
      int sw = (row & 7) << 4;
      bf16x8 bv0 = *(const bf16x8*)(vb8 + row * 128 + ((lkg * 16) ^ sw));
      bf16x8 bv1 = *(const bf16x8*)(vb8 + row * 128 + (((4 + lkg) * 16) ^ sw));
      acc[df] = MFMA16(pa0, bv0, acc[df]);
      acc[df] = MFMA16(pa1, bv1, acc[df]);
    }
    asm volatile("s_barrier" ::: "memory");            // protect VtL before next overwrite
  }
  float invl = 1.0f / l_;
  float invl4[4];
#pragma unroll
  for (int r = 0; r < 4; ++r) invl4[r] = __shfl(invl, 4 * lkg + r);
#pragma unroll
  for (int r = 0; r < 4; ++r) {
    long orow = rowbase + qrow0 + lkg * 4 + r;
#pragma unroll
    for (int df = 0; df < 8; ++df)
      O[orow * HIDN + h * HD + df * 16 + lr] = f2bf(acc[df][r] * invl4[r]);
  }
}

// ---------------------------------------------------------------- launcher
extern "C" void kernel_launch(void* const* d_in, const int* in_sizes, int n_in,
                              void* d_out, int out_size, void* d_ws, size_t ws_size,
                              hipStream_t stream) {
  const float* hidden = (const float*)d_in[0];
  const float* Wq = (const float*)d_in[1];
  const float* Wk = (const float*)d_in[2];
  const float* Wv = (const float*)d_in[3];
  const float* Wo = (const float*)d_in[4];
  const float* w1 = (const float*)d_in[5];
  const float* w2 = (const float*)d_in[6];
  const float* w3 = (const float*)d_in[7];
  const float* ln1 = (const float*)d_in[8];
  const float* ln2 = (const float*)d_in[9];
  float* out = (float*)d_out;

  char* ws = (char*)d_ws;
  size_t off = 0;
  auto alloc = [&](size_t bytes) -> void* {
    void* p = ws + off;
    off += (bytes + 255) & ~(size_t)255;
    return p;
  };
  unsigned short* wblk = (unsigned short*)alloc((size_t)(2048L * 6 + 2048) * HIDN * 2);
  unsigned short* wQ = wblk;
  unsigned short* wK = wblk + (size_t)2048 * HIDN;
  unsigned short* wV = wblk + (size_t)4096 * HIDN;
  unsigned short* wO = wblk + (size_t)6144 * HIDN;
  unsigned short* wG = wblk + (size_t)8192 * HIDN;   // 4096 rows (w1/w3 interleaved)
  unsigned short* wD = wblk + (size_t)12288 * HIDN;
  unsigned short* xb   = (unsigned short*)alloc((size_t)NROWS * HIDN * 2);
  unsigned short* qb   = (unsigned short*)alloc((size_t)NROWS * HIDN * 2);
  unsigned short* kb   = (unsigned short*)alloc((size_t)NROWS * HIDN * 2);
  unsigned short* vb   = (unsigned short*)alloc((size_t)NROWS * HIDN * 2);
  unsigned short* ctxb = (unsigned short*)alloc((size_t)NROWS * HIDN * 2);
  float* cosT = (float*)alloc((size_t)SEQ * 64 * 4);
  float* sinT = (float*)alloc((size_t)SEQ * 64 * 4);
  if (off > ws_size) return;

  dim3 tgrid(HIDN / 32, HIDN / 32);
  transpose_cvt_kernel<1><<<tgrid, 256, 0, stream>>>(Wq, wQ, 0);
  transpose_cvt_kernel<1><<<tgrid, 256, 0, stream>>>(Wk, wK, 0);
  transpose_cvt_kernel<0><<<tgrid, 256, 0, stream>>>(Wv, wV, 0);
  transpose_cvt_kernel<0><<<tgrid, 256, 0, stream>>>(Wo, wO, 0);
  transpose_cvt_kernel<2><<<tgrid, 256, 0, stream>>>(w1, wG, 0);
  transpose_cvt_kernel<2><<<tgrid, 256, 0, stream>>>(w3, wG, 1);
  transpose_cvt_kernel<0><<<tgrid, 256, 0, stream>>>(w2, wD, 0);
  rope_table_kernel<<<SEQ, 64, 0, stream>>>(cosT, sinT);

  rmsnorm_kernel<<<NROWS, 256, 0, stream>>>(hidden, ln1, xb);

  gemm256_kernel<0><<<(6144 / 256) * (NROWS / 256), 512, 0, stream>>>(
      xb, wQ, 6144 / 256, qb, kb, vb, cosT, sinT);

  flash_attn_kernel<<<dim3(SEQ / 64, NHEAD, BATCH), 256, 0, stream>>>(qb, kb, vb, ctxb);

  gemm_kernel<2><<<dim3(2048 / 128, NROWS / 128), 256, 0, stream>>>(
      ctxb, wO, 2048, out, hidden);

  rmsnorm_kernel<<<NROWS, 256, 0, stream>>>(out, ln2, xb);

  gemm256_kernel<1><<<(4096 / 256) * (NROWS / 256), 512, 0, stream>>>(
      xb, wG, 4096 / 256, qb, nullptr, nullptr, nullptr, nullptr);

  gemm_kernel<3><<<dim3(2048 / 128, NROWS / 128), 256, 0, stream>>>(
      qb, wD, 2048, out, nullptr);
}

// Round 6
// 477.086 us; speedup vs baseline: 1.9737x; 1.0752x over previous
//
#include <hip/hip_runtime.h>

#define HIDN 2048
#define NHEAD 16
#define HD 128
#define SEQ 2048
#define BATCH 2
#define NROWS (BATCH*SEQ)   // 4096

typedef __bf16 bf16_t;
typedef bf16_t bf16x8 __attribute__((ext_vector_type(8)));
typedef float f32x4 __attribute__((ext_vector_type(4)));

#define AS1 __attribute__((address_space(1)))
#define AS3 __attribute__((address_space(3)))

__device__ __forceinline__ unsigned short f2bf(float x) {
  union { bf16_t b; unsigned short u; } cv; cv.b = (bf16_t)x; return cv.u;
}

#define MFMA16(a,b,c) __builtin_amdgcn_mfma_f32_16x16x32_bf16((a),(b),(c),0,0,0)

__device__ __forceinline__ void gload16(const void* g, void* l) {
  __builtin_amdgcn_global_load_lds((const AS1 void*)g, (AS3 void*)l, 16, 0, 0);
}

// ---------------------------------------------------------------- fused weight transpose+cvt
// z selects weight. 64x64 tiles, float4 loads, ushort4 stores, [64][69] LDS (bank-clean).
__global__ __launch_bounds__(256) void transpose_all_kernel(
    const float* __restrict__ Wq, const float* __restrict__ Wk,
    const float* __restrict__ Wv, const float* __restrict__ Wo,
    const float* __restrict__ w1, const float* __restrict__ w3,
    const float* __restrict__ w2, unsigned short* __restrict__ wblk) {
  const int z = blockIdx.z;
  const float* W; unsigned short* dstb; int tmode = 0, half = 0;
  switch (z) {
    case 0: W = Wq; dstb = wblk;                       tmode = 1; break;
    case 1: W = Wk; dstb = wblk + (size_t)2048 * HIDN; tmode = 1; break;
    case 2: W = Wv; dstb = wblk + (size_t)4096 * HIDN; break;
    case 3: W = Wo; dstb = wblk + (size_t)6144 * HIDN; break;
    case 4: W = w1; dstb = wblk + (size_t)8192 * HIDN; tmode = 2; half = 0; break;
    case 5: W = w3; dstb = wblk + (size_t)8192 * HIDN; tmode = 2; half = 1; break;
    default: W = w2; dstb = wblk + (size_t)12288 * HIDN; break;
  }
  __shared__ float t[64][69];
  const int tid = threadIdx.x;
  const int bn = blockIdx.x * 64, bk = blockIdx.y * 64;
  const int lc = (tid & 15) * 4, lrw = tid >> 4;   // load: col quad, row
#pragma unroll
  for (int i = 0; i < 4; ++i) {
    int k = bk + lrw + i * 16;
    float4 v = *(const float4*)(W + (long)k * HIDN + bn + lc);
    t[lrw + i * 16][lc] = v.x; t[lrw + i * 16][lc + 1] = v.y;
    t[lrw + i * 16][lc + 2] = v.z; t[lrw + i * 16][lc + 3] = v.w;
  }
  __syncthreads();
  const int nl = tid >> 2, k0 = (tid & 3) * 16;    // write: one n-row, 16 k's
  int n = bn + nl;
  int dst;
  if (tmode == 0) dst = n;
  else if (tmode == 1) { int d = n & 127; dst = (n & ~127) | ((d & 63) << 1) | (d >> 6); }
  else dst = (n >> 4) * 32 + half * 16 + (n & 15);
  unsigned short* orow = dstb + (long)dst * HIDN + bk + k0;
#pragma unroll
  for (int j = 0; j < 16; j += 4) {
    ushort4 o;
    o.x = f2bf(t[k0 + j][nl]);     o.y = f2bf(t[k0 + j + 1][nl]);
    o.z = f2bf(t[k0 + j + 2][nl]); o.w = f2bf(t[k0 + j + 3][nl]);
    *(ushort4*)(orow + j) = o;
  }
}

// ---------------------------------------------------------------- rope tables
__global__ void rope_table_kernel(float* __restrict__ cosT, float* __restrict__ sinT) {
  int s = blockIdx.x, d = threadIdx.x;
  float invf = powf(10000.0f, (-2.0f * (float)d) / 128.0f);
  float ang = (float)s * invf;
  cosT[s * 64 + d] = cosf(ang);
  sinT[s * 64 + d] = sinf(ang);
}

// ---------------------------------------------------------------- rmsnorm
__global__ __launch_bounds__(256) void rmsnorm_kernel(
    const float* __restrict__ x, const float* __restrict__ w, unsigned short* __restrict__ out) {
  long row = blockIdx.x;
  const float* xr = x + row * HIDN;
  int c0 = threadIdx.x * 4;
  float4 v0 = *(const float4*)(xr + c0);
  float4 v1 = *(const float4*)(xr + 1024 + c0);
  float s = v0.x*v0.x + v0.y*v0.y + v0.z*v0.z + v0.w*v0.w
          + v1.x*v1.x + v1.y*v1.y + v1.z*v1.z + v1.w*v1.w;
#pragma unroll
  for (int off = 1; off < 64; off <<= 1) s += __shfl_xor(s, off);
  __shared__ float red[4];
  if ((threadIdx.x & 63) == 0) red[threadIdx.x >> 6] = s;
  __syncthreads();
  float tot = red[0] + red[1] + red[2] + red[3];
  float r = 1.0f / sqrtf(tot * (1.0f / (float)HIDN) + 1e-6f);
  float4 w0 = *(const float4*)(w + c0);
  float4 w1 = *(const float4*)(w + 1024 + c0);
  ushort4 o0, o1;
  o0.x = f2bf(v0.x * r * w0.x); o0.y = f2bf(v0.y * r * w0.y);
  o0.z = f2bf(v0.z * r * w0.z); o0.w = f2bf(v0.w * r * w0.w);
  o1.x = f2bf(v1.x * r * w1.x); o1.y = f2bf(v1.y * r * w1.y);
  o1.z = f2bf(v1.z * r * w1.z); o1.w = f2bf(v1.w * r * w1.w);
  *(ushort4*)(out + row * HIDN + c0) = o0;
  *(ushort4*)(out + row * HIDN + 1024 + c0) = o1;
}

// ---------------------------------------------------------------- GEMM 256x256 (deep pipeline)
// MODE 0: QKV+rope (q pre-scaled); v written TRANSPOSED to p2 = vT[b][h][d][s].
// MODE 1: gate silu-mul.
template <int MODE>
__global__ __launch_bounds__(512, 2) void gemm256_kernel(
    const unsigned short* __restrict__ A, const unsigned short* __restrict__ Bt,
    int nbx,
    void* __restrict__ p0, void* __restrict__ p1, void* __restrict__ p2,
    const float* __restrict__ cosT, const float* __restrict__ sinT) {
  __shared__ unsigned short L[65536];   // [2 dbuf][ A:16384 | B:16384 ] shorts
  const int tid = threadIdx.x;
  const int wave = tid >> 6, lane = tid & 63;
  const int lr = lane & 15, lkg = lane >> 4;
  const int wr = wave >> 2, wc = wave & 3;
  const int nwg = (int)gridDim.x;
  const int bid = (int)blockIdx.x;
  const int wg = (bid & 7) * (nwg >> 3) + (bid >> 3);
  const int bx = wg % nbx, by = wg / nbx;
  const long bm = (long)by * 256, bn = (long)bx * 256;
  const int srow = wave * 8 + (lane >> 3);
  const int sslot = (lane & 7) ^ (lane >> 3);
  const unsigned short* Ag = A + (bm + srow) * HIDN + sslot * 8;
  const unsigned short* Bg = Bt + (bn + srow) * HIDN + sslot * 8;
  f32x4 acc[8][4] = {};

#define STAGE256(kt2)                                                            \
  {                                                                              \
    const long ko = (long)(kt2) * 64;                                            \
    unsigned short* Ld = &L[((kt2) & 1) * 32768];                                \
    _Pragma("unroll")                                                            \
    for (int j = 0; j < 4; ++j) {                                                \
      gload16(Ag + ko + (long)j * 64 * HIDN, &Ld[(j * 64 + wave * 8) * 64]);     \
      gload16(Bg + ko + (long)j * 64 * HIDN, &Ld[16384 + (j * 64 + wave * 8) * 64]); \
    }                                                                            \
  }

  STAGE256(0);
  STAGE256(1);
  asm volatile("s_waitcnt vmcnt(8)" ::: "memory");
  __builtin_amdgcn_sched_barrier(0);
  __builtin_amdgcn_s_barrier();

  for (int kt = 0; kt < 32; ++kt) {
    const int d = kt & 1;
    const char* Lb = (const char*)L + d * 65536;
    bf16x8 bfr[4][2];
#pragma unroll
    for (int n = 0; n < 4; ++n) {
      int row = wc * 64 + n * 16 + lr;
      int x7 = row & 7;
#pragma unroll
      for (int ks = 0; ks < 2; ++ks) {
        int s = ks * 4 + lkg;
        bfr[n][ks] = *(const bf16x8*)(Lb + 32768 + row * 128 + ((s ^ x7) << 4));
      }
    }
#pragma unroll
    for (int q = 0; q < 4; ++q) {
      bf16x8 af[2][2];
#pragma unroll
      for (int mm = 0; mm < 2; ++mm) {
        int row = wr * 128 + (q * 2 + mm) * 16 + lr;
        int x7 = row & 7;
#pragma unroll
        for (int ks = 0; ks < 2; ++ks) {
          int s = ks * 4 + lkg;
          af[mm][ks] = *(const bf16x8*)(Lb + row * 128 + ((s ^ x7) << 4));
        }
      }
      __builtin_amdgcn_s_setprio(1);
#pragma unroll
      for (int mm = 0; mm < 2; ++mm)
#pragma unroll
        for (int n = 0; n < 4; ++n) {
          acc[q * 2 + mm][n] = MFMA16(af[mm][0], bfr[n][0], acc[q * 2 + mm][n]);
          acc[q * 2 + mm][n] = MFMA16(af[mm][1], bfr[n][1], acc[q * 2 + mm][n]);
        }
      __builtin_amdgcn_s_setprio(0);
    }
    if (kt == 31) break;
    asm volatile("s_waitcnt lgkmcnt(0)" ::: "memory");
    __builtin_amdgcn_sched_barrier(0);
    __builtin_amdgcn_s_barrier();
    if (kt < 30) {
      STAGE256(kt + 2);
      asm volatile("s_waitcnt vmcnt(8)" ::: "memory");
    } else {
      asm volatile("s_waitcnt vmcnt(0)" ::: "memory");
    }
    __builtin_amdgcn_sched_barrier(0);
    __builtin_amdgcn_s_barrier();
  }
#undef STAGE256

  // ---------------- epilogues ----------------
  const int gc0 = (int)bn + wc * 64;
  if (MODE == 1) {
    unsigned short* bout = (unsigned short*)p0;
#pragma unroll
    for (int m = 0; m < 8; ++m) {
      long r0 = bm + wr * 128 + m * 16 + lkg * 4;
#pragma unroll
      for (int n = 0; n < 4; n += 2) {
        int ggrp = (gc0 + n * 16) >> 5;
        long c = (long)ggrp * 16 + lr;
#pragma unroll
        for (int r = 0; r < 4; ++r) {
          float x = acc[m][n][r], g = acc[m][n + 1][r];
          float sv = x / (1.0f + __expf(-x)) * g;
          bout[(r0 + r) * 2048 + c] = f2bf(sv);
        }
      }
    }
  } else {  // MODE 0
    int bufid = gc0 >> 11;
    if (bufid == 2) {
      // v: write transposed vT[b][h][d][s], 8B per (m,n) per lane (r's s-contiguous)
      unsigned short* vT = (unsigned short*)p2;
#pragma unroll
      for (int m = 0; m < 8; ++m) {
        long r0 = bm + wr * 128 + m * 16 + lkg * 4;
        long bq = r0 >> 11;
        int s = (int)(r0 & 2047);
#pragma unroll
        for (int n = 0; n < 4; ++n) {
          int wcol = (gc0 + n * 16 + lr) & 2047;
          int hh = wcol >> 7, dd = wcol & 127;
          ushort4 pw;
          pw.x = f2bf(acc[m][n][0]); pw.y = f2bf(acc[m][n][1]);
          pw.z = f2bf(acc[m][n][2]); pw.w = f2bf(acc[m][n][3]);
          *(ushort4*)(vT + ((bq * 16 + hh) * 128 + dd) * (long)SEQ + s) = pw;
        }
      }
    } else {
      unsigned short* dst = (bufid == 0) ? (unsigned short*)p0 : (unsigned short*)p1;
      const float qscale = (bufid == 0) ? 0.08838834764831845f : 1.0f;
#pragma unroll
      for (int m = 0; m < 8; ++m) {
        long r0 = bm + wr * 128 + m * 16 + lkg * 4;
#pragma unroll
        for (int n = 0; n < 4; ++n) {
          int wcol = (gc0 + n * 16 + lr) & 2047;
          int f = wcol & 127, hh = wcol >> 7;
          int j = f >> 1, odd = f & 1;
          int oc = hh * 128 + (odd ? 64 : 0) + j;
#pragma unroll
          for (int r = 0; r < 4; ++r) {
            long row = r0 + r;
            int s = (int)(row & (SEQ - 1));
            float cv = cosT[s * 64 + j], sn = sinT[s * 64 + j];
            float v = acc[m][n][r];
            float o = __shfl_xor(v, 1);
            float res = (odd ? (v * cv + o * sn) : (v * cv - o * sn)) * qscale;
            dst[row * 2048 + oc] = f2bf(res);
          }
        }
      }
    }
  }
}

// ---------------------------------------------------------------- GEMM 128x128 (m97) for N=2048
// MODE 2 ADDH: f32 p0 = p1 + acc.   MODE 3 ADDOUT: f32 p0 += acc.
template <int MODE>
__global__ __launch_bounds__(256) void gemm_kernel(
    const unsigned short* __restrict__ A, const unsigned short* __restrict__ Bt, int N,
    void* __restrict__ p0, const void* __restrict__ p1) {
  __shared__ unsigned short As[128 * 32];
  __shared__ unsigned short Bs[128 * 32];
  const int tid = threadIdx.x;
  const int lane = tid & 63, wave = tid >> 6;
  const int wm = (wave >> 1) * 64, wn = (wave & 1) * 64;
  const int lr = lane & 15, lkg = lane >> 4;
  const long bm = (long)blockIdx.y * 128, bn = (long)blockIdx.x * 128;
  f32x4 acc[4][4] = {};
  const int rA0 = wave * 32 + (lane >> 2);
  const int gs0 = (lane & 3) ^ ((rA0 >> 1) & 3);
  const int gs1 = (lane & 3) ^ (((rA0 + 16) >> 1) & 3);
  const unsigned short* Ag0 = A + (bm + rA0) * HIDN + gs0 * 8;
  const unsigned short* Ag1 = A + (bm + rA0 + 16) * HIDN + gs1 * 8;
  const unsigned short* Bg0 = Bt + (bn + rA0) * HIDN + gs0 * 8;
  const unsigned short* Bg1 = Bt + (bn + rA0 + 16) * HIDN + gs1 * 8;
  unsigned short* lA0 = &As[(wave * 32) * 32];
  unsigned short* lA1 = &As[(wave * 32 + 16) * 32];
  unsigned short* lB0 = &Bs[(wave * 32) * 32];
  unsigned short* lB1 = &Bs[(wave * 32 + 16) * 32];
  for (int k0 = 0; k0 < HIDN; k0 += 32) {
    __syncthreads();
    gload16(Ag0 + k0, lA0);
    gload16(Ag1 + k0, lA1);
    gload16(Bg0 + k0, lB0);
    gload16(Bg1 + k0, lB1);
    __syncthreads();
    bf16x8 af[4], bfr[4];
#pragma unroll
    for (int m = 0; m < 4; ++m) {
      int row = wm + m * 16 + lr;
      af[m] = *(const bf16x8*)((const char*)As + row * 64 + ((lkg ^ ((row >> 1) & 3)) << 4));
    }
#pragma unroll
    for (int n = 0; n < 4; ++n) {
      int row = wn + n * 16 + lr;
      bfr[n] = *(const bf16x8*)((const char*)Bs + row * 64 + ((lkg ^ ((row >> 1) & 3)) << 4));
    }
#pragma unroll
    for (int m = 0; m < 4; ++m)
#pragma unroll
      for (int n = 0; n < 4; ++n) acc[m][n] = MFMA16(af[m], bfr[n], acc[m][n]);
  }
  float* fout = (float*)p0;
  const float* addsrc = (const float*)p1;
#pragma unroll
  for (int m = 0; m < 4; ++m)
#pragma unroll
    for (int n = 0; n < 4; ++n) {
      long r0 = bm + wm + m * 16 + lkg * 4;
      long c = bn + wn + n * 16 + lr;
#pragma unroll
      for (int r = 0; r < 4; ++r) {
        long idx = (r0 + r) * 2048 + c;
        if (MODE == 2) fout[idx] = addsrc[idx] + acc[m][n][r];
        else fout[idx] = fout[idx] + acc[m][n][r];
      }
    }
}

// ---------------------------------------------------------------- flash attention
// Swapped QK^T; K and V^T both staged via global_load_lds (dbuf, source-swizzled);
// defer-max (THR=8).  V^T comes pre-transposed in global: vT[b][h][d][s].
__global__ __launch_bounds__(256) void flash_attn_kernel(
    const unsigned short* __restrict__ Q, const unsigned short* __restrict__ Kb,
    const unsigned short* __restrict__ vT, unsigned short* __restrict__ O) {
  __shared__ unsigned short Ks[2][64 * 128];
  __shared__ unsigned short Vs[2][128 * 64];
  __shared__ unsigned short Ps[4][16][72];
  const int qt = blockIdx.x, h = blockIdx.y, b = blockIdx.z;
  const int tid = threadIdx.x, wave = tid >> 6, lane = tid & 63;
  const int lr = lane & 15, lkg = lane >> 4, lk = lkg * 8;
  const long rowbase = (long)b * SEQ;
  const int qrow0 = qt * 64 + wave * 16;
  bf16x8 aq[4];
#pragma unroll
  for (int ks = 0; ks < 4; ++ks)
    aq[ks] = *(const bf16x8*)(Q + (rowbase + qrow0 + lr) * HIDN + h * HD + ks * 32 + lk);
  const unsigned short* vbase = vT + ((long)(b * 16 + h) * 128) * SEQ;  // [d][s]
  // K staging: wave covers rows wave*16 + j*4 + (lane>>4), chunk lane&15, slot ^= row&15
  const int krl = lane >> 4;
  // V staging: wave covers d-rows wave*32 + j*8 + (lane>>3), chunk lane&7, slot ^= d&7
  const int vrl = lane >> 3, vch = lane & 7;
  f32x4 acc[8] = {};
  float m_ = -3.0e38f, l_ = 0.f;   // per-lane state for q-row = lr (replicated over lkg)

#define STAGEKV(t_, kv0_)                                                          \
  {                                                                                \
    _Pragma("unroll")                                                              \
    for (int j = 0; j < 4; ++j) {                                                  \
      int rl = wave * 16 + j * 4 + krl;                                            \
      int slot = (lane & 15) ^ (rl & 15);                                          \
      gload16(Kb + (rowbase + (kv0_) + rl) * HIDN + h * HD + slot * 8,             \
              &Ks[(t_) & 1][(wave * 16 + j * 4) * 128]);                           \
    }                                                                              \
    _Pragma("unroll")                                                              \
    for (int j = 0; j < 4; ++j) {                                                  \
      int dd = wave * 32 + j * 8 + vrl;                                            \
      int slot = vch ^ (dd & 7);                                                   \
      gload16(vbase + (long)dd * SEQ + (kv0_) + slot * 8,                          \
              &Vs[(t_) & 1][(wave * 32 + j * 8) * 64]);                            \
    }                                                                              \
  }

  STAGEKV(0, 0);

  for (int t = 0; t < SEQ / 64; ++t) {
    asm volatile("s_waitcnt vmcnt(0)" ::: "memory");   // my tile-t DMA done
    asm volatile("s_barrier" ::: "memory");            // all waves' tile-t DMA done
    if (t + 1 < SEQ / 64) STAGEKV(t + 1, (long)(t + 1) * 64);
    // ---- S^T = K x Q^T : col=q (lane&15), row=kv = n*16 + 4*lkg + r ----
    const char* ksb = (const char*)Ks[t & 1];
    f32x4 sa[4] = {};
#pragma unroll
    for (int n = 0; n < 4; ++n) {
      int row = n * 16 + lr;
#pragma unroll
      for (int ks = 0; ks < 4; ++ks) {
        bf16x8 bk = *(const bf16x8*)(ksb + row * 256 + (((ks * 4 + lkg) ^ (row & 15)) << 4));
        sa[n] = MFMA16(bk, aq[ks], sa[n]);
      }
    }
    // ---- softmax (kv lane-local), defer-max THR=8 ----
    float pmax = sa[0][0];
#pragma unroll
    for (int n = 0; n < 4; ++n)
#pragma unroll
      for (int r = 0; r < 4; ++r) pmax = fmaxf(pmax, sa[n][r]);
    pmax = fmaxf(pmax, __shfl_xor(pmax, 16));
    pmax = fmaxf(pmax, __shfl_xor(pmax, 32));
    if (__all(pmax - m_ <= 8.0f)) {
      // skip rescale: keep m_, corr == 1
      float psum = 0.f;
#pragma unroll
      for (int n = 0; n < 4; ++n)
#pragma unroll
        for (int r = 0; r < 4; ++r) {
          float p = __expf(sa[n][r] - m_);
          sa[n][r] = p;
          psum += p;
        }
      psum += __shfl_xor(psum, 16);
      psum += __shfl_xor(psum, 32);
      l_ += psum;
    } else {
      float mnew = fmaxf(m_, pmax);
      float corr = __expf(m_ - mnew);
      float psum = 0.f;
#pragma unroll
      for (int n = 0; n < 4; ++n)
#pragma unroll
        for (int r = 0; r < 4; ++r) {
          float p = __expf(sa[n][r] - mnew);
          sa[n][r] = p;
          psum += p;
        }
      psum += __shfl_xor(psum, 16);
      psum += __shfl_xor(psum, 32);
      l_ = l_ * corr + psum;
      m_ = mnew;
      float corr4[4];
#pragma unroll
      for (int r = 0; r < 4; ++r) corr4[r] = __shfl(corr, 4 * lkg + r);
#pragma unroll
      for (int df = 0; df < 8; ++df)
#pragma unroll
        for (int r = 0; r < 4; ++r) acc[df][r] *= corr4[r];
    }
    // ---- P -> per-wave LDS (b64 packed) ----
#pragma unroll
    for (int n = 0; n < 4; ++n) {
      ushort4 pw;
      pw.x = f2bf(sa[n][0]); pw.y = f2bf(sa[n][1]);
      pw.z = f2bf(sa[n][2]); pw.w = f2bf(sa[n][3]);
      *(ushort4*)&Ps[wave][lr][n * 16 + 4 * lkg] = pw;
    }
    bf16x8 pa0 = *(const bf16x8*)&Ps[wave][lr][lk];
    bf16x8 pa1 = *(const bf16x8*)&Ps[wave][lr][32 + lk];
    // ---- PV from Vs[t&1] ([d][kv], slot^(d&7) swizzle) ----
    const char* vsb = (const char*)Vs[t & 1];
#pragma unroll
    for (int df = 0; df < 8; ++df) {
      int row = df * 16 + lr;
      int x7 = row & 7;
      bf16x8 bv0 = *(const bf16x8*)(vsb + row * 128 + ((lkg ^ x7) << 4));
      bf16x8 bv1 = *(const bf16x8*)(vsb + row * 128 + (((4 + lkg) ^ x7) << 4));
      acc[df] = MFMA16(pa0, bv0, acc[df]);
      acc[df] = MFMA16(pa1, bv1, acc[df]);
    }
    asm volatile("s_barrier" ::: "memory");   // all reads of buf[t&1] done before restage
  }
#undef STAGEKV
  float invl = 1.0f / l_;
  float invl4[4];
#pragma unroll
  for (int r = 0; r < 4; ++r) invl4[r] = __shfl(invl, 4 * lkg + r);
#pragma unroll
  for (int r = 0; r < 4; ++r) {
    long orow = rowbase + qrow0 + lkg * 4 + r;
#pragma unroll
    for (int df = 0; df < 8; ++df)
      O[orow * HIDN + h * HD + df * 16 + lr] = f2bf(acc[df][r] * invl4[r]);
  }
}

// ---------------------------------------------------------------- launcher
extern "C" void kernel_launch(void* const* d_in, const int* in_sizes, int n_in,
                              void* d_out, int out_size, void* d_ws, size_t ws_size,
                              hipStream_t stream) {
  const float* hidden = (const float*)d_in[0];
  const float* Wq = (const float*)d_in[1];
  const float* Wk = (const float*)d_in[2];
  const float* Wv = (const float*)d_in[3];
  const float* Wo = (const float*)d_in[4];
  const float* w1 = (const float*)d_in[5];
  const float* w2 = (const float*)d_in[6];
  const float* w3 = (const float*)d_in[7];
  const float* ln1 = (const float*)d_in[8];
  const float* ln2 = (const float*)d_in[9];
  float* out = (float*)d_out;

  char* ws = (char*)d_ws;
  size_t off = 0;
  auto alloc = [&](size_t bytes) -> void* {
    void* p = ws + off;
    off += (bytes + 255) & ~(size_t)255;
    return p;
  };
  unsigned short* wblk = (unsigned short*)alloc((size_t)(2048L * 6 + 2048) * HIDN * 2);
  unsigned short* wQ = wblk;
  unsigned short* wG = wblk + (size_t)8192 * HIDN;
  unsigned short* wO = wblk + (size_t)6144 * HIDN;
  unsigned short* wD = wblk + (size_t)12288 * HIDN;
  unsigned short* xb   = (unsigned short*)alloc((size_t)NROWS * HIDN * 2);
  unsigned short* qb   = (unsigned short*)alloc((size_t)NROWS * HIDN * 2);
  unsigned short* kb   = (unsigned short*)alloc((size_t)NROWS * HIDN * 2);
  unsigned short* vTb  = (unsigned short*)alloc((size_t)NROWS * HIDN * 2);
  unsigned short* ctxb = (unsigned short*)alloc((size_t)NROWS * HIDN * 2);
  float* cosT = (float*)alloc((size_t)SEQ * 64 * 4);
  float* sinT = (float*)alloc((size_t)SEQ * 64 * 4);
  if (off > ws_size) return;

  transpose_all_kernel<<<dim3(HIDN / 64, HIDN / 64, 7), 256, 0, stream>>>(
      Wq, Wk, Wv, Wo, w1, w3, w2, wblk);
  rope_table_kernel<<<SEQ, 64, 0, stream>>>(cosT, sinT);

  rmsnorm_kernel<<<NROWS, 256, 0, stream>>>(hidden, ln1, xb);

  gemm256_kernel<0><<<(6144 / 256) * (NROWS / 256), 512, 0, stream>>>(
      xb, wQ, 6144 / 256, qb, kb, vTb, cosT, sinT);

  flash_attn_kernel<<<dim3(SEQ / 64, NHEAD, BATCH), 256, 0, stream>>>(qb, kb, vTb, ctxb);

  gemm_kernel<2><<<dim3(2048 / 128, NROWS / 128), 256, 0, stream>>>(
      ctxb, wO, 2048, out, hidden);

  rmsnorm_kernel<<<NROWS, 256, 0, stream>>>(out, ln2, xb);

  gemm256_kernel<1><<<(4096 / 256) * (NROWS / 256), 512, 0, stream>>>(
      xb, wG, 4096 / 256, qb, nullptr, nullptr, nullptr, nullptr);

  gemm_kernel<3><<<dim3(2048 / 128, NROWS / 128), 256, 0, stream>>>(
      qb, wD, 2048, out, nullptr);
}

// Round 7
// 463.733 us; speedup vs baseline: 2.0305x; 1.0288x over previous
//
#include <hip/hip_runtime.h>

#define HIDN 2048
#define NHEAD 16
#define HD 128
#define SEQ 2048
#define BATCH 2
#define NROWS (BATCH*SEQ)   // 4096

typedef __bf16 bf16_t;
typedef bf16_t bf16x8 __attribute__((ext_vector_type(8)));
typedef float f32x4 __attribute__((ext_vector_type(4)));

#define AS1 __attribute__((address_space(1)))
#define AS3 __attribute__((address_space(3)))

__device__ __forceinline__ unsigned short f2bf(float x) {
  union { bf16_t b; unsigned short u; } cv; cv.b = (bf16_t)x; return cv.u;
}

#define MFMA16(a,b,c) __builtin_amdgcn_mfma_f32_16x16x32_bf16((a),(b),(c),0,0,0)

__device__ __forceinline__ void gload16(const void* g, void* l) {
  __builtin_amdgcn_global_load_lds((const AS1 void*)g, (AS3 void*)l, 16, 0, 0);
}

// ---------------------------------------------------------------- fused weight transpose+cvt
__global__ __launch_bounds__(256) void transpose_all_kernel(
    const float* __restrict__ Wq, const float* __restrict__ Wk,
    const float* __restrict__ Wv, const float* __restrict__ Wo,
    const float* __restrict__ w1, const float* __restrict__ w3,
    const float* __restrict__ w2, unsigned short* __restrict__ wblk) {
  const int z = blockIdx.z;
  const float* W; unsigned short* dstb; int tmode = 0, half = 0;
  switch (z) {
    case 0: W = Wq; dstb = wblk;                       tmode = 1; break;
    case 1: W = Wk; dstb = wblk + (size_t)2048 * HIDN; tmode = 1; break;
    case 2: W = Wv; dstb = wblk + (size_t)4096 * HIDN; break;
    case 3: W = Wo; dstb = wblk + (size_t)6144 * HIDN; break;
    case 4: W = w1; dstb = wblk + (size_t)8192 * HIDN; tmode = 2; half = 0; break;
    case 5: W = w3; dstb = wblk + (size_t)8192 * HIDN; tmode = 2; half = 1; break;
    default: W = w2; dstb = wblk + (size_t)12288 * HIDN; break;
  }
  __shared__ float t[64][69];
  const int tid = threadIdx.x;
  const int bn = blockIdx.x * 64, bk = blockIdx.y * 64;
  const int lc = (tid & 15) * 4, lrw = tid >> 4;
#pragma unroll
  for (int i = 0; i < 4; ++i) {
    int k = bk + lrw + i * 16;
    float4 v = *(const float4*)(W + (long)k * HIDN + bn + lc);
    t[lrw + i * 16][lc] = v.x; t[lrw + i * 16][lc + 1] = v.y;
    t[lrw + i * 16][lc + 2] = v.z; t[lrw + i * 16][lc + 3] = v.w;
  }
  __syncthreads();
  const int nl = tid >> 2, k0 = (tid & 3) * 16;
  int n = bn + nl;
  int dst;
  if (tmode == 0) dst = n;
  else if (tmode == 1) { int d = n & 127; dst = (n & ~127) | ((d & 63) << 1) | (d >> 6); }
  else dst = (n >> 4) * 32 + half * 16 + (n & 15);
  unsigned short* orow = dstb + (long)dst * HIDN + bk + k0;
#pragma unroll
  for (int j = 0; j < 16; j += 4) {
    ushort4 o;
    o.x = f2bf(t[k0 + j][nl]);     o.y = f2bf(t[k0 + j + 1][nl]);
    o.z = f2bf(t[k0 + j + 2][nl]); o.w = f2bf(t[k0 + j + 3][nl]);
    *(ushort4*)(orow + j) = o;
  }
}

// ---------------------------------------------------------------- rope tables
__global__ void rope_table_kernel(float* __restrict__ cosT, float* __restrict__ sinT) {
  int s = blockIdx.x, d = threadIdx.x;
  float invf = powf(10000.0f, (-2.0f * (float)d) / 128.0f);
  float ang = (float)s * invf;
  cosT[s * 64 + d] = cosf(ang);
  sinT[s * 64 + d] = sinf(ang);
}

// ---------------------------------------------------------------- rmsnorm
__global__ __launch_bounds__(256) void rmsnorm_kernel(
    const float* __restrict__ x, const float* __restrict__ w, unsigned short* __restrict__ out) {
  long row = blockIdx.x;
  const float* xr = x + row * HIDN;
  int c0 = threadIdx.x * 4;
  float4 v0 = *(const float4*)(xr + c0);
  float4 v1 = *(const float4*)(xr + 1024 + c0);
  float s = v0.x*v0.x + v0.y*v0.y + v0.z*v0.z + v0.w*v0.w
          + v1.x*v1.x + v1.y*v1.y + v1.z*v1.z + v1.w*v1.w;
#pragma unroll
  for (int off = 1; off < 64; off <<= 1) s += __shfl_xor(s, off);
  __shared__ float red[4];
  if ((threadIdx.x & 63) == 0) red[threadIdx.x >> 6] = s;
  __syncthreads();
  float tot = red[0] + red[1] + red[2] + red[3];
  float r = 1.0f / sqrtf(tot * (1.0f / (float)HIDN) + 1e-6f);
  float4 w0 = *(const float4*)(w + c0);
  float4 w1 = *(const float4*)(w + 1024 + c0);
  ushort4 o0, o1;
  o0.x = f2bf(v0.x * r * w0.x); o0.y = f2bf(v0.y * r * w0.y);
  o0.z = f2bf(v0.z * r * w0.z); o0.w = f2bf(v0.w * r * w0.w);
  o1.x = f2bf(v1.x * r * w1.x); o1.y = f2bf(v1.y * r * w1.y);
  o1.z = f2bf(v1.z * r * w1.z); o1.w = f2bf(v1.w * r * w1.w);
  *(ushort4*)(out + row * HIDN + c0) = o0;
  *(ushort4*)(out + row * HIDN + 1024 + c0) = o1;
}

// ---------------------------------------------------------------- GEMM 256x256, 8-phase schedule
// C = A[M,2048] x Bt[N,2048]^T. 512 thr / 8 waves (2Mx4N), BK=64, 128 KiB LDS.
// LDS: half-tiles [buf][mat][half] of 128x64 bf16; per-phase {ds_read, stage 1 half,
// barrier, lgkmcnt(0), setprio MFMA quadrant, barrier}; vmcnt(4)@P4, vmcnt(6)@P8.
// MODE 0: QKV+rope (q pre-scaled); v transposed to p2. MODE 1: gate silu-mul.
template <int MODE>
__global__ __launch_bounds__(512, 2) void gemm256_kernel(
    const unsigned short* __restrict__ A, const unsigned short* __restrict__ Bt,
    int nbx,
    void* __restrict__ p0, void* __restrict__ p1, void* __restrict__ p2,
    const float* __restrict__ cosT, const float* __restrict__ sinT) {
  __shared__ unsigned short L[65536];   // [buf2][mat2][half2][128*64]
  const int tid = threadIdx.x;
  const int wave = tid >> 6, lane = tid & 63;
  const int lr = lane & 15, lkg = lane >> 4;
  const int wr = wave >> 2, wc = wave & 3;
  const int x7 = lr & 7;
  const int nwg = (int)gridDim.x;
  const int bid = (int)blockIdx.x;
  const int wg = (bid & 7) * (nwg >> 3) + (bid >> 3);
  const int bx = wg % nbx, by = wg / nbx;
  const long bm = (long)by * 256, bn = (long)bx * 256;
  // staging: per half-tile (128x64), wave covers rows j*64 + wave*8 + (lane>>3), j=0,1
  const int sslot = (lane & 7) ^ (lane >> 3);
  const unsigned short* Ag = A + (bm + wave * 8 + (lane >> 3)) * HIDN + sslot * 8;
  const unsigned short* Bg = Bt + (bn + wave * 8 + (lane >> 3)) * HIDN + sslot * 8;
  const char* Lc = (const char*)L;
  f32x4 acc[8][4] = {};
  bf16x8 af[2][2], bfr[4][2];

  // STG(buf, mat, half, tile): stage one 128x64 half-tile (2 gload16/thread)
#define STG(b, mat, half, tile)                                                   \
  {                                                                               \
    const unsigned short* gsrc = ((mat) ? Bg : Ag) + ((long)(half) * 128) * HIDN + (long)(tile) * 64; \
    unsigned short* ldst = &L[((4 * (b) + 2 * (mat) + (half)) * 8192) + wave * 8 * 64]; \
    gload16(gsrc, ldst);                                                          \
    gload16(gsrc + (long)64 * HIDN, ldst + 4096);                                 \
  }
#define DSRA(b, q)                                                                \
  { _Pragma("unroll") for (int mm = 0; mm < 2; ++mm) {                            \
      int row128 = ((q) * 2 + mm) * 16 + lr;                                      \
      _Pragma("unroll") for (int ks = 0; ks < 2; ++ks) {                          \
        int s = ks * 4 + lkg;                                                     \
        af[mm][ks] = *(const bf16x8*)(Lc + (4 * (b) + wr) * 16384 + row128 * 128 + ((s ^ x7) << 4)); \
      } } }
#define DSRB(b)                                                                   \
  { _Pragma("unroll") for (int n = 0; n < 4; ++n) {                               \
      int row128 = (wc & 1) * 64 + n * 16 + lr;                                   \
      _Pragma("unroll") for (int ks = 0; ks < 2; ++ks) {                          \
        int s = ks * 4 + lkg;                                                     \
        bfr[n][ks] = *(const bf16x8*)(Lc + (4 * (b) + 2 + (wc >> 1)) * 16384 + row128 * 128 + ((s ^ x7) << 4)); \
      } } }
#define MFMAQ(q)                                                                  \
  { __builtin_amdgcn_s_setprio(1);                                                \
    _Pragma("unroll") for (int mm = 0; mm < 2; ++mm)                              \
      _Pragma("unroll") for (int n = 0; n < 4; ++n) {                             \
        acc[(q) * 2 + mm][n] = MFMA16(af[mm][0], bfr[n][0], acc[(q) * 2 + mm][n]); \
        acc[(q) * 2 + mm][n] = MFMA16(af[mm][1], bfr[n][1], acc[(q) * 2 + mm][n]); \
      }                                                                           \
    __builtin_amdgcn_s_setprio(0); }
#define BARR __builtin_amdgcn_s_barrier()
#define LGK0 { asm volatile("s_waitcnt lgkmcnt(0)" ::: "memory"); __builtin_amdgcn_sched_barrier(0); }

  // ---- prologue: tile0 (buf0) full + tile1 (buf1) B0,B1,A0 ----
  STG(0, 0, 0, 0); STG(0, 0, 1, 0); STG(0, 1, 0, 0); STG(0, 1, 1, 0);
  STG(1, 1, 0, 1); STG(1, 1, 1, 1); STG(1, 0, 0, 1);
  asm volatile("s_waitcnt vmcnt(6)" ::: "memory");   // tile0's 8 loads landed
  __builtin_amdgcn_sched_barrier(0);
  BARR;

  const int NIT = HIDN / 128;   // 16 iterations, 2 K-tiles each
#pragma unroll 1
  for (int i = 0; i < NIT; ++i) {
    const int t2 = 2 * i + 2, t3 = 2 * i + 3;
    const bool nl_ = (i < NIT - 1);
    // P1: compute t0.q0 (buf0); stage A1(t1)->buf1 (just-in-time)
    DSRA(0, 0); DSRB(0);
    STG(1, 0, 1, 2 * i + 1);
    asm volatile("s_waitcnt lgkmcnt(8)" ::: "memory");
    BARR; LGK0; MFMAQ(0); BARR;
    // P2
    DSRA(0, 1);
    if (nl_) STG(0, 1, 0, t2);
    BARR; LGK0; MFMAQ(1); BARR;
    // P3
    DSRA(0, 2);
    if (nl_) STG(0, 1, 1, t2);
    BARR; LGK0; MFMAQ(2); BARR;
    // P4: vmcnt gate for t1's halves
    DSRA(0, 3);
    BARR; LGK0; MFMAQ(3);
    if (nl_) { asm volatile("s_waitcnt vmcnt(4)" ::: "memory"); }
    else     { asm volatile("s_waitcnt vmcnt(0)" ::: "memory"); }
    __builtin_amdgcn_sched_barrier(0);
    BARR;
    // P5: compute t1.q0 (buf1); stage A0(t2)->buf0
    DSRA(1, 0); DSRB(1);
    if (nl_) STG(0, 0, 0, t2);
    asm volatile("s_waitcnt lgkmcnt(8)" ::: "memory");
    BARR; LGK0; MFMAQ(0); BARR;
    // P6
    DSRA(1, 1);
    if (nl_) { STG(0, 0, 1, t2); STG(1, 1, 0, t3); }
    BARR; LGK0; MFMAQ(1); BARR;
    // P7
    DSRA(1, 2);
    if (nl_) STG(1, 1, 1, t3);
    BARR; LGK0; MFMAQ(2); BARR;
    // P8: vmcnt gate for t2's halves
    DSRA(1, 3);
    if (nl_) STG(1, 0, 0, t3);
    BARR; LGK0; MFMAQ(3);
    if (nl_) { asm volatile("s_waitcnt vmcnt(6)" ::: "memory"); __builtin_amdgcn_sched_barrier(0); }
    BARR;
  }
#undef STG
#undef DSRA
#undef DSRB
#undef MFMAQ
#undef BARR
#undef LGK0

  // ---------------- epilogues ----------------
  const int gc0 = (int)bn + wc * 64;
  if (MODE == 1) {
    unsigned short* bout = (unsigned short*)p0;
#pragma unroll
    for (int m = 0; m < 8; ++m) {
      long r0 = bm + wr * 128 + m * 16 + lkg * 4;
#pragma unroll
      for (int n = 0; n < 4; n += 2) {
        int ggrp = (gc0 + n * 16) >> 5;
        long c = (long)ggrp * 16 + lr;
#pragma unroll
        for (int r = 0; r < 4; ++r) {
          float x = acc[m][n][r], g = acc[m][n + 1][r];
          float sv = x / (1.0f + __expf(-x)) * g;
          bout[(r0 + r) * 2048 + c] = f2bf(sv);
        }
      }
    }
  } else {  // MODE 0
    int bufid = gc0 >> 11;
    if (bufid == 2) {
      unsigned short* vT = (unsigned short*)p2;
#pragma unroll
      for (int m = 0; m < 8; ++m) {
        long r0 = bm + wr * 128 + m * 16 + lkg * 4;
        long bq = r0 >> 11;
        int s = (int)(r0 & 2047);
#pragma unroll
        for (int n = 0; n < 4; ++n) {
          int wcol = (gc0 + n * 16 + lr) & 2047;
          int hh = wcol >> 7, dd = wcol & 127;
          ushort4 pw;
          pw.x = f2bf(acc[m][n][0]); pw.y = f2bf(acc[m][n][1]);
          pw.z = f2bf(acc[m][n][2]); pw.w = f2bf(acc[m][n][3]);
          *(ushort4*)(vT + ((bq * 16 + hh) * 128 + dd) * (long)SEQ + s) = pw;
        }
      }
    } else {
      unsigned short* dst = (bufid == 0) ? (unsigned short*)p0 : (unsigned short*)p1;
      const float qscale = (bufid == 0) ? 0.08838834764831845f : 1.0f;
#pragma unroll
      for (int m = 0; m < 8; ++m) {
        long r0 = bm + wr * 128 + m * 16 + lkg * 4;
#pragma unroll
        for (int n = 0; n < 4; ++n) {
          int wcol = (gc0 + n * 16 + lr) & 2047;
          int f = wcol & 127, hh = wcol >> 7;
          int j = f >> 1, odd = f & 1;
          int oc = hh * 128 + (odd ? 64 : 0) + j;
#pragma unroll
          for (int r = 0; r < 4; ++r) {
            long row = r0 + r;
            int s = (int)(row & (SEQ - 1));
            float cv = cosT[s * 64 + j], sn = sinT[s * 64 + j];
            float v = acc[m][n][r];
            float o = __shfl_xor(v, 1);
            float res = (odd ? (v * cv + o * sn) : (v * cv - o * sn)) * qscale;
            dst[row * 2048 + oc] = f2bf(res);
          }
        }
      }
    }
  }
}

// ---------------------------------------------------------------- GEMM 128x128 (m97) for N=2048
template <int MODE>
__global__ __launch_bounds__(256) void gemm_kernel(
    const unsigned short* __restrict__ A, const unsigned short* __restrict__ Bt, int N,
    void* __restrict__ p0, const void* __restrict__ p1) {
  __shared__ unsigned short As[128 * 32];
  __shared__ unsigned short Bs[128 * 32];
  const int tid = threadIdx.x;
  const int lane = tid & 63, wave = tid >> 6;
  const int wm = (wave >> 1) * 64, wn = (wave & 1) * 64;
  const int lr = lane & 15, lkg = lane >> 4;
  const long bm = (long)blockIdx.y * 128, bn = (long)blockIdx.x * 128;
  f32x4 acc[4][4] = {};
  const int rA0 = wave * 32 + (lane >> 2);
  const int gs0 = (lane & 3) ^ ((rA0 >> 1) & 3);
  const int gs1 = (lane & 3) ^ (((rA0 + 16) >> 1) & 3);
  const unsigned short* Ag0 = A + (bm + rA0) * HIDN + gs0 * 8;
  const unsigned short* Ag1 = A + (bm + rA0 + 16) * HIDN + gs1 * 8;
  const unsigned short* Bg0 = Bt + (bn + rA0) * HIDN + gs0 * 8;
  const unsigned short* Bg1 = Bt + (bn + rA0 + 16) * HIDN + gs1 * 8;
  unsigned short* lA0 = &As[(wave * 32) * 32];
  unsigned short* lA1 = &As[(wave * 32 + 16) * 32];
  unsigned short* lB0 = &Bs[(wave * 32) * 32];
  unsigned short* lB1 = &Bs[(wave * 32 + 16) * 32];
  for (int k0 = 0; k0 < HIDN; k0 += 32) {
    __syncthreads();
    gload16(Ag0 + k0, lA0);
    gload16(Ag1 + k0, lA1);
    gload16(Bg0 + k0, lB0);
    gload16(Bg1 + k0, lB1);
    __syncthreads();
    bf16x8 af[4], bfr[4];
#pragma unroll
    for (int m = 0; m < 4; ++m) {
      int row = wm + m * 16 + lr;
      af[m] = *(const bf16x8*)((const char*)As + row * 64 + ((lkg ^ ((row >> 1) & 3)) << 4));
    }
#pragma unroll
    for (int n = 0; n < 4; ++n) {
      int row = wn + n * 16 + lr;
      bfr[n] = *(const bf16x8*)((const char*)Bs + row * 64 + ((lkg ^ ((row >> 1) & 3)) << 4));
    }
#pragma unroll
    for (int m = 0; m < 4; ++m)
#pragma unroll
      for (int n = 0; n < 4; ++n) acc[m][n] = MFMA16(af[m], bfr[n], acc[m][n]);
  }
  float* fout = (float*)p0;
  const float* addsrc = (const float*)p1;
#pragma unroll
  for (int m = 0; m < 4; ++m)
#pragma unroll
    for (int n = 0; n < 4; ++n) {
      long r0 = bm + wm + m * 16 + lkg * 4;
      long c = bn + wn + n * 16 + lr;
#pragma unroll
      for (int r = 0; r < 4; ++r) {
        long idx = (r0 + r) * 2048 + c;
        if (MODE == 2) fout[idx] = addsrc[idx] + acc[m][n][r];
        else fout[idx] = fout[idx] + acc[m][n][r];
      }
    }
}

// ---------------------------------------------------------------- flash attention
__global__ __launch_bounds__(256) void flash_attn_kernel(
    const unsigned short* __restrict__ Q, const unsigned short* __restrict__ Kb,
    const unsigned short* __restrict__ vT, unsigned short* __restrict__ O) {
  __shared__ unsigned short Ks[2][64 * 128];
  __shared__ unsigned short Vs[2][128 * 64];
  __shared__ unsigned short Ps[4][16][72];
  const int qt = blockIdx.x, h = blockIdx.y, b = blockIdx.z;
  const int tid = threadIdx.x, wave = tid >> 6, lane = tid & 63;
  const int lr = lane & 15, lkg = lane >> 4, lk = lkg * 8;
  const long rowbase = (long)b * SEQ;
  const int qrow0 = qt * 64 + wave * 16;
  bf16x8 aq[4];
#pragma unroll
  for (int ks = 0; ks < 4; ++ks)
    aq[ks] = *(const bf16x8*)(Q + (rowbase + qrow0 + lr) * HIDN + h * HD + ks * 32 + lk);
  const unsigned short* vbase = vT + ((long)(b * 16 + h) * 128) * SEQ;  // [d][s]
  const int krl = lane >> 4;
  const int vrl = lane >> 3, vch = lane & 7;
  f32x4 acc[8] = {};
  float m_ = -3.0e38f, l_ = 0.f;

#define STAGEKV(t_, kv0_)                                                          \
  {                                                                                \
    _Pragma("unroll")                                                              \
    for (int j = 0; j < 4; ++j) {                                                  \
      int rl = wave * 16 + j * 4 + krl;                                            \
      int slot = (lane & 15) ^ (rl & 15);                                          \
      gload16(Kb + (rowbase + (kv0_) + rl) * HIDN + h * HD + slot * 8,             \
              &Ks[(t_) & 1][(wave * 16 + j * 4) * 128]);                           \
    }                                                                              \
    _Pragma("unroll")                                                              \
    for (int j = 0; j < 4; ++j) {                                                  \
      int dd = wave * 32 + j * 8 + vrl;                                            \
      int slot = vch ^ (dd & 7);                                                   \
      gload16(vbase + (long)dd * SEQ + (kv0_) + slot * 8,                          \
              &Vs[(t_) & 1][(wave * 32 + j * 8) * 64]);                            \
    }                                                                              \
  }

  STAGEKV(0, 0);

  for (int t = 0; t < SEQ / 64; ++t) {
    asm volatile("s_waitcnt vmcnt(0)" ::: "memory");
    asm volatile("s_barrier" ::: "memory");
    if (t + 1 < SEQ / 64) STAGEKV(t + 1, (long)(t + 1) * 64);
    const char* ksb = (const char*)Ks[t & 1];
    f32x4 sa[4] = {};
#pragma unroll
    for (int n = 0; n < 4; ++n) {
      int row = n * 16 + lr;
#pragma unroll
      for (int ks = 0; ks < 4; ++ks) {
        bf16x8 bk = *(const bf16x8*)(ksb + row * 256 + (((ks * 4 + lkg) ^ (row & 15)) << 4));
        sa[n] = MFMA16(bk, aq[ks], sa[n]);
      }
    }
    float pmax = sa[0][0];
#pragma unroll
    for (int n = 0; n < 4; ++n)
#pragma unroll
      for (int r = 0; r < 4; ++r) pmax = fmaxf(pmax, sa[n][r]);
    pmax = fmaxf(pmax, __shfl_xor(pmax, 16));
    pmax = fmaxf(pmax, __shfl_xor(pmax, 32));
    if (__all(pmax - m_ <= 8.0f)) {
      float psum = 0.f;
#pragma unroll
      for (int n = 0; n < 4; ++n)
#pragma unroll
        for (int r = 0; r < 4; ++r) {
          float p = __expf(sa[n][r] - m_);
          sa[n][r] = p;
          psum += p;
        }
      psum += __shfl_xor(psum, 16);
      psum += __shfl_xor(psum, 32);
      l_ += psum;
    } else {
      float mnew = fmaxf(m_, pmax);
      float corr = __expf(m_ - mnew);
      float psum = 0.f;
#pragma unroll
      for (int n = 0; n < 4; ++n)
#pragma unroll
        for (int r = 0; r < 4; ++r) {
          float p = __expf(sa[n][r] - mnew);
          sa[n][r] = p;
          psum += p;
        }
      psum += __shfl_xor(psum, 16);
      psum += __shfl_xor(psum, 32);
      l_ = l_ * corr + psum;
      m_ = mnew;
      float corr4[4];
#pragma unroll
      for (int r = 0; r < 4; ++r) corr4[r] = __shfl(corr, 4 * lkg + r);
#pragma unroll
      for (int df = 0; df < 8; ++df)
#pragma unroll
        for (int r = 0; r < 4; ++r) acc[df][r] *= corr4[r];
    }
#pragma unroll
    for (int n = 0; n < 4; ++n) {
      ushort4 pw;
      pw.x = f2bf(sa[n][0]); pw.y = f2bf(sa[n][1]);
      pw.z = f2bf(sa[n][2]); pw.w = f2bf(sa[n][3]);
      *(ushort4*)&Ps[wave][lr][n * 16 + 4 * lkg] = pw;
    }
    bf16x8 pa0 = *(const bf16x8*)&Ps[wave][lr][lk];
    bf16x8 pa1 = *(const bf16x8*)&Ps[wave][lr][32 + lk];
    const char* vsb = (const char*)Vs[t & 1];
#pragma unroll
    for (int df = 0; df < 8; ++df) {
      int row = df * 16 + lr;
      int x7 = row & 7;
      bf16x8 bv0 = *(const bf16x8*)(vsb + row * 128 + ((lkg ^ x7) << 4));
      bf16x8 bv1 = *(const bf16x8*)(vsb + row * 128 + (((4 + lkg) ^ x7) << 4));
      acc[df] = MFMA16(pa0, bv0, acc[df]);
      acc[df] = MFMA16(pa1, bv1, acc[df]);
    }
    asm volatile("s_barrier" ::: "memory");
  }
#undef STAGEKV
  float invl = 1.0f / l_;
  float invl4[4];
#pragma unroll
  for (int r = 0; r < 4; ++r) invl4[r] = __shfl(invl, 4 * lkg + r);
#pragma unroll
  for (int r = 0; r < 4; ++r) {
    long orow = rowbase + qrow0 + lkg * 4 + r;
#pragma unroll
    for (int df = 0; df < 8; ++df)
      O[orow * HIDN + h * HD + df * 16 + lr] = f2bf(acc[df][r] * invl4[r]);
  }
}

// ---------------------------------------------------------------- launcher
extern "C" void kernel_launch(void* const* d_in, const int* in_sizes, int n_in,
                              void* d_out, int out_size, void* d_ws, size_t ws_size,
                              hipStream_t stream) {
  const float* hidden = (const float*)d_in[0];
  const float* Wq = (const float*)d_in[1];
  const float* Wk = (const float*)d_in[2];
  const float* Wv = (const float*)d_in[3];
  const float* Wo = (const float*)d_in[4];
  const float* w1 = (const float*)d_in[5];
  const float* w2 = (const float*)d_in[6];
  const float* w3 = (const float*)d_in[7];
  const float* ln1 = (const float*)d_in[8];
  const float* ln2 = (const float*)d_in[9];
  float* out = (float*)d_out;

  char* ws = (char*)d_ws;
  size_t off = 0;
  auto alloc = [&](size_t bytes) -> void* {
    void* p = ws + off;
    off += (bytes + 255) & ~(size_t)255;
    return p;
  };
  unsigned short* wblk = (unsigned short*)alloc((size_t)(2048L * 6 + 2048) * HIDN * 2);
  unsigned short* wQ = wblk;
  unsigned short* wG = wblk + (size_t)8192 * HIDN;
  unsigned short* wO = wblk + (size_t)6144 * HIDN;
  unsigned short* wD = wblk + (size_t)12288 * HIDN;
  unsigned short* xb   = (unsigned short*)alloc((size_t)NROWS * HIDN * 2);
  unsigned short* qb   = (unsigned short*)alloc((size_t)NROWS * HIDN * 2);
  unsigned short* kb   = (unsigned short*)alloc((size_t)NROWS * HIDN * 2);
  unsigned short* vTb  = (unsigned short*)alloc((size_t)NROWS * HIDN * 2);
  unsigned short* ctxb = (unsigned short*)alloc((size_t)NROWS * HIDN * 2);
  float* cosT = (float*)alloc((size_t)SEQ * 64 * 4);
  float* sinT = (float*)alloc((size_t)SEQ * 64 * 4);
  if (off > ws_size) return;

  transpose_all_kernel<<<dim3(HIDN / 64, HIDN / 64, 7), 256, 0, stream>>>(
      Wq, Wk, Wv, Wo, w1, w3, w2, wblk);
  rope_table_kernel<<<SEQ, 64, 0, stream>>>(cosT, sinT);

  rmsnorm_kernel<<<NROWS, 256, 0, stream>>>(hidden, ln1, xb);

  gemm256_kernel<0><<<(6144 / 256) * (NROWS / 256), 512, 0, stream>>>(
      xb, wQ, 6144 / 256, qb, kb, vTb, cosT, sinT);

  flash_attn_kernel<<<dim3(SEQ / 64, NHEAD, BATCH), 256, 0, stream>>>(qb, kb, vTb, ctxb);

  gemm_kernel<2><<<dim3(2048 / 128, NROWS / 128), 256, 0, stream>>>(
      ctxb, wO, 2048, out, hidden);

  rmsnorm_kernel<<<NROWS, 256, 0, stream>>>(out, ln2, xb);

  gemm256_kernel<1><<<(4096 / 256) * (NROWS / 256), 512, 0, stream>>>(
      xb, wG, 4096 / 256, qb, nullptr, nullptr, nullptr, nullptr);

  gemm_kernel<3><<<dim3(2048 / 128, NROWS / 128), 256, 0, stream>>>(
      qb, wD, 2048, out, nullptr);
}

// Round 8
// 463.595 us; speedup vs baseline: 2.0311x; 1.0003x over previous
//
#include <hip/hip_runtime.h>

#define HIDN 2048
#define NHEAD 16
#define HD 128
#define SEQ 2048
#define BATCH 2
#define NROWS (BATCH*SEQ)   // 4096

typedef __bf16 bf16_t;
typedef bf16_t bf16x8 __attribute__((ext_vector_type(8)));
typedef float f32x4 __attribute__((ext_vector_type(4)));

#define AS1 __attribute__((address_space(1)))
#define AS3 __attribute__((address_space(3)))

__device__ __forceinline__ unsigned short f2bf(float x) {
  union { bf16_t b; unsigned short u; } cv; cv.b = (bf16_t)x; return cv.u;
}

#define MFMA16(a,b,c) __builtin_amdgcn_mfma_f32_16x16x32_bf16((a),(b),(c),0,0,0)

__device__ __forceinline__ void gload16(const void* g, void* l) {
  __builtin_amdgcn_global_load_lds((const AS1 void*)g, (AS3 void*)l, 16, 0, 0);
}

// ---------------------------------------------------------------- fused weight transpose+cvt
__global__ __launch_bounds__(256) void transpose_all_kernel(
    const float* __restrict__ Wq, const float* __restrict__ Wk,
    const float* __restrict__ Wv, const float* __restrict__ Wo,
    const float* __restrict__ w1, const float* __restrict__ w3,
    const float* __restrict__ w2, unsigned short* __restrict__ wblk) {
  const int z = blockIdx.z;
  const float* W; unsigned short* dstb; int tmode = 0, half = 0;
  switch (z) {
    case 0: W = Wq; dstb = wblk;                       tmode = 1; break;
    case 1: W = Wk; dstb = wblk + (size_t)2048 * HIDN; tmode = 1; break;
    case 2: W = Wv; dstb = wblk + (size_t)4096 * HIDN; break;
    case 3: W = Wo; dstb = wblk + (size_t)6144 * HIDN; break;
    case 4: W = w1; dstb = wblk + (size_t)8192 * HIDN; tmode = 2; half = 0; break;
    case 5: W = w3; dstb = wblk + (size_t)8192 * HIDN; tmode = 2; half = 1; break;
    default: W = w2; dstb = wblk + (size_t)12288 * HIDN; break;
  }
  __shared__ float t[64][69];
  const int tid = threadIdx.x;
  const int bn = blockIdx.x * 64, bk = blockIdx.y * 64;
  const int lc = (tid & 15) * 4, lrw = tid >> 4;
#pragma unroll
  for (int i = 0; i < 4; ++i) {
    int k = bk + lrw + i * 16;
    float4 v = *(const float4*)(W + (long)k * HIDN + bn + lc);
    t[lrw + i * 16][lc] = v.x; t[lrw + i * 16][lc + 1] = v.y;
    t[lrw + i * 16][lc + 2] = v.z; t[lrw + i * 16][lc + 3] = v.w;
  }
  __syncthreads();
  const int nl = tid >> 2, k0 = (tid & 3) * 16;
  int n = bn + nl;
  int dst;
  if (tmode == 0) dst = n;
  else if (tmode == 1) { int d = n & 127; dst = (n & ~127) | ((d & 63) << 1) | (d >> 6); }
  else dst = (n >> 4) * 32 + half * 16 + (n & 15);
  unsigned short* orow = dstb + (long)dst * HIDN + bk + k0;
#pragma unroll
  for (int j = 0; j < 16; j += 4) {
    ushort4 o;
    o.x = f2bf(t[k0 + j][nl]);     o.y = f2bf(t[k0 + j + 1][nl]);
    o.z = f2bf(t[k0 + j + 2][nl]); o.w = f2bf(t[k0 + j + 3][nl]);
    *(ushort4*)(orow + j) = o;
  }
}

// ---------------------------------------------------------------- rope tables
__global__ void rope_table_kernel(float* __restrict__ cosT, float* __restrict__ sinT) {
  int s = blockIdx.x, d = threadIdx.x;
  float invf = powf(10000.0f, (-2.0f * (float)d) / 128.0f);
  float ang = (float)s * invf;
  cosT[s * 64 + d] = cosf(ang);
  sinT[s * 64 + d] = sinf(ang);
}

// ---------------------------------------------------------------- rmsnorm
__global__ __launch_bounds__(256) void rmsnorm_kernel(
    const float* __restrict__ x, const float* __restrict__ w, unsigned short* __restrict__ out) {
  long row = blockIdx.x;
  const float* xr = x + row * HIDN;
  int c0 = threadIdx.x * 4;
  float4 v0 = *(const float4*)(xr + c0);
  float4 v1 = *(const float4*)(xr + 1024 + c0);
  float s = v0.x*v0.x + v0.y*v0.y + v0.z*v0.z + v0.w*v0.w
          + v1.x*v1.x + v1.y*v1.y + v1.z*v1.z + v1.w*v1.w;
#pragma unroll
  for (int off = 1; off < 64; off <<= 1) s += __shfl_xor(s, off);
  __shared__ float red[4];
  if ((threadIdx.x & 63) == 0) red[threadIdx.x >> 6] = s;
  __syncthreads();
  float tot = red[0] + red[1] + red[2] + red[3];
  float r = 1.0f / sqrtf(tot * (1.0f / (float)HIDN) + 1e-6f);
  float4 w0 = *(const float4*)(w + c0);
  float4 w1 = *(const float4*)(w + 1024 + c0);
  ushort4 o0, o1;
  o0.x = f2bf(v0.x * r * w0.x); o0.y = f2bf(v0.y * r * w0.y);
  o0.z = f2bf(v0.z * r * w0.z); o0.w = f2bf(v0.w * r * w0.w);
  o1.x = f2bf(v1.x * r * w1.x); o1.y = f2bf(v1.y * r * w1.y);
  o1.z = f2bf(v1.z * r * w1.z); o1.w = f2bf(v1.w * r * w1.w);
  *(ushort4*)(out + row * HIDN + c0) = o0;
  *(ushort4*)(out + row * HIDN + 1024 + c0) = o1;
}

// ---------------------------------------------------------------- GEMM 256x256, 8-phase schedule
template <int MODE>
__global__ __launch_bounds__(512, 2) void gemm256_kernel(
    const unsigned short* __restrict__ A, const unsigned short* __restrict__ Bt,
    int nbx,
    void* __restrict__ p0, void* __restrict__ p1, void* __restrict__ p2,
    const float* __restrict__ cosT, const float* __restrict__ sinT) {
  __shared__ unsigned short L[65536];   // [buf2][mat2][half2][128*64]
  const int tid = threadIdx.x;
  const int wave = tid >> 6, lane = tid & 63;
  const int lr = lane & 15, lkg = lane >> 4;
  const int wr = wave >> 2, wc = wave & 3;
  const int x7 = lr & 7;
  const int nwg = (int)gridDim.x;
  const int bid = (int)blockIdx.x;
  const int wg = (bid & 7) * (nwg >> 3) + (bid >> 3);
  const int bx = wg % nbx, by = wg / nbx;
  const long bm = (long)by * 256, bn = (long)bx * 256;
  const int sslot = (lane & 7) ^ (lane >> 3);
  const unsigned short* Ag = A + (bm + wave * 8 + (lane >> 3)) * HIDN + sslot * 8;
  const unsigned short* Bg = Bt + (bn + wave * 8 + (lane >> 3)) * HIDN + sslot * 8;
  const char* Lc = (const char*)L;
  f32x4 acc[8][4] = {};
  bf16x8 af[2][2], bfr[4][2];

#define STG(b, mat, half, tile)                                                   \
  {                                                                               \
    const unsigned short* gsrc = ((mat) ? Bg : Ag) + ((long)(half) * 128) * HIDN + (long)(tile) * 64; \
    unsigned short* ldst = &L[((4 * (b) + 2 * (mat) + (half)) * 8192) + wave * 8 * 64]; \
    gload16(gsrc, ldst);                                                          \
    gload16(gsrc + (long)64 * HIDN, ldst + 4096);                                 \
  }
#define DSRA(b, q)                                                                \
  { _Pragma("unroll") for (int mm = 0; mm < 2; ++mm) {                            \
      int row128 = ((q) * 2 + mm) * 16 + lr;                                      \
      _Pragma("unroll") for (int ks = 0; ks < 2; ++ks) {                          \
        int s = ks * 4 + lkg;                                                     \
        af[mm][ks] = *(const bf16x8*)(Lc + (4 * (b) + wr) * 16384 + row128 * 128 + ((s ^ x7) << 4)); \
      } } }
#define DSRB(b)                                                                   \
  { _Pragma("unroll") for (int n = 0; n < 4; ++n) {                               \
      int row128 = (wc & 1) * 64 + n * 16 + lr;                                   \
      _Pragma("unroll") for (int ks = 0; ks < 2; ++ks) {                          \
        int s = ks * 4 + lkg;                                                     \
        bfr[n][ks] = *(const bf16x8*)(Lc + (4 * (b) + 2 + (wc >> 1)) * 16384 + row128 * 128 + ((s ^ x7) << 4)); \
      } } }
#define MFMAQ(q)                                                                  \
  { __builtin_amdgcn_s_setprio(1);                                                \
    _Pragma("unroll") for (int mm = 0; mm < 2; ++mm)                              \
      _Pragma("unroll") for (int n = 0; n < 4; ++n) {                             \
        acc[(q) * 2 + mm][n] = MFMA16(af[mm][0], bfr[n][0], acc[(q) * 2 + mm][n]); \
        acc[(q) * 2 + mm][n] = MFMA16(af[mm][1], bfr[n][1], acc[(q) * 2 + mm][n]); \
      }                                                                           \
    __builtin_amdgcn_s_setprio(0); }
#define BARR __builtin_amdgcn_s_barrier()
#define LGK0 { asm volatile("s_waitcnt lgkmcnt(0)" ::: "memory"); __builtin_amdgcn_sched_barrier(0); }

  STG(0, 0, 0, 0); STG(0, 0, 1, 0); STG(0, 1, 0, 0); STG(0, 1, 1, 0);
  STG(1, 1, 0, 1); STG(1, 1, 1, 1); STG(1, 0, 0, 1);
  asm volatile("s_waitcnt vmcnt(6)" ::: "memory");
  __builtin_amdgcn_sched_barrier(0);
  BARR;

  const int NIT = HIDN / 128;
#pragma unroll 1
  for (int i = 0; i < NIT; ++i) {
    const int t2 = 2 * i + 2, t3 = 2 * i + 3;
    const bool nl_ = (i < NIT - 1);
    DSRA(0, 0); DSRB(0);
    STG(1, 0, 1, 2 * i + 1);
    asm volatile("s_waitcnt lgkmcnt(8)" ::: "memory");
    BARR; LGK0; MFMAQ(0); BARR;
    DSRA(0, 1);
    if (nl_) STG(0, 1, 0, t2);
    BARR; LGK0; MFMAQ(1); BARR;
    DSRA(0, 2);
    if (nl_) STG(0, 1, 1, t2);
    BARR; LGK0; MFMAQ(2); BARR;
    DSRA(0, 3);
    BARR; LGK0; MFMAQ(3);
    if (nl_) { asm volatile("s_waitcnt vmcnt(4)" ::: "memory"); }
    else     { asm volatile("s_waitcnt vmcnt(0)" ::: "memory"); }
    __builtin_amdgcn_sched_barrier(0);
    BARR;
    DSRA(1, 0); DSRB(1);
    if (nl_) STG(0, 0, 0, t2);
    asm volatile("s_waitcnt lgkmcnt(8)" ::: "memory");
    BARR; LGK0; MFMAQ(0); BARR;
    DSRA(1, 1);
    if (nl_) { STG(0, 0, 1, t2); STG(1, 1, 0, t3); }
    BARR; LGK0; MFMAQ(1); BARR;
    DSRA(1, 2);
    if (nl_) STG(1, 1, 1, t3);
    BARR; LGK0; MFMAQ(2); BARR;
    DSRA(1, 3);
    if (nl_) STG(1, 0, 0, t3);
    BARR; LGK0; MFMAQ(3);
    if (nl_) { asm volatile("s_waitcnt vmcnt(6)" ::: "memory"); __builtin_amdgcn_sched_barrier(0); }
    BARR;
  }
#undef STG
#undef DSRA
#undef DSRB
#undef MFMAQ
#undef BARR
#undef LGK0

  const int gc0 = (int)bn + wc * 64;
  if (MODE == 1) {
    unsigned short* bout = (unsigned short*)p0;
#pragma unroll
    for (int m = 0; m < 8; ++m) {
      long r0 = bm + wr * 128 + m * 16 + lkg * 4;
#pragma unroll
      for (int n = 0; n < 4; n += 2) {
        int ggrp = (gc0 + n * 16) >> 5;
        long c = (long)ggrp * 16 + lr;
#pragma unroll
        for (int r = 0; r < 4; ++r) {
          float x = acc[m][n][r], g = acc[m][n + 1][r];
          float sv = x / (1.0f + __expf(-x)) * g;
          bout[(r0 + r) * 2048 + c] = f2bf(sv);
        }
      }
    }
  } else {
    int bufid = gc0 >> 11;
    if (bufid == 2) {
      unsigned short* vT = (unsigned short*)p2;
#pragma unroll
      for (int m = 0; m < 8; ++m) {
        long r0 = bm + wr * 128 + m * 16 + lkg * 4;
        long bq = r0 >> 11;
        int s = (int)(r0 & 2047);
#pragma unroll
        for (int n = 0; n < 4; ++n) {
          int wcol = (gc0 + n * 16 + lr) & 2047;
          int hh = wcol >> 7, dd = wcol & 127;
          ushort4 pw;
          pw.x = f2bf(acc[m][n][0]); pw.y = f2bf(acc[m][n][1]);
          pw.z = f2bf(acc[m][n][2]); pw.w = f2bf(acc[m][n][3]);
          *(ushort4*)(vT + ((bq * 16 + hh) * 128 + dd) * (long)SEQ + s) = pw;
        }
      }
    } else {
      unsigned short* dst = (bufid == 0) ? (unsigned short*)p0 : (unsigned short*)p1;
      // q gets 1/sqrt(HD) * log2(e) folded in (flash softmax runs in log2 domain)
      const float qscale = (bufid == 0) ? 0.12751689f : 1.0f;
#pragma unroll
      for (int m = 0; m < 8; ++m) {
        long r0 = bm + wr * 128 + m * 16 + lkg * 4;
#pragma unroll
        for (int n = 0; n < 4; ++n) {
          int wcol = (gc0 + n * 16 + lr) & 2047;
          int f = wcol & 127, hh = wcol >> 7;
          int j = f >> 1, odd = f & 1;
          int oc = hh * 128 + (odd ? 64 : 0) + j;
#pragma unroll
          for (int r = 0; r < 4; ++r) {
            long row = r0 + r;
            int s = (int)(row & (SEQ - 1));
            float cv = cosT[s * 64 + j], sn = sinT[s * 64 + j];
            float v = acc[m][n][r];
            float o = __shfl_xor(v, 1);
            float res = (odd ? (v * cv + o * sn) : (v * cv - o * sn)) * qscale;
            dst[row * 2048 + oc] = f2bf(res);
          }
        }
      }
    }
  }
}

// ---------------------------------------------------------------- GEMM 128x128 (m97) for N=2048
template <int MODE>
__global__ __launch_bounds__(256) void gemm_kernel(
    const unsigned short* __restrict__ A, const unsigned short* __restrict__ Bt, int N,
    void* __restrict__ p0, const void* __restrict__ p1) {
  __shared__ unsigned short As[128 * 32];
  __shared__ unsigned short Bs[128 * 32];
  const int tid = threadIdx.x;
  const int lane = tid & 63, wave = tid >> 6;
  const int wm = (wave >> 1) * 64, wn = (wave & 1) * 64;
  const int lr = lane & 15, lkg = lane >> 4;
  const long bm = (long)blockIdx.y * 128, bn = (long)blockIdx.x * 128;
  f32x4 acc[4][4] = {};
  const int rA0 = wave * 32 + (lane >> 2);
  const int gs0 = (lane & 3) ^ ((rA0 >> 1) & 3);
  const int gs1 = (lane & 3) ^ (((rA0 + 16) >> 1) & 3);
  const unsigned short* Ag0 = A + (bm + rA0) * HIDN + gs0 * 8;
  const unsigned short* Ag1 = A + (bm + rA0 + 16) * HIDN + gs1 * 8;
  const unsigned short* Bg0 = Bt + (bn + rA0) * HIDN + gs0 * 8;
  const unsigned short* Bg1 = Bt + (bn + rA0 + 16) * HIDN + gs1 * 8;
  unsigned short* lA0 = &As[(wave * 32) * 32];
  unsigned short* lA1 = &As[(wave * 32 + 16) * 32];
  unsigned short* lB0 = &Bs[(wave * 32) * 32];
  unsigned short* lB1 = &Bs[(wave * 32 + 16) * 32];
  for (int k0 = 0; k0 < HIDN; k0 += 32) {
    __syncthreads();
    gload16(Ag0 + k0, lA0);
    gload16(Ag1 + k0, lA1);
    gload16(Bg0 + k0, lB0);
    gload16(Bg1 + k0, lB1);
    __syncthreads();
    bf16x8 af[4], bfr[4];
#pragma unroll
    for (int m = 0; m < 4; ++m) {
      int row = wm + m * 16 + lr;
      af[m] = *(const bf16x8*)((const char*)As + row * 64 + ((lkg ^ ((row >> 1) & 3)) << 4));
    }
#pragma unroll
    for (int n = 0; n < 4; ++n) {
      int row = wn + n * 16 + lr;
      bfr[n] = *(const bf16x8*)((const char*)Bs + row * 64 + ((lkg ^ ((row >> 1) & 3)) << 4));
    }
#pragma unroll
    for (int m = 0; m < 4; ++m)
#pragma unroll
      for (int n = 0; n < 4; ++n) acc[m][n] = MFMA16(af[m], bfr[n], acc[m][n]);
  }
  float* fout = (float*)p0;
  const float* addsrc = (const float*)p1;
#pragma unroll
  for (int m = 0; m < 4; ++m)
#pragma unroll
    for (int n = 0; n < 4; ++n) {
      long r0 = bm + wm + m * 16 + lkg * 4;
      long c = bn + wn + n * 16 + lr;
#pragma unroll
      for (int r = 0; r < 4; ++r) {
        long idx = (r0 + r) * 2048 + c;
        if (MODE == 2) fout[idx] = addsrc[idx] + acc[m][n][r];
        else fout[idx] = fout[idx] + acc[m][n][r];
      }
    }
}

// ---------------------------------------------------------------- flash attention
// Single-buffered K/V LDS (41KB -> 3 blocks/CU), register prefetch of tile t+1,
// XCD-chunked block swizzle for K/V L2 reuse, log2-domain softmax (q pre-scaled
// by 1/sqrt(HD)*log2e), defer-max THR=11.54 (=8 nats).
__global__ __launch_bounds__(256, 3) void flash_attn_kernel(
    const unsigned short* __restrict__ Q, const unsigned short* __restrict__ Kb,
    const unsigned short* __restrict__ vT, unsigned short* __restrict__ O) {
  __shared__ unsigned short Ks[64 * 128];
  __shared__ unsigned short Vs[128 * 64];
  __shared__ unsigned short Ps[4][16][72];
  // XCD-chunked swizzle: 1024 blocks, 128 per XCD chunk (whole (b,h) groups)
  const int bid = (int)blockIdx.x;
  const int wg = (bid & 7) * 128 + (bid >> 3);
  const int qt = wg & 31, h = (wg >> 5) & 15, b = wg >> 9;
  const int tid = threadIdx.x, wave = tid >> 6, lane = tid & 63;
  const int lr = lane & 15, lkg = lane >> 4, lk = lkg * 8;
  const long rowbase = (long)b * SEQ;
  const int qrow0 = qt * 64 + wave * 16;
  bf16x8 aq[4];
#pragma unroll
  for (int ks = 0; ks < 4; ++ks)
    aq[ks] = *(const bf16x8*)(Q + (rowbase + qrow0 + lr) * HIDN + h * HD + ks * 32 + lk);
  const unsigned short* vbase = vT + ((long)(b * 16 + h) * 128) * SEQ;  // [d][s]
  // staging geometry (reg path)
  const int kr_ = tid >> 4, kc_ = tid & 15;   // K: row kr_+j*16, 16B chunk kc_
  const int vd_ = tid >> 3, vc_ = tid & 7;    // V: d-row vd_+j*32, 16B chunk vc_
  int4 kreg[4], vreg[4];
  f32x4 acc[8] = {};
  float m_ = -3.0e38f, l_ = 0.f;

#define GLOADKV(kv0_)                                                              \
  { _Pragma("unroll")                                                              \
    for (int j = 0; j < 4; ++j)                                                    \
      kreg[j] = *(const int4*)(Kb + (rowbase + (kv0_) + kr_ + j * 16) * HIDN + h * HD + kc_ * 8); \
    _Pragma("unroll")                                                              \
    for (int j = 0; j < 4; ++j)                                                    \
      vreg[j] = *(const int4*)(vbase + (long)(vd_ + j * 32) * SEQ + (kv0_) + vc_ * 8); }
#define DSWRITEKV()                                                                \
  { _Pragma("unroll")                                                              \
    for (int j = 0; j < 4; ++j) {                                                  \
      int row = kr_ + j * 16;                                                      \
      *(int4*)((char*)Ks + row * 256 + ((kc_ ^ (row & 15)) << 4)) = kreg[j];       \
    }                                                                              \
    _Pragma("unroll")                                                              \
    for (int j = 0; j < 4; ++j) {                                                  \
      int d = vd_ + j * 32;                                                        \
      *(int4*)((char*)Vs + d * 128 + ((vc_ ^ (d & 7)) << 4)) = vreg[j];            \
    } }

  // prologue: tile 0
  GLOADKV(0);
  asm volatile("s_waitcnt vmcnt(0)" ::: "memory");
  DSWRITEKV();
  asm volatile("s_waitcnt lgkmcnt(0)" ::: "memory");
  __builtin_amdgcn_sched_barrier(0);
  asm volatile("s_barrier" ::: "memory");

  for (int t = 0; t < SEQ / 64; ++t) {
    if (t + 1 < SEQ / 64) GLOADKV((long)(t + 1) * 64);   // prefetch flies under compute
    // ---- S^T = K x Q^T : col=q (lane&15), row=kv = n*16 + 4*lkg + r ----
    const char* ksb = (const char*)Ks;
    f32x4 sa[4] = {};
#pragma unroll
    for (int n = 0; n < 4; ++n) {
      int row = n * 16 + lr;
#pragma unroll
      for (int ks = 0; ks < 4; ++ks) {
        bf16x8 bk = *(const bf16x8*)(ksb + row * 256 + (((ks * 4 + lkg) ^ (row & 15)) << 4));
        sa[n] = MFMA16(bk, aq[ks], sa[n]);
      }
    }
    // ---- softmax in log2 domain; defer-max ----
    float pmax = sa[0][0];
#pragma unroll
    for (int n = 0; n < 4; ++n)
#pragma unroll
      for (int r = 0; r < 4; ++r) pmax = fmaxf(pmax, sa[n][r]);
    pmax = fmaxf(pmax, __shfl_xor(pmax, 16));
    pmax = fmaxf(pmax, __shfl_xor(pmax, 32));
    if (__all(pmax - m_ <= 11.54f)) {
      float psum = 0.f;
#pragma unroll
      for (int n = 0; n < 4; ++n)
#pragma unroll
        for (int r = 0; r < 4; ++r) {
          float p = exp2f(sa[n][r] - m_);
          sa[n][r] = p;
          psum += p;
        }
      psum += __shfl_xor(psum, 16);
      psum += __shfl_xor(psum, 32);
      l_ += psum;
    } else {
      float mnew = fmaxf(m_, pmax);
      float corr = exp2f(m_ - mnew);
      float psum = 0.f;
#pragma unroll
      for (int n = 0; n < 4; ++n)
#pragma unroll
        for (int r = 0; r < 4; ++r) {
          float p = exp2f(sa[n][r] - mnew);
          sa[n][r] = p;
          psum += p;
        }
      psum += __shfl_xor(psum, 16);
      psum += __shfl_xor(psum, 32);
      l_ = l_ * corr + psum;
      m_ = mnew;
      float corr4[4];
#pragma unroll
      for (int r = 0; r < 4; ++r) corr4[r] = __shfl(corr, 4 * lkg + r);
#pragma unroll
      for (int df = 0; df < 8; ++df)
#pragma unroll
        for (int r = 0; r < 4; ++r) acc[df][r] *= corr4[r];
    }
    // ---- P -> per-wave LDS (b64 packed) ----
#pragma unroll
    for (int n = 0; n < 4; ++n) {
      ushort4 pw;
      pw.x = f2bf(sa[n][0]); pw.y = f2bf(sa[n][1]);
      pw.z = f2bf(sa[n][2]); pw.w = f2bf(sa[n][3]);
      *(ushort4*)&Ps[wave][lr][n * 16 + 4 * lkg] = pw;
    }
    bf16x8 pa0 = *(const bf16x8*)&Ps[wave][lr][lk];
    bf16x8 pa1 = *(const bf16x8*)&Ps[wave][lr][32 + lk];
    const char* vsb = (const char*)Vs;
#pragma unroll
    for (int df = 0; df < 8; ++df) {
      int row = df * 16 + lr;
      int x7 = row & 7;
      bf16x8 bv0 = *(const bf16x8*)(vsb + row * 128 + ((lkg ^ x7) << 4));
      bf16x8 bv1 = *(const bf16x8*)(vsb + row * 128 + (((4 + lkg) ^ x7) << 4));
      acc[df] = MFMA16(pa0, bv0, acc[df]);
      acc[df] = MFMA16(pa1, bv1, acc[df]);
    }
    asm volatile("s_barrier" ::: "memory");            // all waves done reading tile t
    if (t + 1 < SEQ / 64) {
      asm volatile("s_waitcnt vmcnt(0)" ::: "memory"); // prefetch landed
      DSWRITEKV();
      asm volatile("s_waitcnt lgkmcnt(0)" ::: "memory");
      __builtin_amdgcn_sched_barrier(0);
      asm volatile("s_barrier" ::: "memory");          // tile t+1 visible to all
    }
  }
#undef GLOADKV
#undef DSWRITEKV
  float invl = 1.0f / l_;
  float invl4[4];
#pragma unroll
  for (int r = 0; r < 4; ++r) invl4[r] = __shfl(invl, 4 * lkg + r);
#pragma unroll
  for (int r = 0; r < 4; ++r) {
    long orow = rowbase + qrow0 + lkg * 4 + r;
#pragma unroll
    for (int df = 0; df < 8; ++df)
      O[orow * HIDN + h * HD + df * 16 + lr] = f2bf(acc[df][r] * invl4[r]);
  }
}

// ---------------------------------------------------------------- launcher
extern "C" void kernel_launch(void* const* d_in, const int* in_sizes, int n_in,
                              void* d_out, int out_size, void* d_ws, size_t ws_size,
                              hipStream_t stream) {
  const float* hidden = (const float*)d_in[0];
  const float* Wq = (const float*)d_in[1];
  const float* Wk = (const float*)d_in[2];
  const float* Wv = (const float*)d_in[3];
  const float* Wo = (const float*)d_in[4];
  const float* w1 = (const float*)d_in[5];
  const float* w2 = (const float*)d_in[6];
  const float* w3 = (const float*)d_in[7];
  const float* ln1 = (const float*)d_in[8];
  const float* ln2 = (const float*)d_in[9];
  float* out = (float*)d_out;

  char* ws = (char*)d_ws;
  size_t off = 0;
  auto alloc = [&](size_t bytes) -> void* {
    void* p = ws + off;
    off += (bytes + 255) & ~(size_t)255;
    return p;
  };
  unsigned short* wblk = (unsigned short*)alloc((size_t)(2048L * 6 + 2048) * HIDN * 2);
  unsigned short* wQ = wblk;
  unsigned short* wG = wblk + (size_t)8192 * HIDN;
  unsigned short* wO = wblk + (size_t)6144 * HIDN;
  unsigned short* wD = wblk + (size_t)12288 * HIDN;
  unsigned short* xb   = (unsigned short*)alloc((size_t)NROWS * HIDN * 2);
  unsigned short* qb   = (unsigned short*)alloc((size_t)NROWS * HIDN * 2);
  unsigned short* kb   = (unsigned short*)alloc((size_t)NROWS * HIDN * 2);
  unsigned short* vTb  = (unsigned short*)alloc((size_t)NROWS * HIDN * 2);
  unsigned short* ctxb = (unsigned short*)alloc((size_t)NROWS * HIDN * 2);
  float* cosT = (float*)alloc((size_t)SEQ * 64 * 4);
  float* sinT = (float*)alloc((size_t)SEQ * 64 * 4);
  if (off > ws_size) return;

  transpose_all_kernel<<<dim3(HIDN / 64, HIDN / 64, 7), 256, 0, stream>>>(
      Wq, Wk, Wv, Wo, w1, w3, w2, wblk);
  rope_table_kernel<<<SEQ, 64, 0, stream>>>(cosT, sinT);

  rmsnorm_kernel<<<NROWS, 256, 0, stream>>>(hidden, ln1, xb);

  gemm256_kernel<0><<<(6144 / 256) * (NROWS / 256), 512, 0, stream>>>(
      xb, wQ, 6144 / 256, qb, kb, vTb, cosT, sinT);

  flash_attn_kernel<<<(SEQ / 64) * NHEAD * BATCH, 256, 0, stream>>>(qb, kb, vTb, ctxb);

  gemm_kernel<2><<<dim3(2048 / 128, NROWS / 128), 256, 0, stream>>>(
      ctxb, wO, 2048, out, hidden);

  rmsnorm_kernel<<<NROWS, 256, 0, stream>>>(out, ln2, xb);

  gemm256_kernel<1><<<(4096 / 256) * (NROWS / 256), 512, 0, stream>>>(
      xb, wG, 4096 / 256, qb, nullptr, nullptr, nullptr, nullptr);

  gemm_kernel<3><<<dim3(2048 / 128, NROWS / 128), 256, 0, stream>>>(
      qb, wD, 2048, out, nullptr);
}